// Round 8
// baseline (292.374 us; speedup 1.0000x reference)
//
#include <hip/hip_runtime.h>
#include <hip/hip_bf16.h>

// ---------------------------------------------------------------------------
// KEPCE_GCN, round 8: full CSR; atomic-free, gather-coalesced consumers.
//  partition: bucket radix (hist/scan/fillsort) -> k_group (per-bucket
//  counting sort by node) -> CSR(rowstart, recs2=src) + deg/dinv free.
//  k_sA2: thread/node run-sum of dinv[src]; writes g1[N][32] (rank-2).
//  k_AB3: wave/node; per edge one coalesced 128B g1 load; fused node MLP.
//  k_edge unchanged.
// ---------------------------------------------------------------------------

#define NNODES 100000
#define NREG   17
#define KB     782          // buckets = ceil(100000/128)
#define FBC    256          // fill/hist chunk blocks
#define STCAP  12544        // LDS staging capacity (>= chunk)

// wsm element offsets (f32)
#define O_W0    0
#define O_B0    8
#define O_W1    16
#define O_B1    144
#define O_W2    160
#define O_B2C   672
#define O_WN    704
#define O_BN    1728
#define O_WE1   1760
#define O_BE1   3872
#define O_WE2   3904
#define O_BE2   3968
#define WSM_N   3970
#define O_H0    3972
#define O_TS    3992
#define O_NT    4008
#define O_U     4016   // 17*32
#define O_WWR   4560   // 17*32
#define O_M     5104   // 66*2
#define O_BIAS2 5236
#define WSM_TOTAL 6144

__device__ __forceinline__ float bf2f(unsigned short u) {
  union { float f; unsigned int i; } v; v.i = ((unsigned int)u) << 16; return v.f;
}
__device__ __forceinline__ unsigned short f2bf(float f) {
  union { float f; unsigned int i; } v; v.f = f;
  unsigned int x = v.i;
  return (unsigned short)((x + 0x7FFFu + ((x >> 16) & 1u)) >> 16);
}
__device__ __forceinline__ float relu_(float x) { return x > 0.f ? x : 0.f; }

__global__ __launch_bounds__(256) void k_detect(const unsigned short* ew, int* mode) {
  __shared__ int cnt;
  if (threadIdx.x == 0) cnt = 0;
  __syncthreads();
  int ok = 0;
  for (int i = threadIdx.x; i < 512; i += blockDim.x) {
    unsigned short h = ew[i];
    int e = (h >> 7) & 0xFF;
    if (!(h & 0x8000) && e >= 0x70 && e <= 0x7E) ok++;
  }
  atomicAdd(&cnt, ok);
  __syncthreads();
  if (threadIdx.x == 0) *mode = (cnt >= 400) ? 1 : 0;  // 1 = bf16
}

__global__ __launch_bounds__(256) void k_convert_small(
    const void* p0, const void* p1, const void* p2, const void* p3,
    const void* p4, const void* p5, const void* p6, const void* p7,
    const void* p8, const void* p9, const void* p10, const void* p11,
    const int* mode, float* wsm) {
  int idx = blockIdx.x * blockDim.x + threadIdx.x;
  if (idx >= WSM_N) return;
  const void* ptrs[12] = {p0,p1,p2,p3,p4,p5,p6,p7,p8,p9,p10,p11};
  const int offs[13] = {O_W0,O_B0,O_W1,O_B1,O_W2,O_B2C,O_WN,O_BN,O_WE1,O_BE1,O_WE2,O_BE2,WSM_N};
  int seg = 0;
  while (idx >= offs[seg + 1]) seg++;
  int k = idx - offs[seg];
  wsm[idx] = (*mode) ? bf2f(((const unsigned short*)ptrs[seg])[k])
                     : ((const float*)ptrs[seg])[k];
}

__global__ __launch_bounds__(64) void k_prep(float* wsm) {
  __shared__ float h0[16], ts[16];
  __shared__ int snt;
  int t = threadIdx.x;
  if (t < 16) {
    float acc = 0.f;
    for (int j = 0; j < 8; j++)
      acc += (wsm[O_W0 + j] + wsm[O_B0 + j]) * wsm[O_W1 + j * 16 + t];
    h0[t] = acc;
    wsm[O_H0 + t] = acc;
  }
  __syncthreads();
  if (t == 0) {
    int n = 0;
    for (int j = 0; j < 16; j++) {
      float h = h0[j], b = wsm[O_B1 + j];
      if (h != 0.f) {
        float tj = -b / h;
        if (tj > 0.f) {
          int p = n++;
          while (p > 0 && ts[p - 1] > tj) { ts[p] = ts[p - 1]; p--; }
          ts[p] = tj;
        }
      }
    }
    snt = n;
    wsm[O_NT] = (float)n;
    for (int i = 0; i < n; i++) wsm[O_TS + i] = ts[i];
  }
  __syncthreads();
  int n = snt;
  for (int r = 0; r <= n; r++) {
    float srep;
    if (n == 0) srep = 1.f;
    else if (r == 0) srep = ts[0] * 0.5f;
    else if (r == n) srep = ts[n - 1] * 2.f + 1.f;
    else srep = 0.5f * (ts[r - 1] + ts[r]);
    if (t < 32) {
      float uu = 0.f, ww = 0.f;
      for (int j = 0; j < 16; j++) {
        float h = h0[j], b = wsm[O_B1 + j];
        if (srep * h + b > 0.f) {
          float w2 = wsm[O_W2 + j * 32 + t];
          uu += h * w2;
          ww += b * w2;
        }
      }
      wsm[O_U + r * 32 + t] = uu;
      wsm[O_WWR + r * 32 + t] = ww;
    }
  }
  for (int i = t; i < 66; i += blockDim.x) {
    float m0 = 0.f, m1 = 0.f;
    for (int k = 0; k < 32; k++) {
      float w1 = wsm[O_WE1 + i * 32 + k];
      m0 += w1 * wsm[O_WE2 + k * 2 + 0];
      m1 += w1 * wsm[O_WE2 + k * 2 + 1];
    }
    wsm[O_M + i * 2 + 0] = m0;
    wsm[O_M + i * 2 + 1] = m1;
  }
  if (t == 0) {
    float b20 = wsm[O_BE2 + 0], b21 = wsm[O_BE2 + 1];
    for (int k = 0; k < 32; k++) {
      b20 += wsm[O_BE1 + k] * wsm[O_WE2 + k * 2 + 0];
      b21 += wsm[O_BE1 + k] * wsm[O_WE2 + k * 2 + 1];
    }
    wsm[O_BIAS2 + 0] = b20;
    wsm[O_BIAS2 + 1] = b21;
  }
}

// --- bucket radix partition (atomic-free globally) -------------------------
__global__ __launch_bounds__(1024) void k_hist(const int* __restrict__ dst,
                                               int* __restrict__ counts,
                                               int E, int chunk) {
  __shared__ int h[KB];
  for (int i = threadIdx.x; i < KB; i += blockDim.x) h[i] = 0;
  __syncthreads();
  int b = blockIdx.x;
  int start = b * chunk, end = min(E, start + chunk);
  int tid = threadIdx.x, BD = blockDim.x;
  for (int base = start; base < end; base += BD * 4) {
#pragma unroll
    for (int u = 0; u < 4; u++) {
      int idx = base + u * BD + tid;
      if (idx < end) atomicAdd(&h[dst[idx] >> 7], 1);
    }
  }
  __syncthreads();
  for (int i = threadIdx.x; i < KB; i += blockDim.x)
    counts[i * FBC + b] = h[i];
}

__global__ __launch_bounds__(FBC) void k_scanA(int* __restrict__ counts,
                                               int* __restrict__ totals) {
  __shared__ int s[FBC];
  int k = blockIdx.x, t = threadIdx.x;
  int v = counts[k * FBC + t];
  s[t] = v;
  __syncthreads();
  for (int off = 1; off < FBC; off <<= 1) {
    int add = (t >= off) ? s[t - off] : 0;
    __syncthreads();
    s[t] += add;
    __syncthreads();
  }
  counts[k * FBC + t] = s[t] - v;          // exclusive within bucket
  if (t == FBC - 1) totals[k] = s[t];
}

__global__ __launch_bounds__(1024) void k_scanB(const int* __restrict__ totals,
                                                int* __restrict__ bases) {
  __shared__ int s[1024];
  int t = threadIdx.x;
  int v = (t < KB) ? totals[t] : 0;
  s[t] = v;
  __syncthreads();
  for (int off = 1; off < 1024; off <<= 1) {
    int add = (t >= off) ? s[t - off] : 0;
    __syncthreads();
    s[t] += add;
    __syncthreads();
  }
  if (t < KB) bases[t] = s[t] - v;
  if (t == KB - 1) bases[KB] = s[t];
}

// in-LDS counting sort per chunk; flush = per-bucket contiguous runs
__global__ __launch_bounds__(1024) void k_fillsort(const int* __restrict__ src,
                                                   const int* __restrict__ dst,
                                                   const int* __restrict__ counts,
                                                   const int* __restrict__ bases,
                                                   unsigned int* __restrict__ recs,
                                                   int E, int chunk) {
  __shared__ unsigned int staged[STCAP];
  __shared__ int cnt[KB], r0o[KB + 1], r0c[KB], tgt[KB];
  int b = blockIdx.x;
  int tid = threadIdx.x, BD = blockDim.x;
  for (int i = tid; i < KB; i += BD)
    tgt[i] = bases[i] + counts[i * FBC + b];
  int start = b * chunk, end = min(E, start + chunk);
  for (int rs = start; rs < end; rs += STCAP) {
    int rn = min(STCAP, end - rs);
    for (int i = tid; i < KB; i += BD) cnt[i] = 0;
    __syncthreads();
    for (int base = 0; base < rn; base += BD * 4) {
#pragma unroll
      for (int u = 0; u < 4; u++) {
        int idx = base + u * BD + tid;
        if (idx < rn) atomicAdd(&cnt[dst[rs + idx] >> 7], 1);
      }
    }
    __syncthreads();
    if (tid < KB) r0o[tid] = cnt[tid];
    __syncthreads();
    for (int off = 1; off < KB; off <<= 1) {
      int add = 0;
      if (tid < KB && tid >= off) add = r0o[tid - off];
      __syncthreads();
      if (tid < KB) r0o[tid] += add;
      __syncthreads();
    }
    if (tid < KB) r0c[tid] = r0o[tid] - cnt[tid];   // exclusive
    __syncthreads();
    if (tid < KB) r0o[tid] = r0c[tid];
    if (tid == 0) r0o[KB] = rn;
    __syncthreads();
    for (int base = 0; base < rn; base += BD * 4) {
#pragma unroll
      for (int u = 0; u < 4; u++) {
        int idx = base + u * BD + tid;
        if (idx < rn) {
          int d = dst[rs + idx];
          int s = src[rs + idx];
          int pos = atomicAdd(&r0c[d >> 7], 1);
          staged[pos] = ((unsigned int)s << 7) | (unsigned int)(d & 127);
        }
      }
    }
    __syncthreads();
    for (int t = tid; t < rn; t += BD) {
      unsigned int rec = staged[t];
      int lo = 0, hi = KB;
      while (hi - lo > 1) {
        int mid = (lo + hi) >> 1;
        if (r0o[mid] <= t) lo = mid; else hi = mid;
      }
      recs[tgt[lo] + (t - r0o[lo])] = rec;
    }
    __syncthreads();
    if (tid < KB) tgt[tid] += cnt[tid];
    __syncthreads();
  }
}

// --- per-bucket grouping by node -> CSR + deg/dinv -------------------------
__global__ __launch_bounds__(1024) void k_group(const unsigned int* __restrict__ recs,
                                                const int* __restrict__ bases,
                                                unsigned int* __restrict__ recs2,
                                                int* __restrict__ rowstart,
                                                float* __restrict__ dinv, int N) {
  __shared__ int cnt[128], startv[129], cur[128];
  int k = blockIdx.x;
  int tid = threadIdx.x, BD = blockDim.x;
  if (tid < 128) cnt[tid] = 0;
  __syncthreads();
  int s0 = bases[k], n = bases[k + 1] - s0;
  const unsigned int* rp = recs + s0;
  for (int base = 0; base < n; base += BD * 4) {
#pragma unroll
    for (int u = 0; u < 4; u++) {
      int idx = base + u * BD + tid;
      if (idx < n) atomicAdd(&cnt[rp[idx] & 127u], 1);
    }
  }
  __syncthreads();
  if (tid == 0) {
    int acc = 0;
    for (int i = 0; i < 128; i++) { startv[i] = acc; acc += cnt[i]; }
    startv[128] = acc;
  }
  __syncthreads();
  if (tid < 128) cur[tid] = startv[tid];
  __syncthreads();
  for (int base = 0; base < n; base += BD * 4) {
#pragma unroll
    for (int u = 0; u < 4; u++) {
      int idx = base + u * BD + tid;
      if (idx < n) {
        unsigned int r = rp[idx];
        int pos = atomicAdd(&cur[r & 127u], 1);
        recs2[s0 + pos] = r >> 7;            // src id, grouped by dst node
      }
    }
  }
  if (tid < 129) {
    int v = k * 128 + tid;
    if (v < N && tid < 128) {
      rowstart[v] = s0 + startv[tid];
      dinv[v] = rsqrtf((float)cnt[tid] + 1.0f);
    }
    if (v == N) rowstart[N] = s0 + startv[tid];
  }
}

// --- per-node: run-sum dinv[src] -> s, region -> g1[N][32] -----------------
__global__ __launch_bounds__(256) void k_sA2(const float* __restrict__ wsm,
                                             const unsigned int* __restrict__ recs2,
                                             const int* __restrict__ rowstart,
                                             const float* __restrict__ dinv,
                                             float* __restrict__ g1, int N) {
  __shared__ float sU[NREG * 32], sW[NREG * 32], ts[16];
  __shared__ int nt;
  for (int i = threadIdx.x; i < NREG * 32; i += blockDim.x) {
    sU[i] = wsm[O_U + i];
    sW[i] = wsm[O_WWR + i];
  }
  if (threadIdx.x == 0) nt = (int)wsm[O_NT];
  if (threadIdx.x < 16) ts[threadIdx.x] = wsm[O_TS + threadIdx.x];
  __syncthreads();
  int v = blockIdx.x * blockDim.x + threadIdx.x;
  if (v >= N) return;
  int r0 = rowstart[v], r1 = rowstart[v + 1];
  float sacc = 0.f;
  int i = r0;
  for (; i + 4 <= r1; i += 4) {
    unsigned int a0 = recs2[i], a1 = recs2[i + 1], a2 = recs2[i + 2], a3 = recs2[i + 3];
    float d0 = dinv[a0], d1 = dinv[a1], d2 = dinv[a2], d3 = dinv[a3];
    sacc += (d0 + d1) + (d2 + d3);
  }
  for (; i < r1; i++) sacc += dinv[recs2[i]];
  float dv = dinv[v];
  float s = dv * (sacc + dv);
  int rr = 0;
  for (int t = 0; t < nt; t++) rr += (ts[t] < s) ? 1 : 0;
  float alpha = dv * s, beta = dv;
  float4* gp = (float4*)&g1[(size_t)v * 32];
#pragma unroll
  for (int q = 0; q < 8; q++) {
    float4 o;
    float* op = (float*)&o;
#pragma unroll
    for (int j = 0; j < 4; j++) {
      int jj = q * 4 + j;
      op[j] = alpha * sU[rr * 32 + jj] + beta * sW[rr * 32 + jj];
    }
    gp[q] = o;
  }
}

// --- wave per node: coalesced g1 run reduction + fused node MLP ------------
__global__ __launch_bounds__(256) void k_AB3(const float* __restrict__ wsm,
                                             const unsigned int* __restrict__ recs2,
                                             const int* __restrict__ rowstart,
                                             const float* __restrict__ dinv,
                                             const float* __restrict__ g1,
                                             float4* __restrict__ pspd, int N) {
  __shared__ float sWn[1024], sB2[32], sBn[32], sM[132];
  for (int i = threadIdx.x; i < 1024; i += blockDim.x) sWn[i] = wsm[O_WN + i];
  if (threadIdx.x < 32) {
    sB2[threadIdx.x] = wsm[O_B2C + threadIdx.x];
    sBn[threadIdx.x] = wsm[O_BN + threadIdx.x];
  }
  for (int i = threadIdx.x; i < 132; i += blockDim.x) sM[i] = wsm[O_M + i];
  __syncthreads();
  int wid = (int)((blockIdx.x * blockDim.x + threadIdx.x) >> 6);
  int lane = threadIdx.x & 63;
  if (wid >= N) return;
  int v = wid;
  int r0 = rowstart[v], r1 = rowstart[v + 1];
  int j = lane & 31, half = lane >> 5;
  float acc = 0.f;
  int m = r1 - r0;
  for (int base = 0; base < m; base += 64) {
    int rem = m - base; if (rem > 64) rem = 64;
    unsigned int myrec = (lane < rem) ? recs2[r0 + base + lane] : 0u;
#pragma unroll 4
    for (int t = half; t < rem; t += 2) {
      unsigned int s = __shfl(myrec, t);
      acc += g1[(size_t)s * 32 + j];
    }
  }
  acc += __shfl_xor(acc, 32);                       // combine half-waves
  float dv = dinv[v];
  float x2 = relu_(dv * (acc + g1[(size_t)v * 32 + j]) + sB2[j]);
  float a = sBn[j];
#pragma unroll
  for (int kk = 0; kk < 32; kk++) {
    float xk = __shfl(x2, kk);
    a += xk * sWn[kk * 32 + j];
  }
  float x3 = relu_(a);
  float p0 = x3 * sM[(2 + j) * 2 + 0];
  float p1 = x3 * sM[(2 + j) * 2 + 1];
  float p2 = x3 * sM[(34 + j) * 2 + 0];
  float p3 = x3 * sM[(34 + j) * 2 + 1];
#pragma unroll
  for (int off = 16; off >= 1; off >>= 1) {
    p0 += __shfl_xor(p0, off);
    p1 += __shfl_xor(p1, off);
    p2 += __shfl_xor(p2, off);
    p3 += __shfl_xor(p3, off);
  }
  if (lane == 0) pspd[v] = make_float4(p0, p1, p2, p3);
}

#define UE 4
__global__ __launch_bounds__(256) void k_edge(const float* __restrict__ wsm,
                                              const int* __restrict__ src,
                                              const int* __restrict__ dst,
                                              const void* __restrict__ ewraw,
                                              const void* __restrict__ ceraw,
                                              const float4* __restrict__ pspd,
                                              void* __restrict__ out,
                                              const int* __restrict__ mode, int E) {
  int e0 = (blockIdx.x * blockDim.x + threadIdx.x) * UE;
  bool bf = (*mode) != 0;
  float b0 = wsm[O_BIAS2 + 0], b1 = wsm[O_BIAS2 + 1];
  float M00 = wsm[O_M + 0], M01 = wsm[O_M + 1];
  float M10 = wsm[O_M + 2], M11 = wsm[O_M + 3];
  if (e0 + UE <= E) {
    int s[UE], d[UE];
#pragma unroll
    for (int u = 0; u < UE; u++) { s[u] = src[e0 + u]; d[u] = dst[e0 + u]; }
    float4 s4[UE], d4[UE];
#pragma unroll
    for (int u = 0; u < UE; u++) s4[u] = pspd[s[u]];
#pragma unroll
    for (int u = 0; u < UE; u++) d4[u] = pspd[d[u]];
#pragma unroll
    for (int u = 0; u < UE; u++) {
      int e = e0 + u;
      float ew = bf ? bf2f(((const unsigned short*)ewraw)[e]) : ((const float*)ewraw)[e];
      float ce = bf ? bf2f(((const unsigned short*)ceraw)[e]) : ((const float*)ceraw)[e];
      float o0 = b0 + ew * M00 + ce * M10 + s4[u].x + d4[u].z;
      float o1 = b1 + ew * M01 + ce * M11 + s4[u].y + d4[u].w;
      if (bf) {
        unsigned int pk = ((unsigned int)f2bf(o1) << 16) | (unsigned int)f2bf(o0);
        ((unsigned int*)out)[e] = pk;
      } else {
        float2 r; r.x = o0; r.y = o1;
        ((float2*)out)[e] = r;
      }
    }
  } else {
    for (int e = e0; e < E; e++) {
      float ew = bf ? bf2f(((const unsigned short*)ewraw)[e]) : ((const float*)ewraw)[e];
      float ce = bf ? bf2f(((const unsigned short*)ceraw)[e]) : ((const float*)ceraw)[e];
      float4 s4 = pspd[src[e]];
      float4 d4 = pspd[dst[e]];
      float o0 = b0 + ew * M00 + ce * M10 + s4.x + d4.z;
      float o1 = b1 + ew * M01 + ce * M11 + s4.y + d4.w;
      if (bf) {
        unsigned int pk = ((unsigned int)f2bf(o1) << 16) | (unsigned int)f2bf(o0);
        ((unsigned int*)out)[e] = pk;
      } else {
        float2 r; r.x = o0; r.y = o1;
        ((float2*)out)[e] = r;
      }
    }
  }
}

extern "C" void kernel_launch(void* const* d_in, const int* in_sizes, int n_in,
                              void* d_out, int out_size, void* d_ws, size_t ws_size,
                              hipStream_t stream) {
  const int* eidx = (const int*)d_in[0];
  const int E = in_sizes[0] / 2;
  const int N = NNODES;
  const int* src = eidx;
  const int* dst = eidx + E;
  const int chunk = (E + FBC - 1) / FBC;

  char* ws = (char*)d_ws;
  size_t off = 0;
  size_t off_mode = off; off += 256;
  size_t off_wsm  = off; off += (size_t)WSM_TOTAL * 4;
  off = (off + 255) & ~(size_t)255;
  size_t off_cnts = off; off += (size_t)KB * FBC * 4;
  size_t off_tot  = off; off += (size_t)KB * 4;
  off = (off + 255) & ~(size_t)255;
  size_t off_base = off; off += (size_t)(KB + 1) * 4;
  off = (off + 255) & ~(size_t)255;
  size_t off_recs = off; off += (size_t)E * 4;
  size_t off_rec2 = off; off += (size_t)E * 4;
  size_t off_row  = off; off += (size_t)(N + 1) * 4;
  size_t off_dinv = off; off += (size_t)N * 4;
  off = (off + 255) & ~(size_t)255;
  size_t off_g1   = off; off += (size_t)N * 32 * 4;
  size_t off_pspd = off; off += (size_t)N * 16;
  if (ws_size < off) return;

  int*          mode   = (int*)(ws + off_mode);
  float*        wsm    = (float*)(ws + off_wsm);
  int*          counts = (int*)(ws + off_cnts);
  int*          totals = (int*)(ws + off_tot);
  int*          bases  = (int*)(ws + off_base);
  unsigned int* recs   = (unsigned int*)(ws + off_recs);
  unsigned int* recs2  = (unsigned int*)(ws + off_rec2);
  int*          rowst  = (int*)(ws + off_row);
  float*        dinv   = (float*)(ws + off_dinv);
  float*        g1     = (float*)(ws + off_g1);
  float4*       pspd   = (float4*)(ws + off_pspd);

  k_detect<<<1, 256, 0, stream>>>((const unsigned short*)d_in[1], mode);
  k_convert_small<<<(WSM_N + 255) / 256, 256, 0, stream>>>(
      d_in[4], d_in[5], d_in[6], d_in[7], d_in[8], d_in[9], d_in[10], d_in[11],
      d_in[12], d_in[13], d_in[14], d_in[15], mode, wsm);
  k_prep<<<1, 64, 0, stream>>>(wsm);
  k_hist<<<FBC, 1024, 0, stream>>>(dst, counts, E, chunk);
  k_scanA<<<KB, FBC, 0, stream>>>(counts, totals);
  k_scanB<<<1, 1024, 0, stream>>>(totals, bases);
  k_fillsort<<<FBC, 1024, 0, stream>>>(src, dst, counts, bases, recs, E, chunk);
  k_group<<<KB, 1024, 0, stream>>>(recs, bases, recs2, rowst, dinv, N);
  k_sA2<<<(N + 255) / 256, 256, 0, stream>>>(wsm, recs2, rowst, dinv, g1, N);
  {
    long long waves = (long long)N;             // one wave per node
    int blocks = (int)((waves * 64 + 255) / 256);
    k_AB3<<<blocks, 256, 0, stream>>>(wsm, recs2, rowst, dinv, g1, pspd, N);
  }
  {
    long long tot = ((long long)E + UE - 1) / UE;
    int blocks = (int)((tot + 255) / 256);
    k_edge<<<blocks, 256, 0, stream>>>(wsm, src, dst, d_in[1], d_in[2],
                                       pspd, d_out, mode, E);
  }
}

// Round 9
// 290.078 us; speedup vs baseline: 1.0079x; 1.0079x over previous
//
#include <hip/hip_runtime.h>
#include <hip/hip_bf16.h>

// ---------------------------------------------------------------------------
// KEPCE_GCN, round 9 = round 8 CSR structure, but AB3 gathers 16B rec4
// (1.6MB, L2-resident) and reconstructs the 32-vector from the rank-2
// region basis (sU/sW in LDS) in-register. No g1 table (R8's 12.8MB
// L2-thrashing gather payload removed).
// ---------------------------------------------------------------------------

#define NNODES 100000
#define NREG   17
#define KB     782          // buckets = ceil(100000/128)
#define FBC    256          // fill/hist chunk blocks
#define STCAP  12544        // LDS staging capacity (>= chunk)

// wsm element offsets (f32)
#define O_W0    0
#define O_B0    8
#define O_W1    16
#define O_B1    144
#define O_W2    160
#define O_B2C   672
#define O_WN    704
#define O_BN    1728
#define O_WE1   1760
#define O_BE1   3872
#define O_WE2   3904
#define O_BE2   3968
#define WSM_N   3970
#define O_H0    3972
#define O_TS    3992
#define O_NT    4008
#define O_U     4016   // 17*32
#define O_WWR   4560   // 17*32
#define O_M     5104   // 66*2
#define O_BIAS2 5236
#define WSM_TOTAL 6144

__device__ __forceinline__ float bf2f(unsigned short u) {
  union { float f; unsigned int i; } v; v.i = ((unsigned int)u) << 16; return v.f;
}
__device__ __forceinline__ unsigned short f2bf(float f) {
  union { float f; unsigned int i; } v; v.f = f;
  unsigned int x = v.i;
  return (unsigned short)((x + 0x7FFFu + ((x >> 16) & 1u)) >> 16);
}
__device__ __forceinline__ float relu_(float x) { return x > 0.f ? x : 0.f; }

__global__ __launch_bounds__(256) void k_detect(const unsigned short* ew, int* mode) {
  __shared__ int cnt;
  if (threadIdx.x == 0) cnt = 0;
  __syncthreads();
  int ok = 0;
  for (int i = threadIdx.x; i < 512; i += blockDim.x) {
    unsigned short h = ew[i];
    int e = (h >> 7) & 0xFF;
    if (!(h & 0x8000) && e >= 0x70 && e <= 0x7E) ok++;
  }
  atomicAdd(&cnt, ok);
  __syncthreads();
  if (threadIdx.x == 0) *mode = (cnt >= 400) ? 1 : 0;  // 1 = bf16
}

__global__ __launch_bounds__(256) void k_convert_small(
    const void* p0, const void* p1, const void* p2, const void* p3,
    const void* p4, const void* p5, const void* p6, const void* p7,
    const void* p8, const void* p9, const void* p10, const void* p11,
    const int* mode, float* wsm) {
  int idx = blockIdx.x * blockDim.x + threadIdx.x;
  if (idx >= WSM_N) return;
  const void* ptrs[12] = {p0,p1,p2,p3,p4,p5,p6,p7,p8,p9,p10,p11};
  const int offs[13] = {O_W0,O_B0,O_W1,O_B1,O_W2,O_B2C,O_WN,O_BN,O_WE1,O_BE1,O_WE2,O_BE2,WSM_N};
  int seg = 0;
  while (idx >= offs[seg + 1]) seg++;
  int k = idx - offs[seg];
  wsm[idx] = (*mode) ? bf2f(((const unsigned short*)ptrs[seg])[k])
                     : ((const float*)ptrs[seg])[k];
}

__global__ __launch_bounds__(64) void k_prep(float* wsm) {
  __shared__ float h0[16], ts[16];
  __shared__ int snt;
  int t = threadIdx.x;
  if (t < 16) {
    float acc = 0.f;
    for (int j = 0; j < 8; j++)
      acc += (wsm[O_W0 + j] + wsm[O_B0 + j]) * wsm[O_W1 + j * 16 + t];
    h0[t] = acc;
    wsm[O_H0 + t] = acc;
  }
  __syncthreads();
  if (t == 0) {
    int n = 0;
    for (int j = 0; j < 16; j++) {
      float h = h0[j], b = wsm[O_B1 + j];
      if (h != 0.f) {
        float tj = -b / h;
        if (tj > 0.f) {
          int p = n++;
          while (p > 0 && ts[p - 1] > tj) { ts[p] = ts[p - 1]; p--; }
          ts[p] = tj;
        }
      }
    }
    snt = n;
    wsm[O_NT] = (float)n;
    for (int i = 0; i < n; i++) wsm[O_TS + i] = ts[i];
  }
  __syncthreads();
  int n = snt;
  for (int r = 0; r <= n; r++) {
    float srep;
    if (n == 0) srep = 1.f;
    else if (r == 0) srep = ts[0] * 0.5f;
    else if (r == n) srep = ts[n - 1] * 2.f + 1.f;
    else srep = 0.5f * (ts[r - 1] + ts[r]);
    if (t < 32) {
      float uu = 0.f, ww = 0.f;
      for (int j = 0; j < 16; j++) {
        float h = h0[j], b = wsm[O_B1 + j];
        if (srep * h + b > 0.f) {
          float w2 = wsm[O_W2 + j * 32 + t];
          uu += h * w2;
          ww += b * w2;
        }
      }
      wsm[O_U + r * 32 + t] = uu;
      wsm[O_WWR + r * 32 + t] = ww;
    }
  }
  for (int i = t; i < 66; i += blockDim.x) {
    float m0 = 0.f, m1 = 0.f;
    for (int k = 0; k < 32; k++) {
      float w1 = wsm[O_WE1 + i * 32 + k];
      m0 += w1 * wsm[O_WE2 + k * 2 + 0];
      m1 += w1 * wsm[O_WE2 + k * 2 + 1];
    }
    wsm[O_M + i * 2 + 0] = m0;
    wsm[O_M + i * 2 + 1] = m1;
  }
  if (t == 0) {
    float b20 = wsm[O_BE2 + 0], b21 = wsm[O_BE2 + 1];
    for (int k = 0; k < 32; k++) {
      b20 += wsm[O_BE1 + k] * wsm[O_WE2 + k * 2 + 0];
      b21 += wsm[O_BE1 + k] * wsm[O_WE2 + k * 2 + 1];
    }
    wsm[O_BIAS2 + 0] = b20;
    wsm[O_BIAS2 + 1] = b21;
  }
}

// --- bucket radix partition (atomic-free globally) -------------------------
__global__ __launch_bounds__(1024) void k_hist(const int* __restrict__ dst,
                                               int* __restrict__ counts,
                                               int E, int chunk) {
  __shared__ int h[KB];
  for (int i = threadIdx.x; i < KB; i += blockDim.x) h[i] = 0;
  __syncthreads();
  int b = blockIdx.x;
  int start = b * chunk, end = min(E, start + chunk);
  int tid = threadIdx.x, BD = blockDim.x;
  for (int base = start; base < end; base += BD * 4) {
#pragma unroll
    for (int u = 0; u < 4; u++) {
      int idx = base + u * BD + tid;
      if (idx < end) atomicAdd(&h[dst[idx] >> 7], 1);
    }
  }
  __syncthreads();
  for (int i = threadIdx.x; i < KB; i += blockDim.x)
    counts[i * FBC + b] = h[i];
}

__global__ __launch_bounds__(FBC) void k_scanA(int* __restrict__ counts,
                                               int* __restrict__ totals) {
  __shared__ int s[FBC];
  int k = blockIdx.x, t = threadIdx.x;
  int v = counts[k * FBC + t];
  s[t] = v;
  __syncthreads();
  for (int off = 1; off < FBC; off <<= 1) {
    int add = (t >= off) ? s[t - off] : 0;
    __syncthreads();
    s[t] += add;
    __syncthreads();
  }
  counts[k * FBC + t] = s[t] - v;          // exclusive within bucket
  if (t == FBC - 1) totals[k] = s[t];
}

__global__ __launch_bounds__(1024) void k_scanB(const int* __restrict__ totals,
                                                int* __restrict__ bases) {
  __shared__ int s[1024];
  int t = threadIdx.x;
  int v = (t < KB) ? totals[t] : 0;
  s[t] = v;
  __syncthreads();
  for (int off = 1; off < 1024; off <<= 1) {
    int add = (t >= off) ? s[t - off] : 0;
    __syncthreads();
    s[t] += add;
    __syncthreads();
  }
  if (t < KB) bases[t] = s[t] - v;
  if (t == KB - 1) bases[KB] = s[t];
}

// in-LDS counting sort per chunk; flush = per-bucket contiguous runs
__global__ __launch_bounds__(1024) void k_fillsort(const int* __restrict__ src,
                                                   const int* __restrict__ dst,
                                                   const int* __restrict__ counts,
                                                   const int* __restrict__ bases,
                                                   unsigned int* __restrict__ recs,
                                                   int E, int chunk) {
  __shared__ unsigned int staged[STCAP];
  __shared__ int cnt[KB], r0o[KB + 1], r0c[KB], tgt[KB];
  int b = blockIdx.x;
  int tid = threadIdx.x, BD = blockDim.x;
  for (int i = tid; i < KB; i += BD)
    tgt[i] = bases[i] + counts[i * FBC + b];
  int start = b * chunk, end = min(E, start + chunk);
  for (int rs = start; rs < end; rs += STCAP) {
    int rn = min(STCAP, end - rs);
    for (int i = tid; i < KB; i += BD) cnt[i] = 0;
    __syncthreads();
    for (int base = 0; base < rn; base += BD * 4) {
#pragma unroll
      for (int u = 0; u < 4; u++) {
        int idx = base + u * BD + tid;
        if (idx < rn) atomicAdd(&cnt[dst[rs + idx] >> 7], 1);
      }
    }
    __syncthreads();
    if (tid < KB) r0o[tid] = cnt[tid];
    __syncthreads();
    for (int off = 1; off < KB; off <<= 1) {
      int add = 0;
      if (tid < KB && tid >= off) add = r0o[tid - off];
      __syncthreads();
      if (tid < KB) r0o[tid] += add;
      __syncthreads();
    }
    if (tid < KB) r0c[tid] = r0o[tid] - cnt[tid];   // exclusive
    __syncthreads();
    if (tid < KB) r0o[tid] = r0c[tid];
    if (tid == 0) r0o[KB] = rn;
    __syncthreads();
    for (int base = 0; base < rn; base += BD * 4) {
#pragma unroll
      for (int u = 0; u < 4; u++) {
        int idx = base + u * BD + tid;
        if (idx < rn) {
          int d = dst[rs + idx];
          int s = src[rs + idx];
          int pos = atomicAdd(&r0c[d >> 7], 1);
          staged[pos] = ((unsigned int)s << 7) | (unsigned int)(d & 127);
        }
      }
    }
    __syncthreads();
    for (int t = tid; t < rn; t += BD) {
      unsigned int rec = staged[t];
      int lo = 0, hi = KB;
      while (hi - lo > 1) {
        int mid = (lo + hi) >> 1;
        if (r0o[mid] <= t) lo = mid; else hi = mid;
      }
      recs[tgt[lo] + (t - r0o[lo])] = rec;
    }
    __syncthreads();
    if (tid < KB) tgt[tid] += cnt[tid];
    __syncthreads();
  }
}

// --- per-bucket grouping by node -> CSR + deg/dinv -------------------------
__global__ __launch_bounds__(1024) void k_group(const unsigned int* __restrict__ recs,
                                                const int* __restrict__ bases,
                                                unsigned int* __restrict__ recs2,
                                                int* __restrict__ rowstart,
                                                float* __restrict__ dinv, int N) {
  __shared__ int cnt[128], startv[129], cur[128];
  int k = blockIdx.x;
  int tid = threadIdx.x, BD = blockDim.x;
  if (tid < 128) cnt[tid] = 0;
  __syncthreads();
  int s0 = bases[k], n = bases[k + 1] - s0;
  const unsigned int* rp = recs + s0;
  for (int base = 0; base < n; base += BD * 4) {
#pragma unroll
    for (int u = 0; u < 4; u++) {
      int idx = base + u * BD + tid;
      if (idx < n) atomicAdd(&cnt[rp[idx] & 127u], 1);
    }
  }
  __syncthreads();
  if (tid == 0) {
    int acc = 0;
    for (int i = 0; i < 128; i++) { startv[i] = acc; acc += cnt[i]; }
    startv[128] = acc;
  }
  __syncthreads();
  if (tid < 128) cur[tid] = startv[tid];
  __syncthreads();
  for (int base = 0; base < n; base += BD * 4) {
#pragma unroll
    for (int u = 0; u < 4; u++) {
      int idx = base + u * BD + tid;
      if (idx < n) {
        unsigned int r = rp[idx];
        int pos = atomicAdd(&cur[r & 127u], 1);
        recs2[s0 + pos] = r >> 7;            // src id, grouped by dst node
      }
    }
  }
  if (tid < 129) {
    int v = k * 128 + tid;
    if (v < N && tid < 128) {
      rowstart[v] = s0 + startv[tid];
      dinv[v] = rsqrtf((float)cnt[tid] + 1.0f);
    }
    if (v == N) rowstart[N] = s0 + startv[tid];
  }
}

// --- per-node: run-sum dinv[src] -> s, region -> rec4 ----------------------
__global__ __launch_bounds__(256) void k_sA2(const float* __restrict__ wsm,
                                             const unsigned int* __restrict__ recs2,
                                             const int* __restrict__ rowstart,
                                             const float* __restrict__ dinv,
                                             float4* __restrict__ rec4, int N) {
  __shared__ float ts[16];
  __shared__ int nt;
  if (threadIdx.x == 0) nt = (int)wsm[O_NT];
  if (threadIdx.x < 16) ts[threadIdx.x] = wsm[O_TS + threadIdx.x];
  __syncthreads();
  int v = blockIdx.x * blockDim.x + threadIdx.x;
  if (v >= N) return;
  int r0 = rowstart[v], r1 = rowstart[v + 1];
  float sacc = 0.f;
  int i = r0;
  for (; i + 4 <= r1; i += 4) {
    unsigned int a0 = recs2[i], a1 = recs2[i + 1], a2 = recs2[i + 2], a3 = recs2[i + 3];
    float d0 = dinv[a0], d1 = dinv[a1], d2 = dinv[a2], d3 = dinv[a3];
    sacc += (d0 + d1) + (d2 + d3);
  }
  for (; i < r1; i++) sacc += dinv[recs2[i]];
  float dv = dinv[v];
  float s = dv * (sacc + dv);
  int rr = 0;
  for (int t = 0; t < nt; t++) rr += (ts[t] < s) ? 1 : 0;
  rec4[v] = make_float4(dv * s, dv, __int_as_float(rr), 0.f);
}

// --- wave per node: 16B rec4 gathers + in-register rank-2 reconstruction ---
__global__ __launch_bounds__(256) void k_AB3(const float* __restrict__ wsm,
                                             const unsigned int* __restrict__ recs2,
                                             const int* __restrict__ rowstart,
                                             const float4* __restrict__ rec4,
                                             float4* __restrict__ pspd, int N) {
  __shared__ float sU[NREG * 32], sW[NREG * 32], sWn[1024], sB2[32], sBn[32], sM[132];
  for (int i = threadIdx.x; i < NREG * 32; i += blockDim.x) {
    sU[i] = wsm[O_U + i];
    sW[i] = wsm[O_WWR + i];
  }
  for (int i = threadIdx.x; i < 1024; i += blockDim.x) sWn[i] = wsm[O_WN + i];
  if (threadIdx.x < 32) {
    sB2[threadIdx.x] = wsm[O_B2C + threadIdx.x];
    sBn[threadIdx.x] = wsm[O_BN + threadIdx.x];
  }
  for (int i = threadIdx.x; i < 132; i += blockDim.x) sM[i] = wsm[O_M + i];
  __syncthreads();
  int wid = (int)((blockIdx.x * blockDim.x + threadIdx.x) >> 6);
  int lane = threadIdx.x & 63;
  if (wid >= N) return;
  int v = wid;
  int r0 = rowstart[v], r1 = rowstart[v + 1];
  int j = lane & 31, half = lane >> 5;
  float acc = 0.f;
  int m = r1 - r0;
  for (int base = 0; base < m; base += 64) {
    int rem = m - base; if (rem > 64) rem = 64;
    float4 myq = make_float4(0.f, 0.f, 0.f, 0.f);
    if (lane < rem) myq = rec4[recs2[r0 + base + lane]];
#pragma unroll 4
    for (int t = half; t < rem; t += 2) {
      float a = __shfl(myq.x, t);
      float b = __shfl(myq.y, t);
      int rr = __float_as_int(__shfl(myq.z, t));
      acc += a * sU[rr * 32 + j] + b * sW[rr * 32 + j];
    }
  }
  acc += __shfl_xor(acc, 32);                 // combine half-waves
  float4 self = rec4[v];
  int sr = __float_as_int(self.z);
  acc += self.x * sU[sr * 32 + j] + self.y * sW[sr * 32 + j];  // self-loop
  float dv = self.y;
  float x2 = relu_(dv * acc + sB2[j]);
  float a2 = sBn[j];
#pragma unroll
  for (int kk = 0; kk < 32; kk++) {
    float xk = __shfl(x2, kk);
    a2 += xk * sWn[kk * 32 + j];
  }
  float x3 = relu_(a2);
  float p0 = x3 * sM[(2 + j) * 2 + 0];
  float p1 = x3 * sM[(2 + j) * 2 + 1];
  float p2 = x3 * sM[(34 + j) * 2 + 0];
  float p3 = x3 * sM[(34 + j) * 2 + 1];
#pragma unroll
  for (int off = 16; off >= 1; off >>= 1) {
    p0 += __shfl_xor(p0, off);
    p1 += __shfl_xor(p1, off);
    p2 += __shfl_xor(p2, off);
    p3 += __shfl_xor(p3, off);
  }
  if (lane == 0) pspd[v] = make_float4(p0, p1, p2, p3);
}

#define UE 4
__global__ __launch_bounds__(256) void k_edge(const float* __restrict__ wsm,
                                              const int* __restrict__ src,
                                              const int* __restrict__ dst,
                                              const void* __restrict__ ewraw,
                                              const void* __restrict__ ceraw,
                                              const float4* __restrict__ pspd,
                                              void* __restrict__ out,
                                              const int* __restrict__ mode, int E) {
  int e0 = (blockIdx.x * blockDim.x + threadIdx.x) * UE;
  bool bf = (*mode) != 0;
  float b0 = wsm[O_BIAS2 + 0], b1 = wsm[O_BIAS2 + 1];
  float M00 = wsm[O_M + 0], M01 = wsm[O_M + 1];
  float M10 = wsm[O_M + 2], M11 = wsm[O_M + 3];
  if (e0 + UE <= E) {
    int s[UE], d[UE];
#pragma unroll
    for (int u = 0; u < UE; u++) { s[u] = src[e0 + u]; d[u] = dst[e0 + u]; }
    float4 s4[UE], d4[UE];
#pragma unroll
    for (int u = 0; u < UE; u++) s4[u] = pspd[s[u]];
#pragma unroll
    for (int u = 0; u < UE; u++) d4[u] = pspd[d[u]];
#pragma unroll
    for (int u = 0; u < UE; u++) {
      int e = e0 + u;
      float ew = bf ? bf2f(((const unsigned short*)ewraw)[e]) : ((const float*)ewraw)[e];
      float ce = bf ? bf2f(((const unsigned short*)ceraw)[e]) : ((const float*)ceraw)[e];
      float o0 = b0 + ew * M00 + ce * M10 + s4[u].x + d4[u].z;
      float o1 = b1 + ew * M01 + ce * M11 + s4[u].y + d4[u].w;
      if (bf) {
        unsigned int pk = ((unsigned int)f2bf(o1) << 16) | (unsigned int)f2bf(o0);
        ((unsigned int*)out)[e] = pk;
      } else {
        float2 r; r.x = o0; r.y = o1;
        ((float2*)out)[e] = r;
      }
    }
  } else {
    for (int e = e0; e < E; e++) {
      float ew = bf ? bf2f(((const unsigned short*)ewraw)[e]) : ((const float*)ewraw)[e];
      float ce = bf ? bf2f(((const unsigned short*)ceraw)[e]) : ((const float*)ceraw)[e];
      float4 s4 = pspd[src[e]];
      float4 d4 = pspd[dst[e]];
      float o0 = b0 + ew * M00 + ce * M10 + s4.x + d4.z;
      float o1 = b1 + ew * M01 + ce * M11 + s4.y + d4.w;
      if (bf) {
        unsigned int pk = ((unsigned int)f2bf(o1) << 16) | (unsigned int)f2bf(o0);
        ((unsigned int*)out)[e] = pk;
      } else {
        float2 r; r.x = o0; r.y = o1;
        ((float2*)out)[e] = r;
      }
    }
  }
}

extern "C" void kernel_launch(void* const* d_in, const int* in_sizes, int n_in,
                              void* d_out, int out_size, void* d_ws, size_t ws_size,
                              hipStream_t stream) {
  const int* eidx = (const int*)d_in[0];
  const int E = in_sizes[0] / 2;
  const int N = NNODES;
  const int* src = eidx;
  const int* dst = eidx + E;
  const int chunk = (E + FBC - 1) / FBC;

  char* ws = (char*)d_ws;
  size_t off = 0;
  size_t off_mode = off; off += 256;
  size_t off_wsm  = off; off += (size_t)WSM_TOTAL * 4;
  off = (off + 255) & ~(size_t)255;
  size_t off_cnts = off; off += (size_t)KB * FBC * 4;
  size_t off_tot  = off; off += (size_t)KB * 4;
  off = (off + 255) & ~(size_t)255;
  size_t off_base = off; off += (size_t)(KB + 1) * 4;
  off = (off + 255) & ~(size_t)255;
  size_t off_recs = off; off += (size_t)E * 4;
  size_t off_rec2 = off; off += (size_t)E * 4;
  size_t off_row  = off; off += (size_t)(N + 1) * 4;
  size_t off_dinv = off; off += (size_t)N * 4;
  off = (off + 255) & ~(size_t)255;
  size_t off_rec4 = off; off += (size_t)N * 16;
  size_t off_pspd = off; off += (size_t)N * 16;
  if (ws_size < off) return;

  int*          mode   = (int*)(ws + off_mode);
  float*        wsm    = (float*)(ws + off_wsm);
  int*          counts = (int*)(ws + off_cnts);
  int*          totals = (int*)(ws + off_tot);
  int*          bases  = (int*)(ws + off_base);
  unsigned int* recs   = (unsigned int*)(ws + off_recs);
  unsigned int* recs2  = (unsigned int*)(ws + off_rec2);
  int*          rowst  = (int*)(ws + off_row);
  float*        dinv   = (float*)(ws + off_dinv);
  float4*       rec4   = (float4*)(ws + off_rec4);
  float4*       pspd   = (float4*)(ws + off_pspd);

  k_detect<<<1, 256, 0, stream>>>((const unsigned short*)d_in[1], mode);
  k_convert_small<<<(WSM_N + 255) / 256, 256, 0, stream>>>(
      d_in[4], d_in[5], d_in[6], d_in[7], d_in[8], d_in[9], d_in[10], d_in[11],
      d_in[12], d_in[13], d_in[14], d_in[15], mode, wsm);
  k_prep<<<1, 64, 0, stream>>>(wsm);
  k_hist<<<FBC, 1024, 0, stream>>>(dst, counts, E, chunk);
  k_scanA<<<KB, FBC, 0, stream>>>(counts, totals);
  k_scanB<<<1, 1024, 0, stream>>>(totals, bases);
  k_fillsort<<<FBC, 1024, 0, stream>>>(src, dst, counts, bases, recs, E, chunk);
  k_group<<<KB, 1024, 0, stream>>>(recs, bases, recs2, rowst, dinv, N);
  k_sA2<<<(N + 255) / 256, 256, 0, stream>>>(wsm, recs2, rowst, dinv, rec4, N);
  {
    long long waves = (long long)N;             // one wave per node
    int blocks = (int)((waves * 64 + 255) / 256);
    k_AB3<<<blocks, 256, 0, stream>>>(wsm, recs2, rowst, rec4, pspd, N);
  }
  {
    long long tot = ((long long)E + UE - 1) / UE;
    int blocks = (int)((tot + 255) / 256);
    k_edge<<<blocks, 256, 0, stream>>>(wsm, src, dst, d_in[1], d_in[2],
                                       pspd, d_out, mode, E);
  }
}

// Round 10
// 246.680 us; speedup vs baseline: 1.1852x; 1.1759x over previous
//
#include <hip/hip_runtime.h>
#include <hip/hip_bf16.h>

// ---------------------------------------------------------------------------
// KEPCE_GCN, round 10: R7 accumulate structure, repaired.
//  - k_ABfused = k_ABacc + k_node2 fused (no ABg roundtrip), 512thr,
//    8-deep gather unroll (R7 was rec4-gather latency-bound at 4-deep).
//  - k_fillsort: flush binary-search once per 4-elem quad (was per elem).
//  - k_sA / k_degdinv: unroll 8. k_edge: UE=8 + vector loads.
//  - No k_group/recs2 (R9's shuffle AB3 was DS-pipe bound; reverted).
// ---------------------------------------------------------------------------

#define NNODES 100000
#define NREG   17
#define KB     782          // buckets = ceil(100000/128)
#define FBC    256          // fill/hist chunk blocks
#define STCAP  12544        // LDS staging capacity (>= chunk)
#define LSTR   37           // LDS row stride for AB planes

// wsm element offsets (f32)
#define O_W0    0
#define O_B0    8
#define O_W1    16
#define O_B1    144
#define O_W2    160
#define O_B2C   672
#define O_WN    704
#define O_BN    1728
#define O_WE1   1760
#define O_BE1   3872
#define O_WE2   3904
#define O_BE2   3968
#define WSM_N   3970
#define O_H0    3972
#define O_TS    3992
#define O_NT    4008
#define O_U     4016   // 17*32
#define O_WWR   4560   // 17*32
#define O_M     5104   // 66*2
#define O_BIAS2 5236
#define WSM_TOTAL 6144

__device__ __forceinline__ float bf2f(unsigned short u) {
  union { float f; unsigned int i; } v; v.i = ((unsigned int)u) << 16; return v.f;
}
__device__ __forceinline__ unsigned short f2bf(float f) {
  union { float f; unsigned int i; } v; v.f = f;
  unsigned int x = v.i;
  return (unsigned short)((x + 0x7FFFu + ((x >> 16) & 1u)) >> 16);
}
__device__ __forceinline__ float relu_(float x) { return x > 0.f ? x : 0.f; }

__global__ __launch_bounds__(256) void k_detect(const unsigned short* ew, int* mode) {
  __shared__ int cnt;
  if (threadIdx.x == 0) cnt = 0;
  __syncthreads();
  int ok = 0;
  for (int i = threadIdx.x; i < 512; i += blockDim.x) {
    unsigned short h = ew[i];
    int e = (h >> 7) & 0xFF;
    if (!(h & 0x8000) && e >= 0x70 && e <= 0x7E) ok++;
  }
  atomicAdd(&cnt, ok);
  __syncthreads();
  if (threadIdx.x == 0) *mode = (cnt >= 400) ? 1 : 0;  // 1 = bf16
}

__global__ __launch_bounds__(256) void k_convert_small(
    const void* p0, const void* p1, const void* p2, const void* p3,
    const void* p4, const void* p5, const void* p6, const void* p7,
    const void* p8, const void* p9, const void* p10, const void* p11,
    const int* mode, float* wsm) {
  int idx = blockIdx.x * blockDim.x + threadIdx.x;
  if (idx >= WSM_N) return;
  const void* ptrs[12] = {p0,p1,p2,p3,p4,p5,p6,p7,p8,p9,p10,p11};
  const int offs[13] = {O_W0,O_B0,O_W1,O_B1,O_W2,O_B2C,O_WN,O_BN,O_WE1,O_BE1,O_WE2,O_BE2,WSM_N};
  int seg = 0;
  while (idx >= offs[seg + 1]) seg++;
  int k = idx - offs[seg];
  wsm[idx] = (*mode) ? bf2f(((const unsigned short*)ptrs[seg])[k])
                     : ((const float*)ptrs[seg])[k];
}

__global__ __launch_bounds__(64) void k_prep(float* wsm) {
  __shared__ float h0[16], ts[16];
  __shared__ int snt;
  int t = threadIdx.x;
  if (t < 16) {
    float acc = 0.f;
    for (int j = 0; j < 8; j++)
      acc += (wsm[O_W0 + j] + wsm[O_B0 + j]) * wsm[O_W1 + j * 16 + t];
    h0[t] = acc;
    wsm[O_H0 + t] = acc;
  }
  __syncthreads();
  if (t == 0) {
    int n = 0;
    for (int j = 0; j < 16; j++) {
      float h = h0[j], b = wsm[O_B1 + j];
      if (h != 0.f) {
        float tj = -b / h;
        if (tj > 0.f) {
          int p = n++;
          while (p > 0 && ts[p - 1] > tj) { ts[p] = ts[p - 1]; p--; }
          ts[p] = tj;
        }
      }
    }
    snt = n;
    wsm[O_NT] = (float)n;
    for (int i = 0; i < n; i++) wsm[O_TS + i] = ts[i];
  }
  __syncthreads();
  int n = snt;
  for (int r = 0; r <= n; r++) {
    float srep;
    if (n == 0) srep = 1.f;
    else if (r == 0) srep = ts[0] * 0.5f;
    else if (r == n) srep = ts[n - 1] * 2.f + 1.f;
    else srep = 0.5f * (ts[r - 1] + ts[r]);
    if (t < 32) {
      float uu = 0.f, ww = 0.f;
      for (int j = 0; j < 16; j++) {
        float h = h0[j], b = wsm[O_B1 + j];
        if (srep * h + b > 0.f) {
          float w2 = wsm[O_W2 + j * 32 + t];
          uu += h * w2;
          ww += b * w2;
        }
      }
      wsm[O_U + r * 32 + t] = uu;
      wsm[O_WWR + r * 32 + t] = ww;
    }
  }
  for (int i = t; i < 66; i += blockDim.x) {
    float m0 = 0.f, m1 = 0.f;
    for (int k = 0; k < 32; k++) {
      float w1 = wsm[O_WE1 + i * 32 + k];
      m0 += w1 * wsm[O_WE2 + k * 2 + 0];
      m1 += w1 * wsm[O_WE2 + k * 2 + 1];
    }
    wsm[O_M + i * 2 + 0] = m0;
    wsm[O_M + i * 2 + 1] = m1;
  }
  if (t == 0) {
    float b20 = wsm[O_BE2 + 0], b21 = wsm[O_BE2 + 1];
    for (int k = 0; k < 32; k++) {
      b20 += wsm[O_BE1 + k] * wsm[O_WE2 + k * 2 + 0];
      b21 += wsm[O_BE1 + k] * wsm[O_WE2 + k * 2 + 1];
    }
    wsm[O_BIAS2 + 0] = b20;
    wsm[O_BIAS2 + 1] = b21;
  }
}

// --- bucket radix partition (atomic-free globally) -------------------------
__global__ __launch_bounds__(1024) void k_hist(const int* __restrict__ dst,
                                               int* __restrict__ counts,
                                               int E, int chunk) {
  __shared__ int h[KB];
  for (int i = threadIdx.x; i < KB; i += blockDim.x) h[i] = 0;
  __syncthreads();
  int b = blockIdx.x;
  int start = b * chunk, end = min(E, start + chunk);
  int tid = threadIdx.x, BD = blockDim.x;
  for (int base = start; base < end; base += BD * 4) {
#pragma unroll
    for (int u = 0; u < 4; u++) {
      int idx = base + u * BD + tid;
      if (idx < end) atomicAdd(&h[dst[idx] >> 7], 1);
    }
  }
  __syncthreads();
  for (int i = threadIdx.x; i < KB; i += blockDim.x)
    counts[i * FBC + b] = h[i];
}

__global__ __launch_bounds__(FBC) void k_scanA(int* __restrict__ counts,
                                               int* __restrict__ totals) {
  __shared__ int s[FBC];
  int k = blockIdx.x, t = threadIdx.x;
  int v = counts[k * FBC + t];
  s[t] = v;
  __syncthreads();
  for (int off = 1; off < FBC; off <<= 1) {
    int add = (t >= off) ? s[t - off] : 0;
    __syncthreads();
    s[t] += add;
    __syncthreads();
  }
  counts[k * FBC + t] = s[t] - v;          // exclusive within bucket
  if (t == FBC - 1) totals[k] = s[t];
}

__global__ __launch_bounds__(1024) void k_scanB(const int* __restrict__ totals,
                                                int* __restrict__ bases) {
  __shared__ int s[1024];
  int t = threadIdx.x;
  int v = (t < KB) ? totals[t] : 0;
  s[t] = v;
  __syncthreads();
  for (int off = 1; off < 1024; off <<= 1) {
    int add = (t >= off) ? s[t - off] : 0;
    __syncthreads();
    s[t] += add;
    __syncthreads();
  }
  if (t < KB) bases[t] = s[t] - v;
  if (t == KB - 1) bases[KB] = s[t];
}

// in-LDS counting sort per chunk; flush = per-bucket contiguous runs.
// Flush does ONE binary search per 4-element quad + scan-forward.
__global__ __launch_bounds__(1024) void k_fillsort(const int* __restrict__ src,
                                                   const int* __restrict__ dst,
                                                   const int* __restrict__ counts,
                                                   const int* __restrict__ bases,
                                                   unsigned int* __restrict__ recs,
                                                   int E, int chunk) {
  __shared__ unsigned int staged[STCAP];
  __shared__ int cnt[KB], r0o[KB + 1], r0c[KB], tgt[KB];
  int b = blockIdx.x;
  int tid = threadIdx.x, BD = blockDim.x;
  for (int i = tid; i < KB; i += BD)
    tgt[i] = bases[i] + counts[i * FBC + b];
  int start = b * chunk, end = min(E, start + chunk);
  for (int rs = start; rs < end; rs += STCAP) {
    int rn = min(STCAP, end - rs);
    for (int i = tid; i < KB; i += BD) cnt[i] = 0;
    __syncthreads();
    for (int base = 0; base < rn; base += BD * 4) {
#pragma unroll
      for (int u = 0; u < 4; u++) {
        int idx = base + u * BD + tid;
        if (idx < rn) atomicAdd(&cnt[dst[rs + idx] >> 7], 1);
      }
    }
    __syncthreads();
    if (tid < KB) r0o[tid] = cnt[tid];
    __syncthreads();
    for (int off = 1; off < KB; off <<= 1) {
      int add = 0;
      if (tid < KB && tid >= off) add = r0o[tid - off];
      __syncthreads();
      if (tid < KB) r0o[tid] += add;
      __syncthreads();
    }
    if (tid < KB) r0c[tid] = r0o[tid] - cnt[tid];   // exclusive
    __syncthreads();
    if (tid < KB) r0o[tid] = r0c[tid];
    if (tid == 0) r0o[KB] = rn;
    __syncthreads();
    for (int base = 0; base < rn; base += BD * 4) {
#pragma unroll
      for (int u = 0; u < 4; u++) {
        int idx = base + u * BD + tid;
        if (idx < rn) {
          int d = dst[rs + idx];
          int s = src[rs + idx];
          int pos = atomicAdd(&r0c[d >> 7], 1);
          staged[pos] = ((unsigned int)s << 7) | (unsigned int)(d & 127);
        }
      }
    }
    __syncthreads();
    int nquads = (rn + 3) >> 2;
    for (int q = tid; q < nquads; q += BD) {
      int t0 = q * 4;
      int lo = 0, hi = KB;
      while (hi - lo > 1) {
        int mid = (lo + hi) >> 1;
        if (r0o[mid] <= t0) lo = mid; else hi = mid;
      }
      int tend = min(t0 + 4, rn);
      for (int t = t0; t < tend; t++) {
        while (t >= r0o[lo + 1]) lo++;           // advance run (sentinel at KB)
        recs[tgt[lo] + (t - r0o[lo])] = staged[t];
      }
    }
    __syncthreads();
    if (tid < KB) tgt[tid] += cnt[tid];
    __syncthreads();
  }
}

// --- per-bucket passes -----------------------------------------------------
#define UDG 8
__global__ __launch_bounds__(1024) void k_degdinv(const unsigned int* __restrict__ recs,
                                                  const int* __restrict__ bases,
                                                  float* __restrict__ dinv, int N) {
  __shared__ int cnt[128];
  if (threadIdx.x < 128) cnt[threadIdx.x] = 0;
  __syncthreads();
  int k = blockIdx.x;
  int s0 = bases[k], n = bases[k + 1] - s0;
  const unsigned int* rp = recs + s0;
  int tid = threadIdx.x, BD = blockDim.x;
  for (int base = 0; base < n; base += BD * UDG) {
    unsigned int r[UDG]; int ok[UDG];
#pragma unroll
    for (int u = 0; u < UDG; u++) {
      int idx = base + u * BD + tid;
      ok[u] = idx < n;
      r[u] = ok[u] ? rp[idx] : 0u;
    }
#pragma unroll
    for (int u = 0; u < UDG; u++)
      if (ok[u]) atomicAdd(&cnt[r[u] & 127u], 1);
  }
  __syncthreads();
  if (threadIdx.x < 128) {
    int v = k * 128 + threadIdx.x;
    if (v < N) dinv[v] = rsqrtf((float)cnt[threadIdx.x] + 1.0f);
  }
}

#define USA 8
__global__ __launch_bounds__(1024) void k_sA(const float* __restrict__ wsm,
                                             const unsigned int* __restrict__ recs,
                                             const int* __restrict__ bases,
                                             const float* __restrict__ dinv,
                                             float4* __restrict__ rec4, int N) {
  __shared__ float acc[128];
  __shared__ float ts[16];
  __shared__ int nt;
  if (threadIdx.x < 128) acc[threadIdx.x] = 0.f;
  if (threadIdx.x == 0) nt = (int)wsm[O_NT];
  if (threadIdx.x < 16) ts[threadIdx.x] = wsm[O_TS + threadIdx.x];
  __syncthreads();
  int k = blockIdx.x;
  int s0 = bases[k], n = bases[k + 1] - s0;
  const unsigned int* rp = recs + s0;
  int tid = threadIdx.x, BD = blockDim.x;
  for (int base = 0; base < n; base += BD * USA) {
    unsigned int r[USA]; int ok[USA];
#pragma unroll
    for (int u = 0; u < USA; u++) {
      int idx = base + u * BD + tid;
      ok[u] = idx < n;
      r[u] = ok[u] ? rp[idx] : 0u;
    }
    float dv[USA];
#pragma unroll
    for (int u = 0; u < USA; u++) dv[u] = ok[u] ? dinv[r[u] >> 7] : 0.f;
#pragma unroll
    for (int u = 0; u < USA; u++)
      if (ok[u]) atomicAdd(&acc[r[u] & 127u], dv[u]);
  }
  __syncthreads();
  if (threadIdx.x < 128) {
    int v = k * 128 + threadIdx.x;
    if (v < N) {
      float dv = dinv[v];
      float s = dv * (acc[threadIdx.x] + dv);
      int rr = 0;
      for (int i = 0; i < nt; i++) rr += (ts[i] < s) ? 1 : 0;
      rec4[v] = make_float4(dv * s, dv, __int_as_float(rr), 0.f);
    }
  }
}

// --- fused: LDS-plane accumulate + node MLP tail -> pspd -------------------
#define UABF 8
__global__ __launch_bounds__(512) void k_ABfused(const float* __restrict__ wsm,
                                                 const unsigned int* __restrict__ recs,
                                                 const int* __restrict__ bases,
                                                 const float4* __restrict__ rec4,
                                                 float4* __restrict__ pspd, int N) {
  __shared__ float L[128 * LSTR];
  __shared__ float sU[NREG * 32], sW[NREG * 32], sWn[1024], sB2[32], sBn[32], sM[132];
  __shared__ int nt;
  for (int i = threadIdx.x; i < 128 * LSTR; i += blockDim.x) L[i] = 0.f;
  for (int i = threadIdx.x; i < NREG * 32; i += blockDim.x) {
    sU[i] = wsm[O_U + i];
    sW[i] = wsm[O_WWR + i];
  }
  for (int i = threadIdx.x; i < 1024; i += blockDim.x) sWn[i] = wsm[O_WN + i];
  if (threadIdx.x < 32) {
    sB2[threadIdx.x] = wsm[O_B2C + threadIdx.x];
    sBn[threadIdx.x] = wsm[O_BN + threadIdx.x];
  }
  for (int i = threadIdx.x; i < 132; i += blockDim.x) sM[i] = wsm[O_M + i];
  if (threadIdx.x == 0) nt = (int)wsm[O_NT];
  __syncthreads();
  int k = blockIdx.x;
  int s0 = bases[k], n = bases[k + 1] - s0;
  const unsigned int* rp = recs + s0;
  int tid = threadIdx.x, BD = blockDim.x;
  for (int base = 0; base < n; base += BD * UABF) {
    unsigned int r[UABF]; int ok[UABF];
#pragma unroll
    for (int u = 0; u < UABF; u++) {
      int idx = base + u * BD + tid;
      ok[u] = idx < n;
      r[u] = ok[u] ? rp[idx] : 0u;
    }
    float4 q[UABF];
#pragma unroll
    for (int u = 0; u < UABF; u++) {
      q[u] = make_float4(0.f, 0.f, 0.f, 0.f);
      if (ok[u]) q[u] = rec4[r[u] >> 7];
    }
#pragma unroll
    for (int u = 0; u < UABF; u++) {
      if (ok[u]) {
        int rowb = (int)(r[u] & 127u) * LSTR;
        int rr = __float_as_int(q[u].z);
        atomicAdd(&L[rowb + rr], q[u].x);
        atomicAdd(&L[rowb + NREG + rr], q[u].y);
      }
    }
  }
  __syncthreads();
  if (tid < 128) {
    int v = k * 128 + tid;
    if (v < N) {
      float4 self = rec4[v];
      float dv = self.y;
      int sr = __float_as_int(self.z);
      const float* row = &L[tid * LSTR];
      int R = nt + 1;
      float acc[32];
#pragma unroll
      for (int j = 0; j < 32; j++) acc[j] = 0.f;
      for (int r = 0; r < R; r++) {
        float Ar = row[r] + ((r == sr) ? self.x : 0.f);
        float Br = row[NREG + r] + ((r == sr) ? self.y : 0.f);
        if (Ar != 0.f || Br != 0.f) {
#pragma unroll
          for (int j = 0; j < 32; j++)
            acc[j] += Ar * sU[r * 32 + j] + Br * sW[r * 32 + j];
        }
      }
#pragma unroll
      for (int j = 0; j < 32; j++) acc[j] = relu_(dv * acc[j] + sB2[j]);  // x2
      float x3[32];
#pragma unroll
      for (int j = 0; j < 32; j++) {
        float a = sBn[j];
#pragma unroll
        for (int q2 = 0; q2 < 32; q2++) a += acc[q2] * sWn[q2 * 32 + j];
        x3[j] = relu_(a);
      }
      float ps0 = 0.f, ps1 = 0.f, pd0 = 0.f, pd1 = 0.f;
#pragma unroll
      for (int j = 0; j < 32; j++) {
        float x = x3[j];
        ps0 += x * sM[(2 + j) * 2 + 0];
        ps1 += x * sM[(2 + j) * 2 + 1];
        pd0 += x * sM[(34 + j) * 2 + 0];
        pd1 += x * sM[(34 + j) * 2 + 1];
      }
      pspd[v] = make_float4(ps0, ps1, pd0, pd1);
    }
  }
}

#define UE 8
__global__ __launch_bounds__(256) void k_edge(const float* __restrict__ wsm,
                                              const int* __restrict__ src,
                                              const int* __restrict__ dst,
                                              const void* __restrict__ ewraw,
                                              const void* __restrict__ ceraw,
                                              const float4* __restrict__ pspd,
                                              void* __restrict__ out,
                                              const int* __restrict__ mode, int E) {
  int e0 = (blockIdx.x * blockDim.x + threadIdx.x) * UE;
  bool bf = (*mode) != 0;
  float b0 = wsm[O_BIAS2 + 0], b1 = wsm[O_BIAS2 + 1];
  float M00 = wsm[O_M + 0], M01 = wsm[O_M + 1];
  float M10 = wsm[O_M + 2], M11 = wsm[O_M + 3];
  if (e0 + UE <= E) {
    int4 s4i[2], d4i[2];
    s4i[0] = ((const int4*)(src + e0))[0];
    s4i[1] = ((const int4*)(src + e0))[1];
    d4i[0] = ((const int4*)(dst + e0))[0];
    d4i[1] = ((const int4*)(dst + e0))[1];
    const int* s = (const int*)s4i;
    const int* d = (const int*)d4i;
    float4 sv[UE], dv4[UE];
#pragma unroll
    for (int u = 0; u < UE; u++) sv[u] = pspd[s[u]];
#pragma unroll
    for (int u = 0; u < UE; u++) dv4[u] = pspd[d[u]];
    float ewv[UE], cev[UE];
    if (bf) {
      uint4 ewp = *(const uint4*)((const unsigned short*)ewraw + e0);
      uint4 cep = *(const uint4*)((const unsigned short*)ceraw + e0);
      const unsigned int* ewu = (const unsigned int*)&ewp;
      const unsigned int* ceu = (const unsigned int*)&cep;
#pragma unroll
      for (int u = 0; u < UE; u++) {
        unsigned int w = ewu[u >> 1], c = ceu[u >> 1];
        unsigned short hw = (u & 1) ? (unsigned short)(w >> 16) : (unsigned short)(w & 0xFFFF);
        unsigned short hc = (u & 1) ? (unsigned short)(c >> 16) : (unsigned short)(c & 0xFFFF);
        ewv[u] = bf2f(hw);
        cev[u] = bf2f(hc);
      }
    } else {
#pragma unroll
      for (int u = 0; u < UE; u += 4) {
        float4 w = *(const float4*)((const float*)ewraw + e0 + u);
        float4 c = *(const float4*)((const float*)ceraw + e0 + u);
        ewv[u] = w.x; ewv[u+1] = w.y; ewv[u+2] = w.z; ewv[u+3] = w.w;
        cev[u] = c.x; cev[u+1] = c.y; cev[u+2] = c.z; cev[u+3] = c.w;
      }
    }
#pragma unroll
    for (int u = 0; u < UE; u++) {
      int e = e0 + u;
      float o0 = b0 + ewv[u] * M00 + cev[u] * M10 + sv[u].x + dv4[u].z;
      float o1 = b1 + ewv[u] * M01 + cev[u] * M11 + sv[u].y + dv4[u].w;
      if (bf) {
        unsigned int pk = ((unsigned int)f2bf(o1) << 16) | (unsigned int)f2bf(o0);
        ((unsigned int*)out)[e] = pk;
      } else {
        float2 r; r.x = o0; r.y = o1;
        ((float2*)out)[e] = r;
      }
    }
  } else {
    for (int e = e0; e < E; e++) {
      float ew = bf ? bf2f(((const unsigned short*)ewraw)[e]) : ((const float*)ewraw)[e];
      float ce = bf ? bf2f(((const unsigned short*)ceraw)[e]) : ((const float*)ceraw)[e];
      float4 sv = pspd[src[e]];
      float4 dv4 = pspd[dst[e]];
      float o0 = b0 + ew * M00 + ce * M10 + sv.x + dv4.z;
      float o1 = b1 + ew * M01 + ce * M11 + sv.y + dv4.w;
      if (bf) {
        unsigned int pk = ((unsigned int)f2bf(o1) << 16) | (unsigned int)f2bf(o0);
        ((unsigned int*)out)[e] = pk;
      } else {
        float2 r; r.x = o0; r.y = o1;
        ((float2*)out)[e] = r;
      }
    }
  }
}

extern "C" void kernel_launch(void* const* d_in, const int* in_sizes, int n_in,
                              void* d_out, int out_size, void* d_ws, size_t ws_size,
                              hipStream_t stream) {
  const int* eidx = (const int*)d_in[0];
  const int E = in_sizes[0] / 2;
  const int N = NNODES;
  const int* src = eidx;
  const int* dst = eidx + E;
  const int chunk = (E + FBC - 1) / FBC;

  char* ws = (char*)d_ws;
  size_t off = 0;
  size_t off_mode = off; off += 256;
  size_t off_wsm  = off; off += (size_t)WSM_TOTAL * 4;
  off = (off + 255) & ~(size_t)255;
  size_t off_cnts = off; off += (size_t)KB * FBC * 4;
  size_t off_tot  = off; off += (size_t)KB * 4;
  off = (off + 255) & ~(size_t)255;
  size_t off_base = off; off += (size_t)(KB + 1) * 4;
  off = (off + 255) & ~(size_t)255;
  size_t off_recs = off; off += (size_t)E * 4;
  size_t off_dinv = off; off += (size_t)N * 4;
  off = (off + 255) & ~(size_t)255;
  size_t off_rec4 = off; off += (size_t)N * 16;
  size_t off_pspd = off; off += (size_t)N * 16;
  if (ws_size < off) return;

  int*          mode   = (int*)(ws + off_mode);
  float*        wsm    = (float*)(ws + off_wsm);
  int*          counts = (int*)(ws + off_cnts);
  int*          totals = (int*)(ws + off_tot);
  int*          bases  = (int*)(ws + off_base);
  unsigned int* recs   = (unsigned int*)(ws + off_recs);
  float*        dinv   = (float*)(ws + off_dinv);
  float4*       rec4   = (float4*)(ws + off_rec4);
  float4*       pspd   = (float4*)(ws + off_pspd);

  k_detect<<<1, 256, 0, stream>>>((const unsigned short*)d_in[1], mode);
  k_convert_small<<<(WSM_N + 255) / 256, 256, 0, stream>>>(
      d_in[4], d_in[5], d_in[6], d_in[7], d_in[8], d_in[9], d_in[10], d_in[11],
      d_in[12], d_in[13], d_in[14], d_in[15], mode, wsm);
  k_prep<<<1, 64, 0, stream>>>(wsm);
  k_hist<<<FBC, 1024, 0, stream>>>(dst, counts, E, chunk);
  k_scanA<<<KB, FBC, 0, stream>>>(counts, totals);
  k_scanB<<<1, 1024, 0, stream>>>(totals, bases);
  k_fillsort<<<FBC, 1024, 0, stream>>>(src, dst, counts, bases, recs, E, chunk);
  k_degdinv<<<KB, 1024, 0, stream>>>(recs, bases, dinv, N);
  k_sA<<<KB, 1024, 0, stream>>>(wsm, recs, bases, dinv, rec4, N);
  k_ABfused<<<KB, 512, 0, stream>>>(wsm, recs, bases, rec4, pspd, N);
  {
    long long tot = ((long long)E + UE - 1) / UE;
    int blocks = (int)((tot + 255) / 256);
    k_edge<<<blocks, 256, 0, stream>>>(wsm, src, dst, d_in[1], d_in[2],
                                       pspd, d_out, mode, E);
  }
}

// Round 11
// 218.757 us; speedup vs baseline: 1.3365x; 1.1276x over previous
//
#include <hip/hip_runtime.h>
#include <hip/hip_bf16.h>

// ---------------------------------------------------------------------------
// KEPCE_GCN, round 11: skinny sweeps, fat math separate.
//  - R10 lesson: fusing node-MLP tail into ABacc imposed 124 VGPR on the
//    gather phase (occupancy 12.9%, 100us). De-fused: ABacc (12 VGPR,
//    1024thr) + node2 (256thr) via ABg roundtrip (R7 structure, 56+8us).
//  - fillsort reuses k_hist's per-chunk counts (counts kept raw; scanA
//    writes prefixes to prefx) -> pass-1 histogram deleted.
// ---------------------------------------------------------------------------

#define NNODES 100000
#define NREG   17
#define KB     782          // buckets = ceil(100000/128)
#define FBC    256          // chunk blocks (chunk = ceil(E/FBC) must be <= STCAP)
#define STCAP  12544        // LDS staging capacity
#define LSTR   37           // LDS row stride for AB planes
#define ABSTR  4352         // 34*128 floats per bucket in ABg

// wsm element offsets (f32)
#define O_W0    0
#define O_B0    8
#define O_W1    16
#define O_B1    144
#define O_W2    160
#define O_B2C   672
#define O_WN    704
#define O_BN    1728
#define O_WE1   1760
#define O_BE1   3872
#define O_WE2   3904
#define O_BE2   3968
#define WSM_N   3970
#define O_H0    3972
#define O_TS    3992
#define O_NT    4008
#define O_U     4016   // 17*32
#define O_WWR   4560   // 17*32
#define O_M     5104   // 66*2
#define O_BIAS2 5236
#define WSM_TOTAL 6144

__device__ __forceinline__ float bf2f(unsigned short u) {
  union { float f; unsigned int i; } v; v.i = ((unsigned int)u) << 16; return v.f;
}
__device__ __forceinline__ unsigned short f2bf(float f) {
  union { float f; unsigned int i; } v; v.f = f;
  unsigned int x = v.i;
  return (unsigned short)((x + 0x7FFFu + ((x >> 16) & 1u)) >> 16);
}
__device__ __forceinline__ float relu_(float x) { return x > 0.f ? x : 0.f; }

__global__ __launch_bounds__(256) void k_detect(const unsigned short* ew, int* mode) {
  __shared__ int cnt;
  if (threadIdx.x == 0) cnt = 0;
  __syncthreads();
  int ok = 0;
  for (int i = threadIdx.x; i < 512; i += blockDim.x) {
    unsigned short h = ew[i];
    int e = (h >> 7) & 0xFF;
    if (!(h & 0x8000) && e >= 0x70 && e <= 0x7E) ok++;
  }
  atomicAdd(&cnt, ok);
  __syncthreads();
  if (threadIdx.x == 0) *mode = (cnt >= 400) ? 1 : 0;  // 1 = bf16
}

__global__ __launch_bounds__(256) void k_convert_small(
    const void* p0, const void* p1, const void* p2, const void* p3,
    const void* p4, const void* p5, const void* p6, const void* p7,
    const void* p8, const void* p9, const void* p10, const void* p11,
    const int* mode, float* wsm) {
  int idx = blockIdx.x * blockDim.x + threadIdx.x;
  if (idx >= WSM_N) return;
  const void* ptrs[12] = {p0,p1,p2,p3,p4,p5,p6,p7,p8,p9,p10,p11};
  const int offs[13] = {O_W0,O_B0,O_W1,O_B1,O_W2,O_B2C,O_WN,O_BN,O_WE1,O_BE1,O_WE2,O_BE2,WSM_N};
  int seg = 0;
  while (idx >= offs[seg + 1]) seg++;
  int k = idx - offs[seg];
  wsm[idx] = (*mode) ? bf2f(((const unsigned short*)ptrs[seg])[k])
                     : ((const float*)ptrs[seg])[k];
}

__global__ __launch_bounds__(64) void k_prep(float* wsm) {
  __shared__ float h0[16], ts[16];
  __shared__ int snt;
  int t = threadIdx.x;
  if (t < 16) {
    float acc = 0.f;
    for (int j = 0; j < 8; j++)
      acc += (wsm[O_W0 + j] + wsm[O_B0 + j]) * wsm[O_W1 + j * 16 + t];
    h0[t] = acc;
    wsm[O_H0 + t] = acc;
  }
  __syncthreads();
  if (t == 0) {
    int n = 0;
    for (int j = 0; j < 16; j++) {
      float h = h0[j], b = wsm[O_B1 + j];
      if (h != 0.f) {
        float tj = -b / h;
        if (tj > 0.f) {
          int p = n++;
          while (p > 0 && ts[p - 1] > tj) { ts[p] = ts[p - 1]; p--; }
          ts[p] = tj;
        }
      }
    }
    snt = n;
    wsm[O_NT] = (float)n;
    for (int i = 0; i < n; i++) wsm[O_TS + i] = ts[i];
  }
  __syncthreads();
  int n = snt;
  for (int r = 0; r <= n; r++) {
    float srep;
    if (n == 0) srep = 1.f;
    else if (r == 0) srep = ts[0] * 0.5f;
    else if (r == n) srep = ts[n - 1] * 2.f + 1.f;
    else srep = 0.5f * (ts[r - 1] + ts[r]);
    if (t < 32) {
      float uu = 0.f, ww = 0.f;
      for (int j = 0; j < 16; j++) {
        float h = h0[j], b = wsm[O_B1 + j];
        if (srep * h + b > 0.f) {
          float w2 = wsm[O_W2 + j * 32 + t];
          uu += h * w2;
          ww += b * w2;
        }
      }
      wsm[O_U + r * 32 + t] = uu;
      wsm[O_WWR + r * 32 + t] = ww;
    }
  }
  for (int i = t; i < 66; i += blockDim.x) {
    float m0 = 0.f, m1 = 0.f;
    for (int k = 0; k < 32; k++) {
      float w1 = wsm[O_WE1 + i * 32 + k];
      m0 += w1 * wsm[O_WE2 + k * 2 + 0];
      m1 += w1 * wsm[O_WE2 + k * 2 + 1];
    }
    wsm[O_M + i * 2 + 0] = m0;
    wsm[O_M + i * 2 + 1] = m1;
  }
  if (t == 0) {
    float b20 = wsm[O_BE2 + 0], b21 = wsm[O_BE2 + 1];
    for (int k = 0; k < 32; k++) {
      b20 += wsm[O_BE1 + k] * wsm[O_WE2 + k * 2 + 0];
      b21 += wsm[O_BE1 + k] * wsm[O_WE2 + k * 2 + 1];
    }
    wsm[O_BIAS2 + 0] = b20;
    wsm[O_BIAS2 + 1] = b21;
  }
}

// --- bucket radix partition (atomic-free globally) -------------------------
__global__ __launch_bounds__(1024) void k_hist(const int* __restrict__ dst,
                                               int* __restrict__ counts,
                                               int E, int chunk) {
  __shared__ int h[KB];
  for (int i = threadIdx.x; i < KB; i += blockDim.x) h[i] = 0;
  __syncthreads();
  int b = blockIdx.x;
  int start = b * chunk, end = min(E, start + chunk);
  int tid = threadIdx.x, BD = blockDim.x;
  for (int base = start; base < end; base += BD * 4) {
#pragma unroll
    for (int u = 0; u < 4; u++) {
      int idx = base + u * BD + tid;
      if (idx < end) atomicAdd(&h[dst[idx] >> 7], 1);
    }
  }
  __syncthreads();
  for (int i = threadIdx.x; i < KB; i += blockDim.x)
    counts[i * FBC + b] = h[i];          // raw counts kept
}

// prefixes go to prefx; counts stay raw for fillsort reuse
__global__ __launch_bounds__(FBC) void k_scanA(const int* __restrict__ counts,
                                               int* __restrict__ prefx,
                                               int* __restrict__ totals) {
  __shared__ int s[FBC];
  int k = blockIdx.x, t = threadIdx.x;
  int v = counts[k * FBC + t];
  s[t] = v;
  __syncthreads();
  for (int off = 1; off < FBC; off <<= 1) {
    int add = (t >= off) ? s[t - off] : 0;
    __syncthreads();
    s[t] += add;
    __syncthreads();
  }
  prefx[k * FBC + t] = s[t] - v;          // exclusive within bucket
  if (t == FBC - 1) totals[k] = s[t];
}

__global__ __launch_bounds__(1024) void k_scanB(const int* __restrict__ totals,
                                                int* __restrict__ bases) {
  __shared__ int s[1024];
  int t = threadIdx.x;
  int v = (t < KB) ? totals[t] : 0;
  s[t] = v;
  __syncthreads();
  for (int off = 1; off < 1024; off <<= 1) {
    int add = (t >= off) ? s[t - off] : 0;
    __syncthreads();
    s[t] += add;
    __syncthreads();
  }
  if (t < KB) bases[t] = s[t] - v;
  if (t == KB - 1) bases[KB] = s[t];
}

// in-LDS counting sort per chunk (counts precomputed by k_hist); flush =
// per-bucket contiguous runs, binary search once per 4-elem quad.
__global__ __launch_bounds__(1024) void k_fillsort(const int* __restrict__ src,
                                                   const int* __restrict__ dst,
                                                   const int* __restrict__ counts,
                                                   const int* __restrict__ prefx,
                                                   const int* __restrict__ bases,
                                                   unsigned int* __restrict__ recs,
                                                   int E, int chunk) {
  __shared__ unsigned int staged[STCAP];
  __shared__ int cnt[KB], r0o[KB + 1], r0c[KB], tgt[KB];
  int b = blockIdx.x;
  int tid = threadIdx.x, BD = blockDim.x;
  for (int i = tid; i < KB; i += BD) {
    cnt[i] = counts[i * FBC + b];
    tgt[i] = bases[i] + prefx[i * FBC + b];
  }
  __syncthreads();
  int start = b * chunk, end = min(E, start + chunk);
  int rn = end - start;                      // chunk <= STCAP by construction
  // exclusive scan of cnt -> run starts
  if (tid < KB) r0o[tid] = cnt[tid];
  __syncthreads();
  for (int off = 1; off < KB; off <<= 1) {
    int add = 0;
    if (tid < KB && tid >= off) add = r0o[tid - off];
    __syncthreads();
    if (tid < KB) r0o[tid] += add;
    __syncthreads();
  }
  if (tid < KB) r0c[tid] = r0o[tid] - cnt[tid];
  __syncthreads();
  if (tid < KB) r0o[tid] = r0c[tid];
  if (tid == 0) r0o[KB] = rn;
  __syncthreads();
  // scatter records into sorted LDS positions
  for (int base = 0; base < rn; base += BD * 4) {
#pragma unroll
    for (int u = 0; u < 4; u++) {
      int idx = base + u * BD + tid;
      if (idx < rn) {
        int d = dst[start + idx];
        int s = src[start + idx];
        int pos = atomicAdd(&r0c[d >> 7], 1);
        staged[pos] = ((unsigned int)s << 7) | (unsigned int)(d & 127);
      }
    }
  }
  __syncthreads();
  // flush: binary search once per quad, scan forward inside
  int nquads = (rn + 3) >> 2;
  for (int q = tid; q < nquads; q += BD) {
    int t0 = q * 4;
    int lo = 0, hi = KB;
    while (hi - lo > 1) {
      int mid = (lo + hi) >> 1;
      if (r0o[mid] <= t0) lo = mid; else hi = mid;
    }
    int tend = min(t0 + 4, rn);
    for (int t = t0; t < tend; t++) {
      while (t >= r0o[lo + 1]) lo++;
      recs[tgt[lo] + (t - r0o[lo])] = staged[t];
    }
  }
}

// --- per-bucket passes (skinny: low VGPR, 1024 threads) ---------------------
#define UDG 4
__global__ __launch_bounds__(1024) void k_degdinv(const unsigned int* __restrict__ recs,
                                                  const int* __restrict__ bases,
                                                  float* __restrict__ dinv, int N) {
  __shared__ int cnt[128];
  if (threadIdx.x < 128) cnt[threadIdx.x] = 0;
  __syncthreads();
  int k = blockIdx.x;
  int s0 = bases[k], n = bases[k + 1] - s0;
  const unsigned int* rp = recs + s0;
  int tid = threadIdx.x, BD = blockDim.x;
  for (int base = 0; base < n; base += BD * UDG) {
    unsigned int r[UDG]; int ok[UDG];
#pragma unroll
    for (int u = 0; u < UDG; u++) {
      int idx = base + u * BD + tid;
      ok[u] = idx < n;
      r[u] = ok[u] ? rp[idx] : 0u;
    }
#pragma unroll
    for (int u = 0; u < UDG; u++)
      if (ok[u]) atomicAdd(&cnt[r[u] & 127u], 1);
  }
  __syncthreads();
  if (threadIdx.x < 128) {
    int v = k * 128 + threadIdx.x;
    if (v < N) dinv[v] = rsqrtf((float)cnt[threadIdx.x] + 1.0f);
  }
}

#define USA 4
__global__ __launch_bounds__(1024) void k_sA(const float* __restrict__ wsm,
                                             const unsigned int* __restrict__ recs,
                                             const int* __restrict__ bases,
                                             const float* __restrict__ dinv,
                                             float4* __restrict__ rec4, int N) {
  __shared__ float acc[128];
  __shared__ float ts[16];
  __shared__ int nt;
  if (threadIdx.x < 128) acc[threadIdx.x] = 0.f;
  if (threadIdx.x == 0) nt = (int)wsm[O_NT];
  if (threadIdx.x < 16) ts[threadIdx.x] = wsm[O_TS + threadIdx.x];
  __syncthreads();
  int k = blockIdx.x;
  int s0 = bases[k], n = bases[k + 1] - s0;
  const unsigned int* rp = recs + s0;
  int tid = threadIdx.x, BD = blockDim.x;
  for (int base = 0; base < n; base += BD * USA) {
    unsigned int r[USA]; int ok[USA];
#pragma unroll
    for (int u = 0; u < USA; u++) {
      int idx = base + u * BD + tid;
      ok[u] = idx < n;
      r[u] = ok[u] ? rp[idx] : 0u;
    }
    float dv[USA];
#pragma unroll
    for (int u = 0; u < USA; u++) dv[u] = ok[u] ? dinv[r[u] >> 7] : 0.f;
#pragma unroll
    for (int u = 0; u < USA; u++)
      if (ok[u]) atomicAdd(&acc[r[u] & 127u], dv[u]);
  }
  __syncthreads();
  if (threadIdx.x < 128) {
    int v = k * 128 + threadIdx.x;
    if (v < N) {
      float dv = dinv[v];
      float s = dv * (acc[threadIdx.x] + dv);
      int rr = 0;
      for (int i = 0; i < nt; i++) rr += (ts[i] < s) ? 1 : 0;
      rec4[v] = make_float4(dv * s, dv, __int_as_float(rr), 0.f);
    }
  }
}

#define UAB 4
__global__ __launch_bounds__(1024) void k_ABacc(const unsigned int* __restrict__ recs,
                                                const int* __restrict__ bases,
                                                const float4* __restrict__ rec4,
                                                float* __restrict__ ABg, int N) {
  __shared__ float L[128 * LSTR];
  for (int i = threadIdx.x; i < 128 * LSTR; i += blockDim.x) L[i] = 0.f;
  __syncthreads();
  int k = blockIdx.x;
  int s0 = bases[k], n = bases[k + 1] - s0;
  const unsigned int* rp = recs + s0;
  int tid = threadIdx.x, BD = blockDim.x;
  for (int base = 0; base < n; base += BD * UAB) {
    unsigned int r[UAB]; int ok[UAB];
#pragma unroll
    for (int u = 0; u < UAB; u++) {
      int idx = base + u * BD + tid;
      ok[u] = idx < n;
      r[u] = ok[u] ? rp[idx] : 0u;
    }
    float4 q[UAB];
#pragma unroll
    for (int u = 0; u < UAB; u++) {
      q[u] = make_float4(0.f, 0.f, 0.f, 0.f);
      if (ok[u]) q[u] = rec4[r[u] >> 7];
    }
#pragma unroll
    for (int u = 0; u < UAB; u++) {
      if (ok[u]) {
        int rowb = (int)(r[u] & 127u) * LSTR;
        int rr = __float_as_int(q[u].z);
        atomicAdd(&L[rowb + rr], q[u].x);
        atomicAdd(&L[rowb + NREG + rr], q[u].y);
      }
    }
  }
  __syncthreads();
  float* out = ABg + (size_t)k * ABSTR;
  for (int i = tid; i < 34 * 128; i += BD) {
    int r = i >> 7, v = i & 127;
    out[i] = L[v * LSTR + r];
  }
}

// per node: AB planes -> x2 -> x3 -> (ps, pd)
__global__ __launch_bounds__(256) void k_node2(const float* __restrict__ wsm,
                                               const float* __restrict__ ABg,
                                               const float4* __restrict__ rec4,
                                               float4* __restrict__ pspd, int N) {
  __shared__ float sU[NREG * 32], sW[NREG * 32], sB2[32], sWn[1024], sBn[32], sM[132];
  for (int i = threadIdx.x; i < NREG * 32; i += blockDim.x) {
    sU[i] = wsm[O_U + i];
    sW[i] = wsm[O_WWR + i];
  }
  for (int i = threadIdx.x; i < 1024; i += blockDim.x) sWn[i] = wsm[O_WN + i];
  if (threadIdx.x < 32) {
    sB2[threadIdx.x] = wsm[O_B2C + threadIdx.x];
    sBn[threadIdx.x] = wsm[O_BN + threadIdx.x];
  }
  for (int i = threadIdx.x; i < 132; i += blockDim.x) sM[i] = wsm[O_M + i];
  __syncthreads();
  int v = blockIdx.x * blockDim.x + threadIdx.x;
  if (v >= N) return;
  float4 self = rec4[v];
  float dv = self.y;
  int sr = __float_as_int(self.z);
  const float* pb = ABg + (size_t)(v >> 7) * ABSTR + (v & 127);
  float A[NREG], B[NREG];
#pragma unroll
  for (int r = 0; r < NREG; r++) {
    A[r] = pb[r * 128];
    B[r] = pb[(NREG + r) * 128];
  }
  float acc[32];
#pragma unroll
  for (int j = 0; j < 32; j++) acc[j] = 0.f;
#pragma unroll
  for (int r = 0; r < NREG; r++) {
    float Ar = A[r] + ((r == sr) ? self.x : 0.f);
    float Br = B[r] + ((r == sr) ? self.y : 0.f);
    if (Ar != 0.f || Br != 0.f) {
#pragma unroll
      for (int j = 0; j < 32; j++)
        acc[j] += Ar * sU[r * 32 + j] + Br * sW[r * 32 + j];
    }
  }
#pragma unroll
  for (int j = 0; j < 32; j++) acc[j] = relu_(dv * acc[j] + sB2[j]);  // x2
  float x3[32];
#pragma unroll
  for (int j = 0; j < 32; j++) {
    float a = sBn[j];
#pragma unroll
    for (int q2 = 0; q2 < 32; q2++) a += acc[q2] * sWn[q2 * 32 + j];
    x3[j] = relu_(a);
  }
  float ps0 = 0.f, ps1 = 0.f, pd0 = 0.f, pd1 = 0.f;
#pragma unroll
  for (int j = 0; j < 32; j++) {
    float x = x3[j];
    ps0 += x * sM[(2 + j) * 2 + 0];
    ps1 += x * sM[(2 + j) * 2 + 1];
    pd0 += x * sM[(34 + j) * 2 + 0];
    pd1 += x * sM[(34 + j) * 2 + 1];
  }
  pspd[v] = make_float4(ps0, ps1, pd0, pd1);
}

#define UE 8
__global__ __launch_bounds__(256) void k_edge(const float* __restrict__ wsm,
                                              const int* __restrict__ src,
                                              const int* __restrict__ dst,
                                              const void* __restrict__ ewraw,
                                              const void* __restrict__ ceraw,
                                              const float4* __restrict__ pspd,
                                              void* __restrict__ out,
                                              const int* __restrict__ mode, int E) {
  int e0 = (blockIdx.x * blockDim.x + threadIdx.x) * UE;
  bool bf = (*mode) != 0;
  float b0 = wsm[O_BIAS2 + 0], b1 = wsm[O_BIAS2 + 1];
  float M00 = wsm[O_M + 0], M01 = wsm[O_M + 1];
  float M10 = wsm[O_M + 2], M11 = wsm[O_M + 3];
  if (e0 + UE <= E) {
    int4 s4i[2], d4i[2];
    s4i[0] = ((const int4*)(src + e0))[0];
    s4i[1] = ((const int4*)(src + e0))[1];
    d4i[0] = ((const int4*)(dst + e0))[0];
    d4i[1] = ((const int4*)(dst + e0))[1];
    const int* s = (const int*)s4i;
    const int* d = (const int*)d4i;
    float4 sv[UE], dv4[UE];
#pragma unroll
    for (int u = 0; u < UE; u++) sv[u] = pspd[s[u]];
#pragma unroll
    for (int u = 0; u < UE; u++) dv4[u] = pspd[d[u]];
    float ewv[UE], cev[UE];
    if (bf) {
      uint4 ewp = *(const uint4*)((const unsigned short*)ewraw + e0);
      uint4 cep = *(const uint4*)((const unsigned short*)ceraw + e0);
      const unsigned int* ewu = (const unsigned int*)&ewp;
      const unsigned int* ceu = (const unsigned int*)&cep;
#pragma unroll
      for (int u = 0; u < UE; u++) {
        unsigned int w = ewu[u >> 1], c = ceu[u >> 1];
        unsigned short hw = (u & 1) ? (unsigned short)(w >> 16) : (unsigned short)(w & 0xFFFF);
        unsigned short hc = (u & 1) ? (unsigned short)(c >> 16) : (unsigned short)(c & 0xFFFF);
        ewv[u] = bf2f(hw);
        cev[u] = bf2f(hc);
      }
    } else {
#pragma unroll
      for (int u = 0; u < UE; u += 4) {
        float4 w = *(const float4*)((const float*)ewraw + e0 + u);
        float4 c = *(const float4*)((const float*)ceraw + e0 + u);
        ewv[u] = w.x; ewv[u+1] = w.y; ewv[u+2] = w.z; ewv[u+3] = w.w;
        cev[u] = c.x; cev[u+1] = c.y; cev[u+2] = c.z; cev[u+3] = c.w;
      }
    }
#pragma unroll
    for (int u = 0; u < UE; u++) {
      int e = e0 + u;
      float o0 = b0 + ewv[u] * M00 + cev[u] * M10 + sv[u].x + dv4[u].z;
      float o1 = b1 + ewv[u] * M01 + cev[u] * M11 + sv[u].y + dv4[u].w;
      if (bf) {
        unsigned int pk = ((unsigned int)f2bf(o1) << 16) | (unsigned int)f2bf(o0);
        ((unsigned int*)out)[e] = pk;
      } else {
        float2 r; r.x = o0; r.y = o1;
        ((float2*)out)[e] = r;
      }
    }
  } else {
    for (int e = e0; e < E; e++) {
      float ew = bf ? bf2f(((const unsigned short*)ewraw)[e]) : ((const float*)ewraw)[e];
      float ce = bf ? bf2f(((const unsigned short*)ceraw)[e]) : ((const float*)ceraw)[e];
      float4 sv = pspd[src[e]];
      float4 dv4 = pspd[dst[e]];
      float o0 = b0 + ew * M00 + ce * M10 + sv.x + dv4.z;
      float o1 = b1 + ew * M01 + ce * M11 + sv.y + dv4.w;
      if (bf) {
        unsigned int pk = ((unsigned int)f2bf(o1) << 16) | (unsigned int)f2bf(o0);
        ((unsigned int*)out)[e] = pk;
      } else {
        float2 r; r.x = o0; r.y = o1;
        ((float2*)out)[e] = r;
      }
    }
  }
}

extern "C" void kernel_launch(void* const* d_in, const int* in_sizes, int n_in,
                              void* d_out, int out_size, void* d_ws, size_t ws_size,
                              hipStream_t stream) {
  const int* eidx = (const int*)d_in[0];
  const int E = in_sizes[0] / 2;
  const int N = NNODES;
  const int* src = eidx;
  const int* dst = eidx + E;
  const int chunk = (E + FBC - 1) / FBC;   // 12500 for E=3.2M (<= STCAP)

  char* ws = (char*)d_ws;
  size_t off = 0;
  size_t off_mode = off; off += 256;
  size_t off_wsm  = off; off += (size_t)WSM_TOTAL * 4;
  off = (off + 255) & ~(size_t)255;
  size_t off_cnts = off; off += (size_t)KB * FBC * 4;
  size_t off_pfx  = off; off += (size_t)KB * FBC * 4;
  size_t off_tot  = off; off += (size_t)KB * 4;
  off = (off + 255) & ~(size_t)255;
  size_t off_base = off; off += (size_t)(KB + 1) * 4;
  off = (off + 255) & ~(size_t)255;
  size_t off_recs = off; off += (size_t)E * 4;
  size_t off_dinv = off; off += (size_t)N * 4;
  off = (off + 255) & ~(size_t)255;
  size_t off_rec4 = off; off += (size_t)N * 16;
  size_t off_pspd = off; off += (size_t)N * 16;
  off = (off + 255) & ~(size_t)255;
  size_t off_ABg  = off; off += (size_t)KB * ABSTR * 4;
  if (ws_size < off) return;

  int*          mode   = (int*)(ws + off_mode);
  float*        wsm    = (float*)(ws + off_wsm);
  int*          counts = (int*)(ws + off_cnts);
  int*          prefx  = (int*)(ws + off_pfx);
  int*          totals = (int*)(ws + off_tot);
  int*          bases  = (int*)(ws + off_base);
  unsigned int* recs   = (unsigned int*)(ws + off_recs);
  float*        dinv   = (float*)(ws + off_dinv);
  float4*       rec4   = (float4*)(ws + off_rec4);
  float4*       pspd   = (float4*)(ws + off_pspd);
  float*        ABg    = (float*)(ws + off_ABg);

  k_detect<<<1, 256, 0, stream>>>((const unsigned short*)d_in[1], mode);
  k_convert_small<<<(WSM_N + 255) / 256, 256, 0, stream>>>(
      d_in[4], d_in[5], d_in[6], d_in[7], d_in[8], d_in[9], d_in[10], d_in[11],
      d_in[12], d_in[13], d_in[14], d_in[15], mode, wsm);
  k_prep<<<1, 64, 0, stream>>>(wsm);
  k_hist<<<FBC, 1024, 0, stream>>>(dst, counts, E, chunk);
  k_scanA<<<KB, FBC, 0, stream>>>(counts, prefx, totals);
  k_scanB<<<1, 1024, 0, stream>>>(totals, bases);
  k_fillsort<<<FBC, 1024, 0, stream>>>(src, dst, counts, prefx, bases, recs, E, chunk);
  k_degdinv<<<KB, 1024, 0, stream>>>(recs, bases, dinv, N);
  k_sA<<<KB, 1024, 0, stream>>>(wsm, recs, bases, dinv, rec4, N);
  k_ABacc<<<KB, 1024, 0, stream>>>(recs, bases, rec4, ABg, N);
  k_node2<<<(N + 255) / 256, 256, 0, stream>>>(wsm, ABg, rec4, pspd, N);
  {
    long long tot = ((long long)E + UE - 1) / UE;
    int blocks = (int)((tot + 255) / 256);
    k_edge<<<blocks, 256, 0, stream>>>(wsm, src, dst, d_in[1], d_in[2],
                                       pspd, d_out, mode, E);
  }
}

// Round 12
// 185.115 us; speedup vs baseline: 1.5794x; 1.1817x over previous
//
#include <hip/hip_runtime.h>
#include <hip/hip_bf16.h>

// ---------------------------------------------------------------------------
// KEPCE_GCN, round 12 = R11 + packed-u64 LDS atomic in ABacc.
//  DS-pipe model (R11 post-mortem): f32 LDS atomic ~4cyc/lane; ABacc's
//  2 atomics/edge = ~42us floor. Pack (alphaQ,betaQ) at 2^22 fixed point
//  into one u64 ds atomic (fields can't carry: sums < 2^28).
//  Also: detect+convert+prep fused into k_setup (1 block).
// ---------------------------------------------------------------------------

#define NNODES 100000
#define NREG   17
#define KB     782          // buckets = ceil(100000/128)
#define FBC    256          // chunk blocks
#define STCAP  12544        // LDS staging capacity (>= chunk)
#define LSTR64 19           // u64 row stride for AB planes (17 + pad)
#define ABSTR  4352         // 34*128 floats per bucket in ABg
#define QSCALE 4194304.0f   // 2^22
#define INVQ   2.384185791015625e-7f

// wsm element offsets (f32)
#define O_W0    0
#define O_B0    8
#define O_W1    16
#define O_B1    144
#define O_W2    160
#define O_B2C   672
#define O_WN    704
#define O_BN    1728
#define O_WE1   1760
#define O_BE1   3872
#define O_WE2   3904
#define O_BE2   3968
#define WSM_N   3970
#define O_H0    3972
#define O_TS    3992
#define O_NT    4008
#define O_U     4016   // 17*32
#define O_WWR   4560   // 17*32
#define O_M     5104   // 66*2
#define O_BIAS2 5236
#define WSM_TOTAL 6144

__device__ __forceinline__ float bf2f(unsigned short u) {
  union { float f; unsigned int i; } v; v.i = ((unsigned int)u) << 16; return v.f;
}
__device__ __forceinline__ unsigned short f2bf(float f) {
  union { float f; unsigned int i; } v; v.f = f;
  unsigned int x = v.i;
  return (unsigned short)((x + 0x7FFFu + ((x >> 16) & 1u)) >> 16);
}
__device__ __forceinline__ float relu_(float x) { return x > 0.f ? x : 0.f; }

// fused: dtype detect + weight convert + derived-tensor prep (one block)
__global__ __launch_bounds__(1024) void k_setup(
    const unsigned short* ewraw,
    const void* p0, const void* p1, const void* p2, const void* p3,
    const void* p4, const void* p5, const void* p6, const void* p7,
    const void* p8, const void* p9, const void* p10, const void* p11,
    int* mode, float* wsm) {
  __shared__ int cnt, smode, snt;
  __shared__ float h0[16], ts[16];
  int t = threadIdx.x;
  if (t == 0) cnt = 0;
  __syncthreads();
  int ok = 0;
  for (int i = t; i < 512; i += blockDim.x) {
    unsigned short h = ewraw[i];
    int e = (h >> 7) & 0xFF;
    if (!(h & 0x8000) && e >= 0x70 && e <= 0x7E) ok++;
  }
  atomicAdd(&cnt, ok);
  __syncthreads();
  if (t == 0) { smode = (cnt >= 400) ? 1 : 0; *mode = smode; }
  __syncthreads();
  int bf = smode;
  const void* ptrs[12] = {p0,p1,p2,p3,p4,p5,p6,p7,p8,p9,p10,p11};
  const int offs[13] = {O_W0,O_B0,O_W1,O_B1,O_W2,O_B2C,O_WN,O_BN,O_WE1,O_BE1,O_WE2,O_BE2,WSM_N};
  for (int idx = t; idx < WSM_N; idx += blockDim.x) {
    int seg = 0;
    while (idx >= offs[seg + 1]) seg++;
    int k = idx - offs[seg];
    wsm[idx] = bf ? bf2f(((const unsigned short*)ptrs[seg])[k])
                  : ((const float*)ptrs[seg])[k];
  }
  __syncthreads();
  // --- prep ---
  if (t < 16) {
    float acc = 0.f;
    for (int j = 0; j < 8; j++)
      acc += (wsm[O_W0 + j] + wsm[O_B0 + j]) * wsm[O_W1 + j * 16 + t];
    h0[t] = acc;
    wsm[O_H0 + t] = acc;
  }
  __syncthreads();
  if (t == 0) {
    int n = 0;
    for (int j = 0; j < 16; j++) {
      float h = h0[j], b = wsm[O_B1 + j];
      if (h != 0.f) {
        float tj = -b / h;
        if (tj > 0.f) {
          int p = n++;
          while (p > 0 && ts[p - 1] > tj) { ts[p] = ts[p - 1]; p--; }
          ts[p] = tj;
        }
      }
    }
    snt = n;
    wsm[O_NT] = (float)n;
    for (int i = 0; i < n; i++) wsm[O_TS + i] = ts[i];
  }
  __syncthreads();
  int n = snt;
  for (int r = 0; r <= n; r++) {
    float srep;
    if (n == 0) srep = 1.f;
    else if (r == 0) srep = ts[0] * 0.5f;
    else if (r == n) srep = ts[n - 1] * 2.f + 1.f;
    else srep = 0.5f * (ts[r - 1] + ts[r]);
    if (t < 32) {
      float uu = 0.f, ww = 0.f;
      for (int j = 0; j < 16; j++) {
        float h = h0[j], b = wsm[O_B1 + j];
        if (srep * h + b > 0.f) {
          float w2 = wsm[O_W2 + j * 32 + t];
          uu += h * w2;
          ww += b * w2;
        }
      }
      wsm[O_U + r * 32 + t] = uu;
      wsm[O_WWR + r * 32 + t] = ww;
    }
  }
  for (int i = t; i < 66; i += blockDim.x) {
    float m0 = 0.f, m1 = 0.f;
    for (int k = 0; k < 32; k++) {
      float w1 = wsm[O_WE1 + i * 32 + k];
      m0 += w1 * wsm[O_WE2 + k * 2 + 0];
      m1 += w1 * wsm[O_WE2 + k * 2 + 1];
    }
    wsm[O_M + i * 2 + 0] = m0;
    wsm[O_M + i * 2 + 1] = m1;
  }
  if (t == 0) {
    float b20 = wsm[O_BE2 + 0], b21 = wsm[O_BE2 + 1];
    for (int k = 0; k < 32; k++) {
      b20 += wsm[O_BE1 + k] * wsm[O_WE2 + k * 2 + 0];
      b21 += wsm[O_BE1 + k] * wsm[O_WE2 + k * 2 + 1];
    }
    wsm[O_BIAS2 + 0] = b20;
    wsm[O_BIAS2 + 1] = b21;
  }
}

// --- bucket radix partition (atomic-free globally) -------------------------
__global__ __launch_bounds__(1024) void k_hist(const int* __restrict__ dst,
                                               int* __restrict__ counts,
                                               int E, int chunk) {
  __shared__ int h[KB];
  for (int i = threadIdx.x; i < KB; i += blockDim.x) h[i] = 0;
  __syncthreads();
  int b = blockIdx.x;
  int start = b * chunk, end = min(E, start + chunk);
  int tid = threadIdx.x, BD = blockDim.x;
  for (int base = start; base < end; base += BD * 4) {
#pragma unroll
    for (int u = 0; u < 4; u++) {
      int idx = base + u * BD + tid;
      if (idx < end) atomicAdd(&h[dst[idx] >> 7], 1);
    }
  }
  __syncthreads();
  for (int i = threadIdx.x; i < KB; i += blockDim.x)
    counts[i * FBC + b] = h[i];
}

__global__ __launch_bounds__(FBC) void k_scanA(const int* __restrict__ counts,
                                               int* __restrict__ prefx,
                                               int* __restrict__ totals) {
  __shared__ int s[FBC];
  int k = blockIdx.x, t = threadIdx.x;
  int v = counts[k * FBC + t];
  s[t] = v;
  __syncthreads();
  for (int off = 1; off < FBC; off <<= 1) {
    int add = (t >= off) ? s[t - off] : 0;
    __syncthreads();
    s[t] += add;
    __syncthreads();
  }
  prefx[k * FBC + t] = s[t] - v;
  if (t == FBC - 1) totals[k] = s[t];
}

__global__ __launch_bounds__(1024) void k_scanB(const int* __restrict__ totals,
                                                int* __restrict__ bases) {
  __shared__ int s[1024];
  int t = threadIdx.x;
  int v = (t < KB) ? totals[t] : 0;
  s[t] = v;
  __syncthreads();
  for (int off = 1; off < 1024; off <<= 1) {
    int add = (t >= off) ? s[t - off] : 0;
    __syncthreads();
    s[t] += add;
    __syncthreads();
  }
  if (t < KB) bases[t] = s[t] - v;
  if (t == KB - 1) bases[KB] = s[t];
}

__global__ __launch_bounds__(1024) void k_fillsort(const int* __restrict__ src,
                                                   const int* __restrict__ dst,
                                                   const int* __restrict__ counts,
                                                   const int* __restrict__ prefx,
                                                   const int* __restrict__ bases,
                                                   unsigned int* __restrict__ recs,
                                                   int E, int chunk) {
  __shared__ unsigned int staged[STCAP];
  __shared__ int cnt[KB], r0o[KB + 1], r0c[KB], tgt[KB];
  int b = blockIdx.x;
  int tid = threadIdx.x, BD = blockDim.x;
  for (int i = tid; i < KB; i += BD) {
    cnt[i] = counts[i * FBC + b];
    tgt[i] = bases[i] + prefx[i * FBC + b];
  }
  __syncthreads();
  int start = b * chunk, end = min(E, start + chunk);
  int rn = end - start;
  if (tid < KB) r0o[tid] = cnt[tid];
  __syncthreads();
  for (int off = 1; off < KB; off <<= 1) {
    int add = 0;
    if (tid < KB && tid >= off) add = r0o[tid - off];
    __syncthreads();
    if (tid < KB) r0o[tid] += add;
    __syncthreads();
  }
  if (tid < KB) r0c[tid] = r0o[tid] - cnt[tid];
  __syncthreads();
  if (tid < KB) r0o[tid] = r0c[tid];
  if (tid == 0) r0o[KB] = rn;
  __syncthreads();
  for (int base = 0; base < rn; base += BD * 4) {
#pragma unroll
    for (int u = 0; u < 4; u++) {
      int idx = base + u * BD + tid;
      if (idx < rn) {
        int d = dst[start + idx];
        int s = src[start + idx];
        int pos = atomicAdd(&r0c[d >> 7], 1);
        staged[pos] = ((unsigned int)s << 7) | (unsigned int)(d & 127);
      }
    }
  }
  __syncthreads();
  int nquads = (rn + 3) >> 2;
  for (int q = tid; q < nquads; q += BD) {
    int t0 = q * 4;
    int lo = 0, hi = KB;
    while (hi - lo > 1) {
      int mid = (lo + hi) >> 1;
      if (r0o[mid] <= t0) lo = mid; else hi = mid;
    }
    int tend = min(t0 + 4, rn);
    for (int t = t0; t < tend; t++) {
      while (t >= r0o[lo + 1]) lo++;
      recs[tgt[lo] + (t - r0o[lo])] = staged[t];
    }
  }
}

// --- per-bucket passes -----------------------------------------------------
#define UDG 4
__global__ __launch_bounds__(1024) void k_degdinv(const unsigned int* __restrict__ recs,
                                                  const int* __restrict__ bases,
                                                  float* __restrict__ dinv, int N) {
  __shared__ int cnt[128];
  if (threadIdx.x < 128) cnt[threadIdx.x] = 0;
  __syncthreads();
  int k = blockIdx.x;
  int s0 = bases[k], n = bases[k + 1] - s0;
  const unsigned int* rp = recs + s0;
  int tid = threadIdx.x, BD = blockDim.x;
  for (int base = 0; base < n; base += BD * UDG) {
    unsigned int r[UDG]; int ok[UDG];
#pragma unroll
    for (int u = 0; u < UDG; u++) {
      int idx = base + u * BD + tid;
      ok[u] = idx < n;
      r[u] = ok[u] ? rp[idx] : 0u;
    }
#pragma unroll
    for (int u = 0; u < UDG; u++)
      if (ok[u]) atomicAdd(&cnt[r[u] & 127u], 1);
  }
  __syncthreads();
  if (threadIdx.x < 128) {
    int v = k * 128 + threadIdx.x;
    if (v < N) dinv[v] = rsqrtf((float)cnt[threadIdx.x] + 1.0f);
  }
}

// emits recq = (alphaQ, betaQ, region, dv-bits)
#define USA 4
__global__ __launch_bounds__(1024) void k_sA(const float* __restrict__ wsm,
                                             const unsigned int* __restrict__ recs,
                                             const int* __restrict__ bases,
                                             const float* __restrict__ dinv,
                                             uint4* __restrict__ recq, int N) {
  __shared__ float acc[128];
  __shared__ float ts[16];
  __shared__ int nt;
  if (threadIdx.x < 128) acc[threadIdx.x] = 0.f;
  if (threadIdx.x == 0) nt = (int)wsm[O_NT];
  if (threadIdx.x < 16) ts[threadIdx.x] = wsm[O_TS + threadIdx.x];
  __syncthreads();
  int k = blockIdx.x;
  int s0 = bases[k], n = bases[k + 1] - s0;
  const unsigned int* rp = recs + s0;
  int tid = threadIdx.x, BD = blockDim.x;
  for (int base = 0; base < n; base += BD * USA) {
    unsigned int r[USA]; int ok[USA];
#pragma unroll
    for (int u = 0; u < USA; u++) {
      int idx = base + u * BD + tid;
      ok[u] = idx < n;
      r[u] = ok[u] ? rp[idx] : 0u;
    }
    float dv[USA];
#pragma unroll
    for (int u = 0; u < USA; u++) dv[u] = ok[u] ? dinv[r[u] >> 7] : 0.f;
#pragma unroll
    for (int u = 0; u < USA; u++)
      if (ok[u]) atomicAdd(&acc[r[u] & 127u], dv[u]);
  }
  __syncthreads();
  if (threadIdx.x < 128) {
    int v = k * 128 + threadIdx.x;
    if (v < N) {
      float dv = dinv[v];
      float s = dv * (acc[threadIdx.x] + dv);
      int rr = 0;
      for (int i = 0; i < nt; i++) rr += (ts[i] < s) ? 1 : 0;
      float alpha = dv * s;
      uint4 q;
      q.x = (unsigned int)(alpha * QSCALE + 0.5f);
      q.y = (unsigned int)(dv * QSCALE + 0.5f);
      q.z = (unsigned int)rr;
      q.w = __float_as_uint(dv);
      recq[v] = q;
    }
  }
}

// one packed u64 LDS atomic per edge; decode to ABg planes
#define UAB 4
__global__ __launch_bounds__(1024) void k_ABacc(const unsigned int* __restrict__ recs,
                                                const int* __restrict__ bases,
                                                const uint4* __restrict__ recq,
                                                float* __restrict__ ABg, int N) {
  __shared__ unsigned long long Lu[128 * LSTR64];
  for (int i = threadIdx.x; i < 128 * LSTR64; i += blockDim.x) Lu[i] = 0ull;
  __syncthreads();
  int k = blockIdx.x;
  int s0 = bases[k], n = bases[k + 1] - s0;
  const unsigned int* rp = recs + s0;
  int tid = threadIdx.x, BD = blockDim.x;
  for (int base = 0; base < n; base += BD * UAB) {
    unsigned int r[UAB]; int ok[UAB];
#pragma unroll
    for (int u = 0; u < UAB; u++) {
      int idx = base + u * BD + tid;
      ok[u] = idx < n;
      r[u] = ok[u] ? rp[idx] : 0u;
    }
    uint4 q[UAB];
#pragma unroll
    for (int u = 0; u < UAB; u++) {
      q[u] = make_uint4(0u, 0u, 0u, 0u);
      if (ok[u]) q[u] = recq[r[u] >> 7];
    }
#pragma unroll
    for (int u = 0; u < UAB; u++) {
      if (ok[u]) {
        unsigned long long c = ((unsigned long long)q[u].x << 32) | (unsigned long long)q[u].y;
        atomicAdd(&Lu[(int)(r[u] & 127u) * LSTR64 + (int)q[u].z], c);
      }
    }
  }
  __syncthreads();
  float* out = ABg + (size_t)k * ABSTR;
  for (int i = tid; i < 34 * 128; i += BD) {
    int r = i >> 7, v = i & 127;
    unsigned long long w;
    float val;
    if (r < NREG) {
      w = Lu[v * LSTR64 + r];
      val = (float)((unsigned int)(w >> 32)) * INVQ;      // alpha plane
    } else {
      w = Lu[v * LSTR64 + (r - NREG)];
      val = (float)((unsigned int)(w & 0xFFFFFFFFull)) * INVQ;  // beta plane
    }
    out[i] = val;
  }
}

// per node: AB planes -> x2 -> x3 -> (ps, pd)
__global__ __launch_bounds__(256) void k_node2(const float* __restrict__ wsm,
                                               const float* __restrict__ ABg,
                                               const uint4* __restrict__ recq,
                                               float4* __restrict__ pspd, int N) {
  __shared__ float sU[NREG * 32], sW[NREG * 32], sB2[32], sWn[1024], sBn[32], sM[132];
  for (int i = threadIdx.x; i < NREG * 32; i += blockDim.x) {
    sU[i] = wsm[O_U + i];
    sW[i] = wsm[O_WWR + i];
  }
  for (int i = threadIdx.x; i < 1024; i += blockDim.x) sWn[i] = wsm[O_WN + i];
  if (threadIdx.x < 32) {
    sB2[threadIdx.x] = wsm[O_B2C + threadIdx.x];
    sBn[threadIdx.x] = wsm[O_BN + threadIdx.x];
  }
  for (int i = threadIdx.x; i < 132; i += blockDim.x) sM[i] = wsm[O_M + i];
  __syncthreads();
  int v = blockIdx.x * blockDim.x + threadIdx.x;
  if (v >= N) return;
  uint4 self = recq[v];
  float dv = __uint_as_float(self.w);
  float selfa = (float)self.x * INVQ;
  int sr = (int)self.z;
  const float* pb = ABg + (size_t)(v >> 7) * ABSTR + (v & 127);
  float A[NREG], B[NREG];
#pragma unroll
  for (int r = 0; r < NREG; r++) {
    A[r] = pb[r * 128];
    B[r] = pb[(NREG + r) * 128];
  }
  float acc[32];
#pragma unroll
  for (int j = 0; j < 32; j++) acc[j] = 0.f;
#pragma unroll
  for (int r = 0; r < NREG; r++) {
    float Ar = A[r] + ((r == sr) ? selfa : 0.f);
    float Br = B[r] + ((r == sr) ? dv : 0.f);
    if (Ar != 0.f || Br != 0.f) {
#pragma unroll
      for (int j = 0; j < 32; j++)
        acc[j] += Ar * sU[r * 32 + j] + Br * sW[r * 32 + j];
    }
  }
#pragma unroll
  for (int j = 0; j < 32; j++) acc[j] = relu_(dv * acc[j] + sB2[j]);  // x2
  float x3[32];
#pragma unroll
  for (int j = 0; j < 32; j++) {
    float a = sBn[j];
#pragma unroll
    for (int q2 = 0; q2 < 32; q2++) a += acc[q2] * sWn[q2 * 32 + j];
    x3[j] = relu_(a);
  }
  float ps0 = 0.f, ps1 = 0.f, pd0 = 0.f, pd1 = 0.f;
#pragma unroll
  for (int j = 0; j < 32; j++) {
    float x = x3[j];
    ps0 += x * sM[(2 + j) * 2 + 0];
    ps1 += x * sM[(2 + j) * 2 + 1];
    pd0 += x * sM[(34 + j) * 2 + 0];
    pd1 += x * sM[(34 + j) * 2 + 1];
  }
  pspd[v] = make_float4(ps0, ps1, pd0, pd1);
}

#define UE 8
__global__ __launch_bounds__(256) void k_edge(const float* __restrict__ wsm,
                                              const int* __restrict__ src,
                                              const int* __restrict__ dst,
                                              const void* __restrict__ ewraw,
                                              const void* __restrict__ ceraw,
                                              const float4* __restrict__ pspd,
                                              void* __restrict__ out,
                                              const int* __restrict__ mode, int E) {
  int e0 = (blockIdx.x * blockDim.x + threadIdx.x) * UE;
  bool bf = (*mode) != 0;
  float b0 = wsm[O_BIAS2 + 0], b1 = wsm[O_BIAS2 + 1];
  float M00 = wsm[O_M + 0], M01 = wsm[O_M + 1];
  float M10 = wsm[O_M + 2], M11 = wsm[O_M + 3];
  if (e0 + UE <= E) {
    int4 s4i[2], d4i[2];
    s4i[0] = ((const int4*)(src + e0))[0];
    s4i[1] = ((const int4*)(src + e0))[1];
    d4i[0] = ((const int4*)(dst + e0))[0];
    d4i[1] = ((const int4*)(dst + e0))[1];
    const int* s = (const int*)s4i;
    const int* d = (const int*)d4i;
    float4 sv[UE], dv4[UE];
#pragma unroll
    for (int u = 0; u < UE; u++) sv[u] = pspd[s[u]];
#pragma unroll
    for (int u = 0; u < UE; u++) dv4[u] = pspd[d[u]];
    float ewv[UE], cev[UE];
    if (bf) {
      uint4 ewp = *(const uint4*)((const unsigned short*)ewraw + e0);
      uint4 cep = *(const uint4*)((const unsigned short*)ceraw + e0);
      const unsigned int* ewu = (const unsigned int*)&ewp;
      const unsigned int* ceu = (const unsigned int*)&cep;
#pragma unroll
    for (int u = 0; u < UE; u++) {
        unsigned int w = ewu[u >> 1], c = ceu[u >> 1];
        unsigned short hw = (u & 1) ? (unsigned short)(w >> 16) : (unsigned short)(w & 0xFFFF);
        unsigned short hc = (u & 1) ? (unsigned short)(c >> 16) : (unsigned short)(c & 0xFFFF);
        ewv[u] = bf2f(hw);
        cev[u] = bf2f(hc);
      }
    } else {
#pragma unroll
      for (int u = 0; u < UE; u += 4) {
        float4 w = *(const float4*)((const float*)ewraw + e0 + u);
        float4 c = *(const float4*)((const float*)ceraw + e0 + u);
        ewv[u] = w.x; ewv[u+1] = w.y; ewv[u+2] = w.z; ewv[u+3] = w.w;
        cev[u] = c.x; cev[u+1] = c.y; cev[u+2] = c.z; cev[u+3] = c.w;
      }
    }
#pragma unroll
    for (int u = 0; u < UE; u++) {
      int e = e0 + u;
      float o0 = b0 + ewv[u] * M00 + cev[u] * M10 + sv[u].x + dv4[u].z;
      float o1 = b1 + ewv[u] * M01 + cev[u] * M11 + sv[u].y + dv4[u].w;
      if (bf) {
        unsigned int pk = ((unsigned int)f2bf(o1) << 16) | (unsigned int)f2bf(o0);
        ((unsigned int*)out)[e] = pk;
      } else {
        float2 r; r.x = o0; r.y = o1;
        ((float2*)out)[e] = r;
      }
    }
  } else {
    for (int e = e0; e < E; e++) {
      float ew = bf ? bf2f(((const unsigned short*)ewraw)[e]) : ((const float*)ewraw)[e];
      float ce = bf ? bf2f(((const unsigned short*)ceraw)[e]) : ((const float*)ceraw)[e];
      float4 sv = pspd[src[e]];
      float4 dv4 = pspd[dst[e]];
      float o0 = b0 + ew * M00 + ce * M10 + sv.x + dv4.z;
      float o1 = b1 + ew * M01 + ce * M11 + sv.y + dv4.w;
      if (bf) {
        unsigned int pk = ((unsigned int)f2bf(o1) << 16) | (unsigned int)f2bf(o0);
        ((unsigned int*)out)[e] = pk;
      } else {
        float2 r; r.x = o0; r.y = o1;
        ((float2*)out)[e] = r;
      }
    }
  }
}

extern "C" void kernel_launch(void* const* d_in, const int* in_sizes, int n_in,
                              void* d_out, int out_size, void* d_ws, size_t ws_size,
                              hipStream_t stream) {
  const int* eidx = (const int*)d_in[0];
  const int E = in_sizes[0] / 2;
  const int N = NNODES;
  const int* src = eidx;
  const int* dst = eidx + E;
  const int chunk = (E + FBC - 1) / FBC;

  char* ws = (char*)d_ws;
  size_t off = 0;
  size_t off_mode = off; off += 256;
  size_t off_wsm  = off; off += (size_t)WSM_TOTAL * 4;
  off = (off + 255) & ~(size_t)255;
  size_t off_cnts = off; off += (size_t)KB * FBC * 4;
  size_t off_pfx  = off; off += (size_t)KB * FBC * 4;
  size_t off_tot  = off; off += (size_t)KB * 4;
  off = (off + 255) & ~(size_t)255;
  size_t off_base = off; off += (size_t)(KB + 1) * 4;
  off = (off + 255) & ~(size_t)255;
  size_t off_recs = off; off += (size_t)E * 4;
  size_t off_dinv = off; off += (size_t)N * 4;
  off = (off + 255) & ~(size_t)255;
  size_t off_recq = off; off += (size_t)N * 16;
  size_t off_pspd = off; off += (size_t)N * 16;
  off = (off + 255) & ~(size_t)255;
  size_t off_ABg  = off; off += (size_t)KB * ABSTR * 4;
  if (ws_size < off) return;

  int*          mode   = (int*)(ws + off_mode);
  float*        wsm    = (float*)(ws + off_wsm);
  int*          counts = (int*)(ws + off_cnts);
  int*          prefx  = (int*)(ws + off_pfx);
  int*          totals = (int*)(ws + off_tot);
  int*          bases  = (int*)(ws + off_base);
  unsigned int* recs   = (unsigned int*)(ws + off_recs);
  float*        dinv   = (float*)(ws + off_dinv);
  uint4*        recq   = (uint4*)(ws + off_recq);
  float4*       pspd   = (float4*)(ws + off_pspd);
  float*        ABg    = (float*)(ws + off_ABg);

  k_setup<<<1, 1024, 0, stream>>>((const unsigned short*)d_in[1],
      d_in[4], d_in[5], d_in[6], d_in[7], d_in[8], d_in[9], d_in[10],
      d_in[11], d_in[12], d_in[13], d_in[14], d_in[15], mode, wsm);
  k_hist<<<FBC, 1024, 0, stream>>>(dst, counts, E, chunk);
  k_scanA<<<KB, FBC, 0, stream>>>(counts, prefx, totals);
  k_scanB<<<1, 1024, 0, stream>>>(totals, bases);
  k_fillsort<<<FBC, 1024, 0, stream>>>(src, dst, counts, prefx, bases, recs, E, chunk);
  k_degdinv<<<KB, 1024, 0, stream>>>(recs, bases, dinv, N);
  k_sA<<<KB, 1024, 0, stream>>>(wsm, recs, bases, dinv, recq, N);
  k_ABacc<<<KB, 1024, 0, stream>>>(recs, bases, recq, ABg, N);
  k_node2<<<(N + 255) / 256, 256, 0, stream>>>(wsm, ABg, recq, pspd, N);
  {
    long long tot = ((long long)E + UE - 1) / UE;
    int blocks = (int)((tot + 255) / 256);
    k_edge<<<blocks, 256, 0, stream>>>(wsm, src, dst, d_in[1], d_in[2],
                                       pspd, d_out, mode, E);
  }
}

// Round 13
// 174.803 us; speedup vs baseline: 1.6726x; 1.0590x over previous
//
#include <hip/hip_runtime.h>
#include <hip/hip_bf16.h>

// ---------------------------------------------------------------------------
// KEPCE_GCN, round 13 = R12 + k_edge store-coalescing fix.
//  R12 counters: k_edge WRITE_SIZE 35.4MB for 12.8MB output (2.77x) -- UE=8
//  made per-instr stores 4B/lane at 32B lane stride (partial sectors).
//  Now: UE=4, one uint4 store/thread (lane-contiguous), ps/pd split into
//  float2 tables (8B gathers), launch_bounds(256,8).
// ---------------------------------------------------------------------------

#define NNODES 100000
#define NREG   17
#define KB     782          // buckets = ceil(100000/128)
#define FBC    256          // chunk blocks
#define STCAP  12544        // LDS staging capacity (>= chunk)
#define LSTR64 19           // u64 row stride for AB planes (17 + pad)
#define ABSTR  4352         // 34*128 floats per bucket in ABg
#define QSCALE 4194304.0f   // 2^22
#define INVQ   2.384185791015625e-7f

// wsm element offsets (f32)
#define O_W0    0
#define O_B0    8
#define O_W1    16
#define O_B1    144
#define O_W2    160
#define O_B2C   672
#define O_WN    704
#define O_BN    1728
#define O_WE1   1760
#define O_BE1   3872
#define O_WE2   3904
#define O_BE2   3968
#define WSM_N   3970
#define O_H0    3972
#define O_TS    3992
#define O_NT    4008
#define O_U     4016   // 17*32
#define O_WWR   4560   // 17*32
#define O_M     5104   // 66*2
#define O_BIAS2 5236
#define WSM_TOTAL 6144

__device__ __forceinline__ float bf2f(unsigned short u) {
  union { float f; unsigned int i; } v; v.i = ((unsigned int)u) << 16; return v.f;
}
__device__ __forceinline__ unsigned short f2bf(float f) {
  union { float f; unsigned int i; } v; v.f = f;
  unsigned int x = v.i;
  return (unsigned short)((x + 0x7FFFu + ((x >> 16) & 1u)) >> 16);
}
__device__ __forceinline__ float relu_(float x) { return x > 0.f ? x : 0.f; }

// fused: dtype detect + weight convert + derived-tensor prep (one block)
__global__ __launch_bounds__(1024) void k_setup(
    const unsigned short* ewraw,
    const void* p0, const void* p1, const void* p2, const void* p3,
    const void* p4, const void* p5, const void* p6, const void* p7,
    const void* p8, const void* p9, const void* p10, const void* p11,
    int* mode, float* wsm) {
  __shared__ int cnt, smode, snt;
  __shared__ float h0[16], ts[16];
  int t = threadIdx.x;
  if (t == 0) cnt = 0;
  __syncthreads();
  int ok = 0;
  for (int i = t; i < 512; i += blockDim.x) {
    unsigned short h = ewraw[i];
    int e = (h >> 7) & 0xFF;
    if (!(h & 0x8000) && e >= 0x70 && e <= 0x7E) ok++;
  }
  atomicAdd(&cnt, ok);
  __syncthreads();
  if (t == 0) { smode = (cnt >= 400) ? 1 : 0; *mode = smode; }
  __syncthreads();
  int bf = smode;
  const void* ptrs[12] = {p0,p1,p2,p3,p4,p5,p6,p7,p8,p9,p10,p11};
  const int offs[13] = {O_W0,O_B0,O_W1,O_B1,O_W2,O_B2C,O_WN,O_BN,O_WE1,O_BE1,O_WE2,O_BE2,WSM_N};
  for (int idx = t; idx < WSM_N; idx += blockDim.x) {
    int seg = 0;
    while (idx >= offs[seg + 1]) seg++;
    int k = idx - offs[seg];
    wsm[idx] = bf ? bf2f(((const unsigned short*)ptrs[seg])[k])
                  : ((const float*)ptrs[seg])[k];
  }
  __syncthreads();
  if (t < 16) {
    float acc = 0.f;
    for (int j = 0; j < 8; j++)
      acc += (wsm[O_W0 + j] + wsm[O_B0 + j]) * wsm[O_W1 + j * 16 + t];
    h0[t] = acc;
    wsm[O_H0 + t] = acc;
  }
  __syncthreads();
  if (t == 0) {
    int n = 0;
    for (int j = 0; j < 16; j++) {
      float h = h0[j], b = wsm[O_B1 + j];
      if (h != 0.f) {
        float tj = -b / h;
        if (tj > 0.f) {
          int p = n++;
          while (p > 0 && ts[p - 1] > tj) { ts[p] = ts[p - 1]; p--; }
          ts[p] = tj;
        }
      }
    }
    snt = n;
    wsm[O_NT] = (float)n;
    for (int i = 0; i < n; i++) wsm[O_TS + i] = ts[i];
  }
  __syncthreads();
  int n = snt;
  for (int r = 0; r <= n; r++) {
    float srep;
    if (n == 0) srep = 1.f;
    else if (r == 0) srep = ts[0] * 0.5f;
    else if (r == n) srep = ts[n - 1] * 2.f + 1.f;
    else srep = 0.5f * (ts[r - 1] + ts[r]);
    if (t < 32) {
      float uu = 0.f, ww = 0.f;
      for (int j = 0; j < 16; j++) {
        float h = h0[j], b = wsm[O_B1 + j];
        if (srep * h + b > 0.f) {
          float w2 = wsm[O_W2 + j * 32 + t];
          uu += h * w2;
          ww += b * w2;
        }
      }
      wsm[O_U + r * 32 + t] = uu;
      wsm[O_WWR + r * 32 + t] = ww;
    }
  }
  for (int i = t; i < 66; i += blockDim.x) {
    float m0 = 0.f, m1 = 0.f;
    for (int k = 0; k < 32; k++) {
      float w1 = wsm[O_WE1 + i * 32 + k];
      m0 += w1 * wsm[O_WE2 + k * 2 + 0];
      m1 += w1 * wsm[O_WE2 + k * 2 + 1];
    }
    wsm[O_M + i * 2 + 0] = m0;
    wsm[O_M + i * 2 + 1] = m1;
  }
  if (t == 0) {
    float b20 = wsm[O_BE2 + 0], b21 = wsm[O_BE2 + 1];
    for (int k = 0; k < 32; k++) {
      b20 += wsm[O_BE1 + k] * wsm[O_WE2 + k * 2 + 0];
      b21 += wsm[O_BE1 + k] * wsm[O_WE2 + k * 2 + 1];
    }
    wsm[O_BIAS2 + 0] = b20;
    wsm[O_BIAS2 + 1] = b21;
  }
}

// --- bucket radix partition (atomic-free globally) -------------------------
__global__ __launch_bounds__(1024) void k_hist(const int* __restrict__ dst,
                                               int* __restrict__ counts,
                                               int E, int chunk) {
  __shared__ int h[KB];
  for (int i = threadIdx.x; i < KB; i += blockDim.x) h[i] = 0;
  __syncthreads();
  int b = blockIdx.x;
  int start = b * chunk, end = min(E, start + chunk);
  int tid = threadIdx.x, BD = blockDim.x;
  for (int base = start; base < end; base += BD * 4) {
#pragma unroll
    for (int u = 0; u < 4; u++) {
      int idx = base + u * BD + tid;
      if (idx < end) atomicAdd(&h[dst[idx] >> 7], 1);
    }
  }
  __syncthreads();
  for (int i = threadIdx.x; i < KB; i += blockDim.x)
    counts[i * FBC + b] = h[i];
}

__global__ __launch_bounds__(FBC) void k_scanA(const int* __restrict__ counts,
                                               int* __restrict__ prefx,
                                               int* __restrict__ totals) {
  __shared__ int s[FBC];
  int k = blockIdx.x, t = threadIdx.x;
  int v = counts[k * FBC + t];
  s[t] = v;
  __syncthreads();
  for (int off = 1; off < FBC; off <<= 1) {
    int add = (t >= off) ? s[t - off] : 0;
    __syncthreads();
    s[t] += add;
    __syncthreads();
  }
  prefx[k * FBC + t] = s[t] - v;
  if (t == FBC - 1) totals[k] = s[t];
}

__global__ __launch_bounds__(1024) void k_scanB(const int* __restrict__ totals,
                                                int* __restrict__ bases) {
  __shared__ int s[1024];
  int t = threadIdx.x;
  int v = (t < KB) ? totals[t] : 0;
  s[t] = v;
  __syncthreads();
  for (int off = 1; off < 1024; off <<= 1) {
    int add = (t >= off) ? s[t - off] : 0;
    __syncthreads();
    s[t] += add;
    __syncthreads();
  }
  if (t < KB) bases[t] = s[t] - v;
  if (t == KB - 1) bases[KB] = s[t];
}

__global__ __launch_bounds__(1024) void k_fillsort(const int* __restrict__ src,
                                                   const int* __restrict__ dst,
                                                   const int* __restrict__ counts,
                                                   const int* __restrict__ prefx,
                                                   const int* __restrict__ bases,
                                                   unsigned int* __restrict__ recs,
                                                   int E, int chunk) {
  __shared__ unsigned int staged[STCAP];
  __shared__ int cnt[KB], r0o[KB + 1], r0c[KB], tgt[KB];
  int b = blockIdx.x;
  int tid = threadIdx.x, BD = blockDim.x;
  for (int i = tid; i < KB; i += BD) {
    cnt[i] = counts[i * FBC + b];
    tgt[i] = bases[i] + prefx[i * FBC + b];
  }
  __syncthreads();
  int start = b * chunk, end = min(E, start + chunk);
  int rn = end - start;
  if (tid < KB) r0o[tid] = cnt[tid];
  __syncthreads();
  for (int off = 1; off < KB; off <<= 1) {
    int add = 0;
    if (tid < KB && tid >= off) add = r0o[tid - off];
    __syncthreads();
    if (tid < KB) r0o[tid] += add;
    __syncthreads();
  }
  if (tid < KB) r0c[tid] = r0o[tid] - cnt[tid];
  __syncthreads();
  if (tid < KB) r0o[tid] = r0c[tid];
  if (tid == 0) r0o[KB] = rn;
  __syncthreads();
  for (int base = 0; base < rn; base += BD * 4) {
#pragma unroll
    for (int u = 0; u < 4; u++) {
      int idx = base + u * BD + tid;
      if (idx < rn) {
        int d = dst[start + idx];
        int s = src[start + idx];
        int pos = atomicAdd(&r0c[d >> 7], 1);
        staged[pos] = ((unsigned int)s << 7) | (unsigned int)(d & 127);
      }
    }
  }
  __syncthreads();
  int nquads = (rn + 3) >> 2;
  for (int q = tid; q < nquads; q += BD) {
    int t0 = q * 4;
    int lo = 0, hi = KB;
    while (hi - lo > 1) {
      int mid = (lo + hi) >> 1;
      if (r0o[mid] <= t0) lo = mid; else hi = mid;
    }
    int tend = min(t0 + 4, rn);
    for (int t = t0; t < tend; t++) {
      while (t >= r0o[lo + 1]) lo++;
      recs[tgt[lo] + (t - r0o[lo])] = staged[t];
    }
  }
}

// --- per-bucket passes -----------------------------------------------------
#define UDG 4
__global__ __launch_bounds__(1024) void k_degdinv(const unsigned int* __restrict__ recs,
                                                  const int* __restrict__ bases,
                                                  float* __restrict__ dinv, int N) {
  __shared__ int cnt[128];
  if (threadIdx.x < 128) cnt[threadIdx.x] = 0;
  __syncthreads();
  int k = blockIdx.x;
  int s0 = bases[k], n = bases[k + 1] - s0;
  const unsigned int* rp = recs + s0;
  int tid = threadIdx.x, BD = blockDim.x;
  for (int base = 0; base < n; base += BD * UDG) {
    unsigned int r[UDG]; int ok[UDG];
#pragma unroll
    for (int u = 0; u < UDG; u++) {
      int idx = base + u * BD + tid;
      ok[u] = idx < n;
      r[u] = ok[u] ? rp[idx] : 0u;
    }
#pragma unroll
    for (int u = 0; u < UDG; u++)
      if (ok[u]) atomicAdd(&cnt[r[u] & 127u], 1);
  }
  __syncthreads();
  if (threadIdx.x < 128) {
    int v = k * 128 + threadIdx.x;
    if (v < N) dinv[v] = rsqrtf((float)cnt[threadIdx.x] + 1.0f);
  }
}

// emits recq = (alphaQ, betaQ, region, dv-bits)
#define USA 4
__global__ __launch_bounds__(1024) void k_sA(const float* __restrict__ wsm,
                                             const unsigned int* __restrict__ recs,
                                             const int* __restrict__ bases,
                                             const float* __restrict__ dinv,
                                             uint4* __restrict__ recq, int N) {
  __shared__ float acc[128];
  __shared__ float ts[16];
  __shared__ int nt;
  if (threadIdx.x < 128) acc[threadIdx.x] = 0.f;
  if (threadIdx.x == 0) nt = (int)wsm[O_NT];
  if (threadIdx.x < 16) ts[threadIdx.x] = wsm[O_TS + threadIdx.x];
  __syncthreads();
  int k = blockIdx.x;
  int s0 = bases[k], n = bases[k + 1] - s0;
  const unsigned int* rp = recs + s0;
  int tid = threadIdx.x, BD = blockDim.x;
  for (int base = 0; base < n; base += BD * USA) {
    unsigned int r[USA]; int ok[USA];
#pragma unroll
    for (int u = 0; u < USA; u++) {
      int idx = base + u * BD + tid;
      ok[u] = idx < n;
      r[u] = ok[u] ? rp[idx] : 0u;
    }
    float dv[USA];
#pragma unroll
    for (int u = 0; u < USA; u++) dv[u] = ok[u] ? dinv[r[u] >> 7] : 0.f;
#pragma unroll
    for (int u = 0; u < USA; u++)
      if (ok[u]) atomicAdd(&acc[r[u] & 127u], dv[u]);
  }
  __syncthreads();
  if (threadIdx.x < 128) {
    int v = k * 128 + threadIdx.x;
    if (v < N) {
      float dv = dinv[v];
      float s = dv * (acc[threadIdx.x] + dv);
      int rr = 0;
      for (int i = 0; i < nt; i++) rr += (ts[i] < s) ? 1 : 0;
      float alpha = dv * s;
      uint4 q;
      q.x = (unsigned int)(alpha * QSCALE + 0.5f);
      q.y = (unsigned int)(dv * QSCALE + 0.5f);
      q.z = (unsigned int)rr;
      q.w = __float_as_uint(dv);
      recq[v] = q;
    }
  }
}

// one packed u64 LDS atomic per edge; decode to ABg planes
#define UAB 4
__global__ __launch_bounds__(1024) void k_ABacc(const unsigned int* __restrict__ recs,
                                                const int* __restrict__ bases,
                                                const uint4* __restrict__ recq,
                                                float* __restrict__ ABg, int N) {
  __shared__ unsigned long long Lu[128 * LSTR64];
  for (int i = threadIdx.x; i < 128 * LSTR64; i += blockDim.x) Lu[i] = 0ull;
  __syncthreads();
  int k = blockIdx.x;
  int s0 = bases[k], n = bases[k + 1] - s0;
  const unsigned int* rp = recs + s0;
  int tid = threadIdx.x, BD = blockDim.x;
  for (int base = 0; base < n; base += BD * UAB) {
    unsigned int r[UAB]; int ok[UAB];
#pragma unroll
    for (int u = 0; u < UAB; u++) {
      int idx = base + u * BD + tid;
      ok[u] = idx < n;
      r[u] = ok[u] ? rp[idx] : 0u;
    }
    uint4 q[UAB];
#pragma unroll
    for (int u = 0; u < UAB; u++) {
      q[u] = make_uint4(0u, 0u, 0u, 0u);
      if (ok[u]) q[u] = recq[r[u] >> 7];
    }
#pragma unroll
    for (int u = 0; u < UAB; u++) {
      if (ok[u]) {
        unsigned long long c = ((unsigned long long)q[u].x << 32) | (unsigned long long)q[u].y;
        atomicAdd(&Lu[(int)(r[u] & 127u) * LSTR64 + (int)q[u].z], c);
      }
    }
  }
  __syncthreads();
  float* out = ABg + (size_t)k * ABSTR;
  for (int i = tid; i < 34 * 128; i += BD) {
    int r = i >> 7, v = i & 127;
    unsigned long long w;
    float val;
    if (r < NREG) {
      w = Lu[v * LSTR64 + r];
      val = (float)((unsigned int)(w >> 32)) * INVQ;
    } else {
      w = Lu[v * LSTR64 + (r - NREG)];
      val = (float)((unsigned int)(w & 0xFFFFFFFFull)) * INVQ;
    }
    out[i] = val;
  }
}

// per node: AB planes -> x2 -> x3 -> (ps, pd) split tables
__global__ __launch_bounds__(256) void k_node2(const float* __restrict__ wsm,
                                               const float* __restrict__ ABg,
                                               const uint4* __restrict__ recq,
                                               float2* __restrict__ ps2,
                                               float2* __restrict__ pd2, int N) {
  __shared__ float sU[NREG * 32], sW[NREG * 32], sB2[32], sWn[1024], sBn[32], sM[132];
  for (int i = threadIdx.x; i < NREG * 32; i += blockDim.x) {
    sU[i] = wsm[O_U + i];
    sW[i] = wsm[O_WWR + i];
  }
  for (int i = threadIdx.x; i < 1024; i += blockDim.x) sWn[i] = wsm[O_WN + i];
  if (threadIdx.x < 32) {
    sB2[threadIdx.x] = wsm[O_B2C + threadIdx.x];
    sBn[threadIdx.x] = wsm[O_BN + threadIdx.x];
  }
  for (int i = threadIdx.x; i < 132; i += blockDim.x) sM[i] = wsm[O_M + i];
  __syncthreads();
  int v = blockIdx.x * blockDim.x + threadIdx.x;
  if (v >= N) return;
  uint4 self = recq[v];
  float dv = __uint_as_float(self.w);
  float selfa = (float)self.x * INVQ;
  int sr = (int)self.z;
  const float* pb = ABg + (size_t)(v >> 7) * ABSTR + (v & 127);
  float A[NREG], B[NREG];
#pragma unroll
  for (int r = 0; r < NREG; r++) {
    A[r] = pb[r * 128];
    B[r] = pb[(NREG + r) * 128];
  }
  float acc[32];
#pragma unroll
  for (int j = 0; j < 32; j++) acc[j] = 0.f;
#pragma unroll
  for (int r = 0; r < NREG; r++) {
    float Ar = A[r] + ((r == sr) ? selfa : 0.f);
    float Br = B[r] + ((r == sr) ? dv : 0.f);
    if (Ar != 0.f || Br != 0.f) {
#pragma unroll
      for (int j = 0; j < 32; j++)
        acc[j] += Ar * sU[r * 32 + j] + Br * sW[r * 32 + j];
    }
  }
#pragma unroll
  for (int j = 0; j < 32; j++) acc[j] = relu_(dv * acc[j] + sB2[j]);  // x2
  float x3[32];
#pragma unroll
  for (int j = 0; j < 32; j++) {
    float a = sBn[j];
#pragma unroll
    for (int q2 = 0; q2 < 32; q2++) a += acc[q2] * sWn[q2 * 32 + j];
    x3[j] = relu_(a);
  }
  float ps0 = 0.f, ps1 = 0.f, pd0 = 0.f, pd1 = 0.f;
#pragma unroll
  for (int j = 0; j < 32; j++) {
    float x = x3[j];
    ps0 += x * sM[(2 + j) * 2 + 0];
    ps1 += x * sM[(2 + j) * 2 + 1];
    pd0 += x * sM[(34 + j) * 2 + 0];
    pd1 += x * sM[(34 + j) * 2 + 1];
  }
  ps2[v] = make_float2(ps0, ps1);
  pd2[v] = make_float2(pd0, pd1);
}

#define UE 4
__global__ __launch_bounds__(256, 8) void k_edge(const float* __restrict__ wsm,
                                                 const int* __restrict__ src,
                                                 const int* __restrict__ dst,
                                                 const void* __restrict__ ewraw,
                                                 const void* __restrict__ ceraw,
                                                 const float2* __restrict__ ps2,
                                                 const float2* __restrict__ pd2,
                                                 void* __restrict__ out,
                                                 const int* __restrict__ mode, int E) {
  int e0 = (blockIdx.x * blockDim.x + threadIdx.x) * UE;
  bool bf = (*mode) != 0;
  float b0 = wsm[O_BIAS2 + 0], b1 = wsm[O_BIAS2 + 1];
  float M00 = wsm[O_M + 0], M01 = wsm[O_M + 1];
  float M10 = wsm[O_M + 2], M11 = wsm[O_M + 3];
  if (e0 + UE <= E) {
    int4 s4i = *(const int4*)(src + e0);
    int4 d4i = *(const int4*)(dst + e0);
    const int* s = (const int*)&s4i;
    const int* d = (const int*)&d4i;
    float2 sv[UE], dv2[UE];
#pragma unroll
    for (int u = 0; u < UE; u++) sv[u] = ps2[s[u]];
#pragma unroll
    for (int u = 0; u < UE; u++) dv2[u] = pd2[d[u]];
    float ewv[UE], cev[UE];
    if (bf) {
      uint2 ewp = *(const uint2*)((const unsigned short*)ewraw + e0);
      uint2 cep = *(const uint2*)((const unsigned short*)ceraw + e0);
      const unsigned int* ewu = (const unsigned int*)&ewp;
      const unsigned int* ceu = (const unsigned int*)&cep;
#pragma unroll
      for (int u = 0; u < UE; u++) {
        unsigned int w = ewu[u >> 1], c = ceu[u >> 1];
        unsigned short hw = (u & 1) ? (unsigned short)(w >> 16) : (unsigned short)(w & 0xFFFF);
        unsigned short hc = (u & 1) ? (unsigned short)(c >> 16) : (unsigned short)(c & 0xFFFF);
        ewv[u] = bf2f(hw);
        cev[u] = bf2f(hc);
      }
    } else {
      float4 w = *(const float4*)((const float*)ewraw + e0);
      float4 c = *(const float4*)((const float*)ceraw + e0);
      ewv[0] = w.x; ewv[1] = w.y; ewv[2] = w.z; ewv[3] = w.w;
      cev[0] = c.x; cev[1] = c.y; cev[2] = c.z; cev[3] = c.w;
    }
    float o0[UE], o1[UE];
#pragma unroll
    for (int u = 0; u < UE; u++) {
      o0[u] = b0 + ewv[u] * M00 + cev[u] * M10 + sv[u].x + dv2[u].x;
      o1[u] = b1 + ewv[u] * M01 + cev[u] * M11 + sv[u].y + dv2[u].y;
    }
    if (bf) {
      uint4 pk;
      pk.x = ((unsigned int)f2bf(o1[0]) << 16) | (unsigned int)f2bf(o0[0]);
      pk.y = ((unsigned int)f2bf(o1[1]) << 16) | (unsigned int)f2bf(o0[1]);
      pk.z = ((unsigned int)f2bf(o1[2]) << 16) | (unsigned int)f2bf(o0[2]);
      pk.w = ((unsigned int)f2bf(o1[3]) << 16) | (unsigned int)f2bf(o0[3]);
      *(uint4*)((unsigned int*)out + e0) = pk;      // 16B/lane contiguous
    } else {
      float4 w0, w1;
      w0.x = o0[0]; w0.y = o1[0]; w0.z = o0[1]; w0.w = o1[1];
      w1.x = o0[2]; w1.y = o1[2]; w1.z = o0[3]; w1.w = o1[3];
      float* ob = (float*)out + (size_t)e0 * 2;
      *(float4*)ob = w0;
      *(float4*)(ob + 4) = w1;
    }
  } else {
    for (int e = e0; e < E; e++) {
      float ew = bf ? bf2f(((const unsigned short*)ewraw)[e]) : ((const float*)ewraw)[e];
      float ce = bf ? bf2f(((const unsigned short*)ceraw)[e]) : ((const float*)ceraw)[e];
      float2 sv = ps2[src[e]];
      float2 dv2 = pd2[dst[e]];
      float o0 = b0 + ew * M00 + ce * M10 + sv.x + dv2.x;
      float o1 = b1 + ew * M01 + ce * M11 + sv.y + dv2.y;
      if (bf) {
        unsigned int pk = ((unsigned int)f2bf(o1) << 16) | (unsigned int)f2bf(o0);
        ((unsigned int*)out)[e] = pk;
      } else {
        float2 r; r.x = o0; r.y = o1;
        ((float2*)out)[e] = r;
      }
    }
  }
}

extern "C" void kernel_launch(void* const* d_in, const int* in_sizes, int n_in,
                              void* d_out, int out_size, void* d_ws, size_t ws_size,
                              hipStream_t stream) {
  const int* eidx = (const int*)d_in[0];
  const int E = in_sizes[0] / 2;
  const int N = NNODES;
  const int* src = eidx;
  const int* dst = eidx + E;
  const int chunk = (E + FBC - 1) / FBC;

  char* ws = (char*)d_ws;
  size_t off = 0;
  size_t off_mode = off; off += 256;
  size_t off_wsm  = off; off += (size_t)WSM_TOTAL * 4;
  off = (off + 255) & ~(size_t)255;
  size_t off_cnts = off; off += (size_t)KB * FBC * 4;
  size_t off_pfx  = off; off += (size_t)KB * FBC * 4;
  size_t off_tot  = off; off += (size_t)KB * 4;
  off = (off + 255) & ~(size_t)255;
  size_t off_base = off; off += (size_t)(KB + 1) * 4;
  off = (off + 255) & ~(size_t)255;
  size_t off_recs = off; off += (size_t)E * 4;
  size_t off_dinv = off; off += (size_t)N * 4;
  off = (off + 255) & ~(size_t)255;
  size_t off_recq = off; off += (size_t)N * 16;
  size_t off_ps2  = off; off += (size_t)N * 8;
  size_t off_pd2  = off; off += (size_t)N * 8;
  off = (off + 255) & ~(size_t)255;
  size_t off_ABg  = off; off += (size_t)KB * ABSTR * 4;
  if (ws_size < off) return;

  int*          mode   = (int*)(ws + off_mode);
  float*        wsm    = (float*)(ws + off_wsm);
  int*          counts = (int*)(ws + off_cnts);
  int*          prefx  = (int*)(ws + off_pfx);
  int*          totals = (int*)(ws + off_tot);
  int*          bases  = (int*)(ws + off_base);
  unsigned int* recs   = (unsigned int*)(ws + off_recs);
  float*        dinv   = (float*)(ws + off_dinv);
  uint4*        recq   = (uint4*)(ws + off_recq);
  float2*       ps2    = (float2*)(ws + off_ps2);
  float2*       pd2    = (float2*)(ws + off_pd2);
  float*        ABg    = (float*)(ws + off_ABg);

  k_setup<<<1, 1024, 0, stream>>>((const unsigned short*)d_in[1],
      d_in[4], d_in[5], d_in[6], d_in[7], d_in[8], d_in[9], d_in[10],
      d_in[11], d_in[12], d_in[13], d_in[14], d_in[15], mode, wsm);
  k_hist<<<FBC, 1024, 0, stream>>>(dst, counts, E, chunk);
  k_scanA<<<KB, FBC, 0, stream>>>(counts, prefx, totals);
  k_scanB<<<1, 1024, 0, stream>>>(totals, bases);
  k_fillsort<<<FBC, 1024, 0, stream>>>(src, dst, counts, prefx, bases, recs, E, chunk);
  k_degdinv<<<KB, 1024, 0, stream>>>(recs, bases, dinv, N);
  k_sA<<<KB, 1024, 0, stream>>>(wsm, recs, bases, dinv, recq, N);
  k_ABacc<<<KB, 1024, 0, stream>>>(recs, bases, recq, ABg, N);
  k_node2<<<(N + 255) / 256, 256, 0, stream>>>(wsm, ABg, recq, ps2, pd2, N);
  {
    long long tot = ((long long)E + UE - 1) / UE;
    int blocks = (int)((tot + 255) / 256);
    k_edge<<<blocks, 256, 0, stream>>>(wsm, src, dst, d_in[1], d_in[2],
                                       ps2, pd2, d_out, mode, E);
  }
}

// Round 14
// 171.263 us; speedup vs baseline: 1.7072x; 1.0207x over previous
//
#include <hip/hip_runtime.h>
#include <hip/hip_bf16.h>

// ---------------------------------------------------------------------------
// KEPCE_GCN, round 14 = R13 + three independent fixes:
//  - k_edge: launch_bounds(256,4) (VGPR 20 -> ~44) so all 8 random gathers
//    stay in flight (R13 was gather-serialized: VALUBusy 2.4%, HBM 17%).
//  - k_hist / k_fillsort: int4 vectorized edge-index reads (4 VMEM -> 1).
// ---------------------------------------------------------------------------

#define NNODES 100000
#define NREG   17
#define KB     782          // buckets = ceil(100000/128)
#define FBC    256          // chunk blocks
#define STCAP  12544        // LDS staging capacity (>= chunk)
#define LSTR64 19           // u64 row stride for AB planes (17 + pad)
#define ABSTR  4352         // 34*128 floats per bucket in ABg
#define QSCALE 4194304.0f   // 2^22
#define INVQ   2.384185791015625e-7f

// wsm element offsets (f32)
#define O_W0    0
#define O_B0    8
#define O_W1    16
#define O_B1    144
#define O_W2    160
#define O_B2C   672
#define O_WN    704
#define O_BN    1728
#define O_WE1   1760
#define O_BE1   3872
#define O_WE2   3904
#define O_BE2   3968
#define WSM_N   3970
#define O_H0    3972
#define O_TS    3992
#define O_NT    4008
#define O_U     4016   // 17*32
#define O_WWR   4560   // 17*32
#define O_M     5104   // 66*2
#define O_BIAS2 5236
#define WSM_TOTAL 6144

__device__ __forceinline__ float bf2f(unsigned short u) {
  union { float f; unsigned int i; } v; v.i = ((unsigned int)u) << 16; return v.f;
}
__device__ __forceinline__ unsigned short f2bf(float f) {
  union { float f; unsigned int i; } v; v.f = f;
  unsigned int x = v.i;
  return (unsigned short)((x + 0x7FFFu + ((x >> 16) & 1u)) >> 16);
}
__device__ __forceinline__ float relu_(float x) { return x > 0.f ? x : 0.f; }

// fused: dtype detect + weight convert + derived-tensor prep (one block)
__global__ __launch_bounds__(1024) void k_setup(
    const unsigned short* ewraw,
    const void* p0, const void* p1, const void* p2, const void* p3,
    const void* p4, const void* p5, const void* p6, const void* p7,
    const void* p8, const void* p9, const void* p10, const void* p11,
    int* mode, float* wsm) {
  __shared__ int cnt, smode, snt;
  __shared__ float h0[16], ts[16];
  int t = threadIdx.x;
  if (t == 0) cnt = 0;
  __syncthreads();
  int ok = 0;
  for (int i = t; i < 512; i += blockDim.x) {
    unsigned short h = ewraw[i];
    int e = (h >> 7) & 0xFF;
    if (!(h & 0x8000) && e >= 0x70 && e <= 0x7E) ok++;
  }
  atomicAdd(&cnt, ok);
  __syncthreads();
  if (t == 0) { smode = (cnt >= 400) ? 1 : 0; *mode = smode; }
  __syncthreads();
  int bf = smode;
  const void* ptrs[12] = {p0,p1,p2,p3,p4,p5,p6,p7,p8,p9,p10,p11};
  const int offs[13] = {O_W0,O_B0,O_W1,O_B1,O_W2,O_B2C,O_WN,O_BN,O_WE1,O_BE1,O_WE2,O_BE2,WSM_N};
  for (int idx = t; idx < WSM_N; idx += blockDim.x) {
    int seg = 0;
    while (idx >= offs[seg + 1]) seg++;
    int k = idx - offs[seg];
    wsm[idx] = bf ? bf2f(((const unsigned short*)ptrs[seg])[k])
                  : ((const float*)ptrs[seg])[k];
  }
  __syncthreads();
  if (t < 16) {
    float acc = 0.f;
    for (int j = 0; j < 8; j++)
      acc += (wsm[O_W0 + j] + wsm[O_B0 + j]) * wsm[O_W1 + j * 16 + t];
    h0[t] = acc;
    wsm[O_H0 + t] = acc;
  }
  __syncthreads();
  if (t == 0) {
    int n = 0;
    for (int j = 0; j < 16; j++) {
      float h = h0[j], b = wsm[O_B1 + j];
      if (h != 0.f) {
        float tj = -b / h;
        if (tj > 0.f) {
          int p = n++;
          while (p > 0 && ts[p - 1] > tj) { ts[p] = ts[p - 1]; p--; }
          ts[p] = tj;
        }
      }
    }
    snt = n;
    wsm[O_NT] = (float)n;
    for (int i = 0; i < n; i++) wsm[O_TS + i] = ts[i];
  }
  __syncthreads();
  int n = snt;
  for (int r = 0; r <= n; r++) {
    float srep;
    if (n == 0) srep = 1.f;
    else if (r == 0) srep = ts[0] * 0.5f;
    else if (r == n) srep = ts[n - 1] * 2.f + 1.f;
    else srep = 0.5f * (ts[r - 1] + ts[r]);
    if (t < 32) {
      float uu = 0.f, ww = 0.f;
      for (int j = 0; j < 16; j++) {
        float h = h0[j], b = wsm[O_B1 + j];
        if (srep * h + b > 0.f) {
          float w2 = wsm[O_W2 + j * 32 + t];
          uu += h * w2;
          ww += b * w2;
        }
      }
      wsm[O_U + r * 32 + t] = uu;
      wsm[O_WWR + r * 32 + t] = ww;
    }
  }
  for (int i = t; i < 66; i += blockDim.x) {
    float m0 = 0.f, m1 = 0.f;
    for (int k = 0; k < 32; k++) {
      float w1 = wsm[O_WE1 + i * 32 + k];
      m0 += w1 * wsm[O_WE2 + k * 2 + 0];
      m1 += w1 * wsm[O_WE2 + k * 2 + 1];
    }
    wsm[O_M + i * 2 + 0] = m0;
    wsm[O_M + i * 2 + 1] = m1;
  }
  if (t == 0) {
    float b20 = wsm[O_BE2 + 0], b21 = wsm[O_BE2 + 1];
    for (int k = 0; k < 32; k++) {
      b20 += wsm[O_BE1 + k] * wsm[O_WE2 + k * 2 + 0];
      b21 += wsm[O_BE1 + k] * wsm[O_WE2 + k * 2 + 1];
    }
    wsm[O_BIAS2 + 0] = b20;
    wsm[O_BIAS2 + 1] = b21;
  }
}

// --- bucket radix partition (atomic-free globally) -------------------------
__global__ __launch_bounds__(1024) void k_hist(const int* __restrict__ dst,
                                               int* __restrict__ counts,
                                               int E, int chunk) {
  __shared__ int h[KB];
  for (int i = threadIdx.x; i < KB; i += blockDim.x) h[i] = 0;
  __syncthreads();
  int b = blockIdx.x;
  int start = b * chunk, end = min(E, start + chunk);
  int tid = threadIdx.x, BD = blockDim.x;
  bool va = ((chunk & 3) == 0) && ((((unsigned long long)(const void*)dst) & 15ull) == 0ull);
  if (va) {
    for (int base = start; base < end; base += BD * 4) {
      int idx = base + tid * 4;
      if (idx + 4 <= end) {
        int4 d4 = *(const int4*)(dst + idx);
        atomicAdd(&h[d4.x >> 7], 1);
        atomicAdd(&h[d4.y >> 7], 1);
        atomicAdd(&h[d4.z >> 7], 1);
        atomicAdd(&h[d4.w >> 7], 1);
      } else {
        for (int e = idx; e < end; e++) atomicAdd(&h[dst[e] >> 7], 1);
      }
    }
  } else {
    for (int base = start; base < end; base += BD * 4) {
#pragma unroll
      for (int u = 0; u < 4; u++) {
        int idx = base + u * BD + tid;
        if (idx < end) atomicAdd(&h[dst[idx] >> 7], 1);
      }
    }
  }
  __syncthreads();
  for (int i = threadIdx.x; i < KB; i += blockDim.x)
    counts[i * FBC + b] = h[i];
}

__global__ __launch_bounds__(FBC) void k_scanA(const int* __restrict__ counts,
                                               int* __restrict__ prefx,
                                               int* __restrict__ totals) {
  __shared__ int s[FBC];
  int k = blockIdx.x, t = threadIdx.x;
  int v = counts[k * FBC + t];
  s[t] = v;
  __syncthreads();
  for (int off = 1; off < FBC; off <<= 1) {
    int add = (t >= off) ? s[t - off] : 0;
    __syncthreads();
    s[t] += add;
    __syncthreads();
  }
  prefx[k * FBC + t] = s[t] - v;
  if (t == FBC - 1) totals[k] = s[t];
}

__global__ __launch_bounds__(1024) void k_scanB(const int* __restrict__ totals,
                                                int* __restrict__ bases) {
  __shared__ int s[1024];
  int t = threadIdx.x;
  int v = (t < KB) ? totals[t] : 0;
  s[t] = v;
  __syncthreads();
  for (int off = 1; off < 1024; off <<= 1) {
    int add = (t >= off) ? s[t - off] : 0;
    __syncthreads();
    s[t] += add;
    __syncthreads();
  }
  if (t < KB) bases[t] = s[t] - v;
  if (t == KB - 1) bases[KB] = s[t];
}

__global__ __launch_bounds__(1024) void k_fillsort(const int* __restrict__ src,
                                                   const int* __restrict__ dst,
                                                   const int* __restrict__ counts,
                                                   const int* __restrict__ prefx,
                                                   const int* __restrict__ bases,
                                                   unsigned int* __restrict__ recs,
                                                   int E, int chunk) {
  __shared__ unsigned int staged[STCAP];
  __shared__ int cnt[KB], r0o[KB + 1], r0c[KB], tgt[KB];
  int b = blockIdx.x;
  int tid = threadIdx.x, BD = blockDim.x;
  for (int i = tid; i < KB; i += BD) {
    cnt[i] = counts[i * FBC + b];
    tgt[i] = bases[i] + prefx[i * FBC + b];
  }
  __syncthreads();
  int start = b * chunk, end = min(E, start + chunk);
  int rn = end - start;
  if (tid < KB) r0o[tid] = cnt[tid];
  __syncthreads();
  for (int off = 1; off < KB; off <<= 1) {
    int add = 0;
    if (tid < KB && tid >= off) add = r0o[tid - off];
    __syncthreads();
    if (tid < KB) r0o[tid] += add;
    __syncthreads();
  }
  if (tid < KB) r0c[tid] = r0o[tid] - cnt[tid];
  __syncthreads();
  if (tid < KB) r0o[tid] = r0c[tid];
  if (tid == 0) r0o[KB] = rn;
  __syncthreads();
  bool va = ((chunk & 3) == 0) &&
            ((((unsigned long long)(const void*)dst) & 15ull) == 0ull) &&
            ((((unsigned long long)(const void*)src) & 15ull) == 0ull);
  if (va) {
    for (int base = 0; base < rn; base += BD * 4) {
      int idx = base + tid * 4;
      if (idx + 4 <= rn) {
        int4 d4 = *(const int4*)(dst + start + idx);
        int4 s4 = *(const int4*)(src + start + idx);
        int p0 = atomicAdd(&r0c[d4.x >> 7], 1);
        staged[p0] = ((unsigned int)s4.x << 7) | (unsigned int)(d4.x & 127);
        int p1 = atomicAdd(&r0c[d4.y >> 7], 1);
        staged[p1] = ((unsigned int)s4.y << 7) | (unsigned int)(d4.y & 127);
        int p2 = atomicAdd(&r0c[d4.z >> 7], 1);
        staged[p2] = ((unsigned int)s4.z << 7) | (unsigned int)(d4.z & 127);
        int p3 = atomicAdd(&r0c[d4.w >> 7], 1);
        staged[p3] = ((unsigned int)s4.w << 7) | (unsigned int)(d4.w & 127);
      } else {
        for (int e2 = idx; e2 < rn; e2++) {
          int d = dst[start + e2];
          int s = src[start + e2];
          int pos = atomicAdd(&r0c[d >> 7], 1);
          staged[pos] = ((unsigned int)s << 7) | (unsigned int)(d & 127);
        }
      }
    }
  } else {
    for (int base = 0; base < rn; base += BD * 4) {
#pragma unroll
      for (int u = 0; u < 4; u++) {
        int idx = base + u * BD + tid;
        if (idx < rn) {
          int d = dst[start + idx];
          int s = src[start + idx];
          int pos = atomicAdd(&r0c[d >> 7], 1);
          staged[pos] = ((unsigned int)s << 7) | (unsigned int)(d & 127);
        }
      }
    }
  }
  __syncthreads();
  int nquads = (rn + 3) >> 2;
  for (int q = tid; q < nquads; q += BD) {
    int t0 = q * 4;
    int lo = 0, hi = KB;
    while (hi - lo > 1) {
      int mid = (lo + hi) >> 1;
      if (r0o[mid] <= t0) lo = mid; else hi = mid;
    }
    int tend = min(t0 + 4, rn);
    for (int t = t0; t < tend; t++) {
      while (t >= r0o[lo + 1]) lo++;
      recs[tgt[lo] + (t - r0o[lo])] = staged[t];
    }
  }
}

// --- per-bucket passes -----------------------------------------------------
#define UDG 4
__global__ __launch_bounds__(1024) void k_degdinv(const unsigned int* __restrict__ recs,
                                                  const int* __restrict__ bases,
                                                  float* __restrict__ dinv, int N) {
  __shared__ int cnt[128];
  if (threadIdx.x < 128) cnt[threadIdx.x] = 0;
  __syncthreads();
  int k = blockIdx.x;
  int s0 = bases[k], n = bases[k + 1] - s0;
  const unsigned int* rp = recs + s0;
  int tid = threadIdx.x, BD = blockDim.x;
  for (int base = 0; base < n; base += BD * UDG) {
    unsigned int r[UDG]; int ok[UDG];
#pragma unroll
    for (int u = 0; u < UDG; u++) {
      int idx = base + u * BD + tid;
      ok[u] = idx < n;
      r[u] = ok[u] ? rp[idx] : 0u;
    }
#pragma unroll
    for (int u = 0; u < UDG; u++)
      if (ok[u]) atomicAdd(&cnt[r[u] & 127u], 1);
  }
  __syncthreads();
  if (threadIdx.x < 128) {
    int v = k * 128 + threadIdx.x;
    if (v < N) dinv[v] = rsqrtf((float)cnt[threadIdx.x] + 1.0f);
  }
}

// emits recq = (alphaQ, betaQ, region, dv-bits)
#define USA 4
__global__ __launch_bounds__(1024) void k_sA(const float* __restrict__ wsm,
                                             const unsigned int* __restrict__ recs,
                                             const int* __restrict__ bases,
                                             const float* __restrict__ dinv,
                                             uint4* __restrict__ recq, int N) {
  __shared__ float acc[128];
  __shared__ float ts[16];
  __shared__ int nt;
  if (threadIdx.x < 128) acc[threadIdx.x] = 0.f;
  if (threadIdx.x == 0) nt = (int)wsm[O_NT];
  if (threadIdx.x < 16) ts[threadIdx.x] = wsm[O_TS + threadIdx.x];
  __syncthreads();
  int k = blockIdx.x;
  int s0 = bases[k], n = bases[k + 1] - s0;
  const unsigned int* rp = recs + s0;
  int tid = threadIdx.x, BD = blockDim.x;
  for (int base = 0; base < n; base += BD * USA) {
    unsigned int r[USA]; int ok[USA];
#pragma unroll
    for (int u = 0; u < USA; u++) {
      int idx = base + u * BD + tid;
      ok[u] = idx < n;
      r[u] = ok[u] ? rp[idx] : 0u;
    }
    float dv[USA];
#pragma unroll
    for (int u = 0; u < USA; u++) dv[u] = ok[u] ? dinv[r[u] >> 7] : 0.f;
#pragma unroll
    for (int u = 0; u < USA; u++)
      if (ok[u]) atomicAdd(&acc[r[u] & 127u], dv[u]);
  }
  __syncthreads();
  if (threadIdx.x < 128) {
    int v = k * 128 + threadIdx.x;
    if (v < N) {
      float dv = dinv[v];
      float s = dv * (acc[threadIdx.x] + dv);
      int rr = 0;
      for (int i = 0; i < nt; i++) rr += (ts[i] < s) ? 1 : 0;
      float alpha = dv * s;
      uint4 q;
      q.x = (unsigned int)(alpha * QSCALE + 0.5f);
      q.y = (unsigned int)(dv * QSCALE + 0.5f);
      q.z = (unsigned int)rr;
      q.w = __float_as_uint(dv);
      recq[v] = q;
    }
  }
}

// one packed u64 LDS atomic per edge; decode to ABg planes
#define UAB 4
__global__ __launch_bounds__(1024) void k_ABacc(const unsigned int* __restrict__ recs,
                                                const int* __restrict__ bases,
                                                const uint4* __restrict__ recq,
                                                float* __restrict__ ABg, int N) {
  __shared__ unsigned long long Lu[128 * LSTR64];
  for (int i = threadIdx.x; i < 128 * LSTR64; i += blockDim.x) Lu[i] = 0ull;
  __syncthreads();
  int k = blockIdx.x;
  int s0 = bases[k], n = bases[k + 1] - s0;
  const unsigned int* rp = recs + s0;
  int tid = threadIdx.x, BD = blockDim.x;
  for (int base = 0; base < n; base += BD * UAB) {
    unsigned int r[UAB]; int ok[UAB];
#pragma unroll
    for (int u = 0; u < UAB; u++) {
      int idx = base + u * BD + tid;
      ok[u] = idx < n;
      r[u] = ok[u] ? rp[idx] : 0u;
    }
    uint4 q[UAB];
#pragma unroll
    for (int u = 0; u < UAB; u++) {
      q[u] = make_uint4(0u, 0u, 0u, 0u);
      if (ok[u]) q[u] = recq[r[u] >> 7];
    }
#pragma unroll
    for (int u = 0; u < UAB; u++) {
      if (ok[u]) {
        unsigned long long c = ((unsigned long long)q[u].x << 32) | (unsigned long long)q[u].y;
        atomicAdd(&Lu[(int)(r[u] & 127u) * LSTR64 + (int)q[u].z], c);
      }
    }
  }
  __syncthreads();
  float* out = ABg + (size_t)k * ABSTR;
  for (int i = tid; i < 34 * 128; i += BD) {
    int r = i >> 7, v = i & 127;
    unsigned long long w;
    float val;
    if (r < NREG) {
      w = Lu[v * LSTR64 + r];
      val = (float)((unsigned int)(w >> 32)) * INVQ;
    } else {
      w = Lu[v * LSTR64 + (r - NREG)];
      val = (float)((unsigned int)(w & 0xFFFFFFFFull)) * INVQ;
    }
    out[i] = val;
  }
}

// per node: AB planes -> x2 -> x3 -> (ps, pd) split tables
__global__ __launch_bounds__(256) void k_node2(const float* __restrict__ wsm,
                                               const float* __restrict__ ABg,
                                               const uint4* __restrict__ recq,
                                               float2* __restrict__ ps2,
                                               float2* __restrict__ pd2, int N) {
  __shared__ float sU[NREG * 32], sW[NREG * 32], sB2[32], sWn[1024], sBn[32], sM[132];
  for (int i = threadIdx.x; i < NREG * 32; i += blockDim.x) {
    sU[i] = wsm[O_U + i];
    sW[i] = wsm[O_WWR + i];
  }
  for (int i = threadIdx.x; i < 1024; i += blockDim.x) sWn[i] = wsm[O_WN + i];
  if (threadIdx.x < 32) {
    sB2[threadIdx.x] = wsm[O_B2C + threadIdx.x];
    sBn[threadIdx.x] = wsm[O_BN + threadIdx.x];
  }
  for (int i = threadIdx.x; i < 132; i += blockDim.x) sM[i] = wsm[O_M + i];
  __syncthreads();
  int v = blockIdx.x * blockDim.x + threadIdx.x;
  if (v >= N) return;
  uint4 self = recq[v];
  float dv = __uint_as_float(self.w);
  float selfa = (float)self.x * INVQ;
  int sr = (int)self.z;
  const float* pb = ABg + (size_t)(v >> 7) * ABSTR + (v & 127);
  float A[NREG], B[NREG];
#pragma unroll
  for (int r = 0; r < NREG; r++) {
    A[r] = pb[r * 128];
    B[r] = pb[(NREG + r) * 128];
  }
  float acc[32];
#pragma unroll
  for (int j = 0; j < 32; j++) acc[j] = 0.f;
#pragma unroll
  for (int r = 0; r < NREG; r++) {
    float Ar = A[r] + ((r == sr) ? selfa : 0.f);
    float Br = B[r] + ((r == sr) ? dv : 0.f);
    if (Ar != 0.f || Br != 0.f) {
#pragma unroll
      for (int j = 0; j < 32; j++)
        acc[j] += Ar * sU[r * 32 + j] + Br * sW[r * 32 + j];
    }
  }
#pragma unroll
  for (int j = 0; j < 32; j++) acc[j] = relu_(dv * acc[j] + sB2[j]);  // x2
  float x3[32];
#pragma unroll
  for (int j = 0; j < 32; j++) {
    float a = sBn[j];
#pragma unroll
    for (int q2 = 0; q2 < 32; q2++) a += acc[q2] * sWn[q2 * 32 + j];
    x3[j] = relu_(a);
  }
  float ps0 = 0.f, ps1 = 0.f, pd0 = 0.f, pd1 = 0.f;
#pragma unroll
  for (int j = 0; j < 32; j++) {
    float x = x3[j];
    ps0 += x * sM[(2 + j) * 2 + 0];
    ps1 += x * sM[(2 + j) * 2 + 1];
    pd0 += x * sM[(34 + j) * 2 + 0];
    pd1 += x * sM[(34 + j) * 2 + 1];
  }
  ps2[v] = make_float2(ps0, ps1);
  pd2[v] = make_float2(pd0, pd1);
}

#define UE 4
__global__ __launch_bounds__(256, 4) void k_edge(const float* __restrict__ wsm,
                                                 const int* __restrict__ src,
                                                 const int* __restrict__ dst,
                                                 const void* __restrict__ ewraw,
                                                 const void* __restrict__ ceraw,
                                                 const float2* __restrict__ ps2,
                                                 const float2* __restrict__ pd2,
                                                 void* __restrict__ out,
                                                 const int* __restrict__ mode, int E) {
  int e0 = (blockIdx.x * blockDim.x + threadIdx.x) * UE;
  bool bf = (*mode) != 0;
  float b0 = wsm[O_BIAS2 + 0], b1 = wsm[O_BIAS2 + 1];
  float M00 = wsm[O_M + 0], M01 = wsm[O_M + 1];
  float M10 = wsm[O_M + 2], M11 = wsm[O_M + 3];
  if (e0 + UE <= E) {
    int4 s4i = *(const int4*)(src + e0);
    int4 d4i = *(const int4*)(dst + e0);
    const int* s = (const int*)&s4i;
    const int* d = (const int*)&d4i;
    float2 sv[UE], dv2[UE];
#pragma unroll
    for (int u = 0; u < UE; u++) sv[u] = ps2[s[u]];
#pragma unroll
    for (int u = 0; u < UE; u++) dv2[u] = pd2[d[u]];
    float ewv[UE], cev[UE];
    if (bf) {
      uint2 ewp = *(const uint2*)((const unsigned short*)ewraw + e0);
      uint2 cep = *(const uint2*)((const unsigned short*)ceraw + e0);
      const unsigned int* ewu = (const unsigned int*)&ewp;
      const unsigned int* ceu = (const unsigned int*)&cep;
#pragma unroll
      for (int u = 0; u < UE; u++) {
        unsigned int w = ewu[u >> 1], c = ceu[u >> 1];
        unsigned short hw = (u & 1) ? (unsigned short)(w >> 16) : (unsigned short)(w & 0xFFFF);
        unsigned short hc = (u & 1) ? (unsigned short)(c >> 16) : (unsigned short)(c & 0xFFFF);
        ewv[u] = bf2f(hw);
        cev[u] = bf2f(hc);
      }
    } else {
      float4 w = *(const float4*)((const float*)ewraw + e0);
      float4 c = *(const float4*)((const float*)ceraw + e0);
      ewv[0] = w.x; ewv[1] = w.y; ewv[2] = w.z; ewv[3] = w.w;
      cev[0] = c.x; cev[1] = c.y; cev[2] = c.z; cev[3] = c.w;
    }
    float o0[UE], o1[UE];
#pragma unroll
    for (int u = 0; u < UE; u++) {
      o0[u] = b0 + ewv[u] * M00 + cev[u] * M10 + sv[u].x + dv2[u].x;
      o1[u] = b1 + ewv[u] * M01 + cev[u] * M11 + sv[u].y + dv2[u].y;
    }
    if (bf) {
      uint4 pk;
      pk.x = ((unsigned int)f2bf(o1[0]) << 16) | (unsigned int)f2bf(o0[0]);
      pk.y = ((unsigned int)f2bf(o1[1]) << 16) | (unsigned int)f2bf(o0[1]);
      pk.z = ((unsigned int)f2bf(o1[2]) << 16) | (unsigned int)f2bf(o0[2]);
      pk.w = ((unsigned int)f2bf(o1[3]) << 16) | (unsigned int)f2bf(o0[3]);
      *(uint4*)((unsigned int*)out + e0) = pk;      // 16B/lane contiguous
    } else {
      float4 w0, w1;
      w0.x = o0[0]; w0.y = o1[0]; w0.z = o0[1]; w0.w = o1[1];
      w1.x = o0[2]; w1.y = o1[2]; w1.z = o0[3]; w1.w = o1[3];
      float* ob = (float*)out + (size_t)e0 * 2;
      *(float4*)ob = w0;
      *(float4*)(ob + 4) = w1;
    }
  } else {
    for (int e = e0; e < E; e++) {
      float ew = bf ? bf2f(((const unsigned short*)ewraw)[e]) : ((const float*)ewraw)[e];
      float ce = bf ? bf2f(((const unsigned short*)ceraw)[e]) : ((const float*)ceraw)[e];
      float2 sv = ps2[src[e]];
      float2 dv2 = pd2[dst[e]];
      float o0 = b0 + ew * M00 + ce * M10 + sv.x + dv2.x;
      float o1 = b1 + ew * M01 + ce * M11 + sv.y + dv2.y;
      if (bf) {
        unsigned int pk = ((unsigned int)f2bf(o1) << 16) | (unsigned int)f2bf(o0);
        ((unsigned int*)out)[e] = pk;
      } else {
        float2 r; r.x = o0; r.y = o1;
        ((float2*)out)[e] = r;
      }
    }
  }
}

extern "C" void kernel_launch(void* const* d_in, const int* in_sizes, int n_in,
                              void* d_out, int out_size, void* d_ws, size_t ws_size,
                              hipStream_t stream) {
  const int* eidx = (const int*)d_in[0];
  const int E = in_sizes[0] / 2;
  const int N = NNODES;
  const int* src = eidx;
  const int* dst = eidx + E;
  int chunk = (E + FBC - 1) / FBC;
  chunk = (chunk + 3) & ~3;                 // multiple of 4 for int4 loads
  if (chunk > STCAP) chunk = (E + FBC - 1) / FBC;  // safety (then scalar path)

  char* ws = (char*)d_ws;
  size_t off = 0;
  size_t off_mode = off; off += 256;
  size_t off_wsm  = off; off += (size_t)WSM_TOTAL * 4;
  off = (off + 255) & ~(size_t)255;
  size_t off_cnts = off; off += (size_t)KB * FBC * 4;
  size_t off_pfx  = off; off += (size_t)KB * FBC * 4;
  size_t off_tot  = off; off += (size_t)KB * 4;
  off = (off + 255) & ~(size_t)255;
  size_t off_base = off; off += (size_t)(KB + 1) * 4;
  off = (off + 255) & ~(size_t)255;
  size_t off_recs = off; off += (size_t)E * 4;
  size_t off_dinv = off; off += (size_t)N * 4;
  off = (off + 255) & ~(size_t)255;
  size_t off_recq = off; off += (size_t)N * 16;
  size_t off_ps2  = off; off += (size_t)N * 8;
  size_t off_pd2  = off; off += (size_t)N * 8;
  off = (off + 255) & ~(size_t)255;
  size_t off_ABg  = off; off += (size_t)KB * ABSTR * 4;
  if (ws_size < off) return;

  int*          mode   = (int*)(ws + off_mode);
  float*        wsm    = (float*)(ws + off_wsm);
  int*          counts = (int*)(ws + off_cnts);
  int*          prefx  = (int*)(ws + off_pfx);
  int*          totals = (int*)(ws + off_tot);
  int*          bases  = (int*)(ws + off_base);
  unsigned int* recs   = (unsigned int*)(ws + off_recs);
  float*        dinv   = (float*)(ws + off_dinv);
  uint4*        recq   = (uint4*)(ws + off_recq);
  float2*       ps2    = (float2*)(ws + off_ps2);
  float2*       pd2    = (float2*)(ws + off_pd2);
  float*        ABg    = (float*)(ws + off_ABg);

  k_setup<<<1, 1024, 0, stream>>>((const unsigned short*)d_in[1],
      d_in[4], d_in[5], d_in[6], d_in[7], d_in[8], d_in[9], d_in[10],
      d_in[11], d_in[12], d_in[13], d_in[14], d_in[15], mode, wsm);
  k_hist<<<FBC, 1024, 0, stream>>>(dst, counts, E, chunk);
  k_scanA<<<KB, FBC, 0, stream>>>(counts, prefx, totals);
  k_scanB<<<1, 1024, 0, stream>>>(totals, bases);
  k_fillsort<<<FBC, 1024, 0, stream>>>(src, dst, counts, prefx, bases, recs, E, chunk);
  k_degdinv<<<KB, 1024, 0, stream>>>(recs, bases, dinv, N);
  k_sA<<<KB, 1024, 0, stream>>>(wsm, recs, bases, dinv, recq, N);
  k_ABacc<<<KB, 1024, 0, stream>>>(recs, bases, recq, ABg, N);
  k_node2<<<(N + 255) / 256, 256, 0, stream>>>(wsm, ABg, recq, ps2, pd2, N);
  {
    long long tot = ((long long)E + UE - 1) / UE;
    int blocks = (int)((tot + 255) / 256);
    k_edge<<<blocks, 256, 0, stream>>>(wsm, src, dst, d_in[1], d_in[2],
                                       ps2, pd2, d_out, mode, E);
  }
}

// Round 15
// 170.381 us; speedup vs baseline: 1.7160x; 1.0052x over previous
//
#include <hip/hip_runtime.h>
#include <hip/hip_bf16.h>

// ---------------------------------------------------------------------------
// KEPCE_GCN, round 15 = R14 with k_edge rewritten SROA-friendly.
//  R14 post-mortem: k_edge stuck at VGPR=20 (can't hold 8 in-flight gathers)
//  because pointer-cast locals ((int*)&s4i, (uint*)&ewp) defeat SROA ->
//  serialized gathers, latency-bound at ~2 in flight. Now: named scalars,
//  .x/.y/.z/.w access only, no address-taken locals.
// ---------------------------------------------------------------------------

#define NNODES 100000
#define NREG   17
#define KB     782          // buckets = ceil(100000/128)
#define FBC    256          // chunk blocks
#define STCAP  12544        // LDS staging capacity (>= chunk)
#define LSTR64 19           // u64 row stride for AB planes (17 + pad)
#define ABSTR  4352         // 34*128 floats per bucket in ABg
#define QSCALE 4194304.0f   // 2^22
#define INVQ   2.384185791015625e-7f

// wsm element offsets (f32)
#define O_W0    0
#define O_B0    8
#define O_W1    16
#define O_B1    144
#define O_W2    160
#define O_B2C   672
#define O_WN    704
#define O_BN    1728
#define O_WE1   1760
#define O_BE1   3872
#define O_WE2   3904
#define O_BE2   3968
#define WSM_N   3970
#define O_H0    3972
#define O_TS    3992
#define O_NT    4008
#define O_U     4016   // 17*32
#define O_WWR   4560   // 17*32
#define O_M     5104   // 66*2
#define O_BIAS2 5236
#define WSM_TOTAL 6144

__device__ __forceinline__ float bf2f(unsigned short u) {
  union { float f; unsigned int i; } v; v.i = ((unsigned int)u) << 16; return v.f;
}
__device__ __forceinline__ unsigned short f2bf(float f) {
  union { float f; unsigned int i; } v; v.f = f;
  unsigned int x = v.i;
  return (unsigned short)((x + 0x7FFFu + ((x >> 16) & 1u)) >> 16);
}
__device__ __forceinline__ float relu_(float x) { return x > 0.f ? x : 0.f; }

// fused: dtype detect + weight convert + derived-tensor prep (one block)
__global__ __launch_bounds__(1024) void k_setup(
    const unsigned short* ewraw,
    const void* p0, const void* p1, const void* p2, const void* p3,
    const void* p4, const void* p5, const void* p6, const void* p7,
    const void* p8, const void* p9, const void* p10, const void* p11,
    int* mode, float* wsm) {
  __shared__ int cnt, smode, snt;
  __shared__ float h0[16], ts[16];
  int t = threadIdx.x;
  if (t == 0) cnt = 0;
  __syncthreads();
  int ok = 0;
  for (int i = t; i < 512; i += blockDim.x) {
    unsigned short h = ewraw[i];
    int e = (h >> 7) & 0xFF;
    if (!(h & 0x8000) && e >= 0x70 && e <= 0x7E) ok++;
  }
  atomicAdd(&cnt, ok);
  __syncthreads();
  if (t == 0) { smode = (cnt >= 400) ? 1 : 0; *mode = smode; }
  __syncthreads();
  int bf = smode;
  const void* ptrs[12] = {p0,p1,p2,p3,p4,p5,p6,p7,p8,p9,p10,p11};
  const int offs[13] = {O_W0,O_B0,O_W1,O_B1,O_W2,O_B2C,O_WN,O_BN,O_WE1,O_BE1,O_WE2,O_BE2,WSM_N};
  for (int idx = t; idx < WSM_N; idx += blockDim.x) {
    int seg = 0;
    while (idx >= offs[seg + 1]) seg++;
    int k = idx - offs[seg];
    wsm[idx] = bf ? bf2f(((const unsigned short*)ptrs[seg])[k])
                  : ((const float*)ptrs[seg])[k];
  }
  __syncthreads();
  if (t < 16) {
    float acc = 0.f;
    for (int j = 0; j < 8; j++)
      acc += (wsm[O_W0 + j] + wsm[O_B0 + j]) * wsm[O_W1 + j * 16 + t];
    h0[t] = acc;
    wsm[O_H0 + t] = acc;
  }
  __syncthreads();
  if (t == 0) {
    int n = 0;
    for (int j = 0; j < 16; j++) {
      float h = h0[j], b = wsm[O_B1 + j];
      if (h != 0.f) {
        float tj = -b / h;
        if (tj > 0.f) {
          int p = n++;
          while (p > 0 && ts[p - 1] > tj) { ts[p] = ts[p - 1]; p--; }
          ts[p] = tj;
        }
      }
    }
    snt = n;
    wsm[O_NT] = (float)n;
    for (int i = 0; i < n; i++) wsm[O_TS + i] = ts[i];
  }
  __syncthreads();
  int n = snt;
  for (int r = 0; r <= n; r++) {
    float srep;
    if (n == 0) srep = 1.f;
    else if (r == 0) srep = ts[0] * 0.5f;
    else if (r == n) srep = ts[n - 1] * 2.f + 1.f;
    else srep = 0.5f * (ts[r - 1] + ts[r]);
    if (t < 32) {
      float uu = 0.f, ww = 0.f;
      for (int j = 0; j < 16; j++) {
        float h = h0[j], b = wsm[O_B1 + j];
        if (srep * h + b > 0.f) {
          float w2 = wsm[O_W2 + j * 32 + t];
          uu += h * w2;
          ww += b * w2;
        }
      }
      wsm[O_U + r * 32 + t] = uu;
      wsm[O_WWR + r * 32 + t] = ww;
    }
  }
  for (int i = t; i < 66; i += blockDim.x) {
    float m0 = 0.f, m1 = 0.f;
    for (int k = 0; k < 32; k++) {
      float w1 = wsm[O_WE1 + i * 32 + k];
      m0 += w1 * wsm[O_WE2 + k * 2 + 0];
      m1 += w1 * wsm[O_WE2 + k * 2 + 1];
    }
    wsm[O_M + i * 2 + 0] = m0;
    wsm[O_M + i * 2 + 1] = m1;
  }
  if (t == 0) {
    float b20 = wsm[O_BE2 + 0], b21 = wsm[O_BE2 + 1];
    for (int k = 0; k < 32; k++) {
      b20 += wsm[O_BE1 + k] * wsm[O_WE2 + k * 2 + 0];
      b21 += wsm[O_BE1 + k] * wsm[O_WE2 + k * 2 + 1];
    }
    wsm[O_BIAS2 + 0] = b20;
    wsm[O_BIAS2 + 1] = b21;
  }
}

// --- bucket radix partition (atomic-free globally) -------------------------
__global__ __launch_bounds__(1024) void k_hist(const int* __restrict__ dst,
                                               int* __restrict__ counts,
                                               int E, int chunk) {
  __shared__ int h[KB];
  for (int i = threadIdx.x; i < KB; i += blockDim.x) h[i] = 0;
  __syncthreads();
  int b = blockIdx.x;
  int start = b * chunk, end = min(E, start + chunk);
  int tid = threadIdx.x, BD = blockDim.x;
  bool va = ((chunk & 3) == 0) && ((((unsigned long long)(const void*)dst) & 15ull) == 0ull);
  if (va) {
    for (int base = start; base < end; base += BD * 4) {
      int idx = base + tid * 4;
      if (idx + 4 <= end) {
        int4 d4 = *(const int4*)(dst + idx);
        atomicAdd(&h[d4.x >> 7], 1);
        atomicAdd(&h[d4.y >> 7], 1);
        atomicAdd(&h[d4.z >> 7], 1);
        atomicAdd(&h[d4.w >> 7], 1);
      } else {
        for (int e = idx; e < end; e++) atomicAdd(&h[dst[e] >> 7], 1);
      }
    }
  } else {
    for (int base = start; base < end; base += BD * 4) {
#pragma unroll
      for (int u = 0; u < 4; u++) {
        int idx = base + u * BD + tid;
        if (idx < end) atomicAdd(&h[dst[idx] >> 7], 1);
      }
    }
  }
  __syncthreads();
  for (int i = threadIdx.x; i < KB; i += blockDim.x)
    counts[i * FBC + b] = h[i];
}

__global__ __launch_bounds__(FBC) void k_scanA(const int* __restrict__ counts,
                                               int* __restrict__ prefx,
                                               int* __restrict__ totals) {
  __shared__ int s[FBC];
  int k = blockIdx.x, t = threadIdx.x;
  int v = counts[k * FBC + t];
  s[t] = v;
  __syncthreads();
  for (int off = 1; off < FBC; off <<= 1) {
    int add = (t >= off) ? s[t - off] : 0;
    __syncthreads();
    s[t] += add;
    __syncthreads();
  }
  prefx[k * FBC + t] = s[t] - v;
  if (t == FBC - 1) totals[k] = s[t];
}

__global__ __launch_bounds__(1024) void k_scanB(const int* __restrict__ totals,
                                                int* __restrict__ bases) {
  __shared__ int s[1024];
  int t = threadIdx.x;
  int v = (t < KB) ? totals[t] : 0;
  s[t] = v;
  __syncthreads();
  for (int off = 1; off < 1024; off <<= 1) {
    int add = (t >= off) ? s[t - off] : 0;
    __syncthreads();
    s[t] += add;
    __syncthreads();
  }
  if (t < KB) bases[t] = s[t] - v;
  if (t == KB - 1) bases[KB] = s[t];
}

__global__ __launch_bounds__(1024) void k_fillsort(const int* __restrict__ src,
                                                   const int* __restrict__ dst,
                                                   const int* __restrict__ counts,
                                                   const int* __restrict__ prefx,
                                                   const int* __restrict__ bases,
                                                   unsigned int* __restrict__ recs,
                                                   int E, int chunk) {
  __shared__ unsigned int staged[STCAP];
  __shared__ int cnt[KB], r0o[KB + 1], r0c[KB], tgt[KB];
  int b = blockIdx.x;
  int tid = threadIdx.x, BD = blockDim.x;
  for (int i = tid; i < KB; i += BD) {
    cnt[i] = counts[i * FBC + b];
    tgt[i] = bases[i] + prefx[i * FBC + b];
  }
  __syncthreads();
  int start = b * chunk, end = min(E, start + chunk);
  int rn = end - start;
  if (tid < KB) r0o[tid] = cnt[tid];
  __syncthreads();
  for (int off = 1; off < KB; off <<= 1) {
    int add = 0;
    if (tid < KB && tid >= off) add = r0o[tid - off];
    __syncthreads();
    if (tid < KB) r0o[tid] += add;
    __syncthreads();
  }
  if (tid < KB) r0c[tid] = r0o[tid] - cnt[tid];
  __syncthreads();
  if (tid < KB) r0o[tid] = r0c[tid];
  if (tid == 0) r0o[KB] = rn;
  __syncthreads();
  bool va = ((chunk & 3) == 0) &&
            ((((unsigned long long)(const void*)dst) & 15ull) == 0ull) &&
            ((((unsigned long long)(const void*)src) & 15ull) == 0ull);
  if (va) {
    for (int base = 0; base < rn; base += BD * 4) {
      int idx = base + tid * 4;
      if (idx + 4 <= rn) {
        int4 d4 = *(const int4*)(dst + start + idx);
        int4 s4 = *(const int4*)(src + start + idx);
        int p0 = atomicAdd(&r0c[d4.x >> 7], 1);
        staged[p0] = ((unsigned int)s4.x << 7) | (unsigned int)(d4.x & 127);
        int p1 = atomicAdd(&r0c[d4.y >> 7], 1);
        staged[p1] = ((unsigned int)s4.y << 7) | (unsigned int)(d4.y & 127);
        int p2 = atomicAdd(&r0c[d4.z >> 7], 1);
        staged[p2] = ((unsigned int)s4.z << 7) | (unsigned int)(d4.z & 127);
        int p3 = atomicAdd(&r0c[d4.w >> 7], 1);
        staged[p3] = ((unsigned int)s4.w << 7) | (unsigned int)(d4.w & 127);
      } else {
        for (int e2 = idx; e2 < rn; e2++) {
          int d = dst[start + e2];
          int s = src[start + e2];
          int pos = atomicAdd(&r0c[d >> 7], 1);
          staged[pos] = ((unsigned int)s << 7) | (unsigned int)(d & 127);
        }
      }
    }
  } else {
    for (int base = 0; base < rn; base += BD * 4) {
#pragma unroll
      for (int u = 0; u < 4; u++) {
        int idx = base + u * BD + tid;
        if (idx < rn) {
          int d = dst[start + idx];
          int s = src[start + idx];
          int pos = atomicAdd(&r0c[d >> 7], 1);
          staged[pos] = ((unsigned int)s << 7) | (unsigned int)(d & 127);
        }
      }
    }
  }
  __syncthreads();
  int nquads = (rn + 3) >> 2;
  for (int q = tid; q < nquads; q += BD) {
    int t0 = q * 4;
    int lo = 0, hi = KB;
    while (hi - lo > 1) {
      int mid = (lo + hi) >> 1;
      if (r0o[mid] <= t0) lo = mid; else hi = mid;
    }
    int tend = min(t0 + 4, rn);
    for (int t = t0; t < tend; t++) {
      while (t >= r0o[lo + 1]) lo++;
      recs[tgt[lo] + (t - r0o[lo])] = staged[t];
    }
  }
}

// --- per-bucket passes -----------------------------------------------------
#define UDG 4
__global__ __launch_bounds__(1024) void k_degdinv(const unsigned int* __restrict__ recs,
                                                  const int* __restrict__ bases,
                                                  float* __restrict__ dinv, int N) {
  __shared__ int cnt[128];
  if (threadIdx.x < 128) cnt[threadIdx.x] = 0;
  __syncthreads();
  int k = blockIdx.x;
  int s0 = bases[k], n = bases[k + 1] - s0;
  const unsigned int* rp = recs + s0;
  int tid = threadIdx.x, BD = blockDim.x;
  for (int base = 0; base < n; base += BD * UDG) {
    unsigned int r[UDG]; int ok[UDG];
#pragma unroll
    for (int u = 0; u < UDG; u++) {
      int idx = base + u * BD + tid;
      ok[u] = idx < n;
      r[u] = ok[u] ? rp[idx] : 0u;
    }
#pragma unroll
    for (int u = 0; u < UDG; u++)
      if (ok[u]) atomicAdd(&cnt[r[u] & 127u], 1);
  }
  __syncthreads();
  if (threadIdx.x < 128) {
    int v = k * 128 + threadIdx.x;
    if (v < N) dinv[v] = rsqrtf((float)cnt[threadIdx.x] + 1.0f);
  }
}

// emits recq = (alphaQ, betaQ, region, dv-bits)
#define USA 4
__global__ __launch_bounds__(1024) void k_sA(const float* __restrict__ wsm,
                                             const unsigned int* __restrict__ recs,
                                             const int* __restrict__ bases,
                                             const float* __restrict__ dinv,
                                             uint4* __restrict__ recq, int N) {
  __shared__ float acc[128];
  __shared__ float ts[16];
  __shared__ int nt;
  if (threadIdx.x < 128) acc[threadIdx.x] = 0.f;
  if (threadIdx.x == 0) nt = (int)wsm[O_NT];
  if (threadIdx.x < 16) ts[threadIdx.x] = wsm[O_TS + threadIdx.x];
  __syncthreads();
  int k = blockIdx.x;
  int s0 = bases[k], n = bases[k + 1] - s0;
  const unsigned int* rp = recs + s0;
  int tid = threadIdx.x, BD = blockDim.x;
  for (int base = 0; base < n; base += BD * USA) {
    unsigned int r[USA]; int ok[USA];
#pragma unroll
    for (int u = 0; u < USA; u++) {
      int idx = base + u * BD + tid;
      ok[u] = idx < n;
      r[u] = ok[u] ? rp[idx] : 0u;
    }
    float dv[USA];
#pragma unroll
    for (int u = 0; u < USA; u++) dv[u] = ok[u] ? dinv[r[u] >> 7] : 0.f;
#pragma unroll
    for (int u = 0; u < USA; u++)
      if (ok[u]) atomicAdd(&acc[r[u] & 127u], dv[u]);
  }
  __syncthreads();
  if (threadIdx.x < 128) {
    int v = k * 128 + threadIdx.x;
    if (v < N) {
      float dv = dinv[v];
      float s = dv * (acc[threadIdx.x] + dv);
      int rr = 0;
      for (int i = 0; i < nt; i++) rr += (ts[i] < s) ? 1 : 0;
      float alpha = dv * s;
      uint4 q;
      q.x = (unsigned int)(alpha * QSCALE + 0.5f);
      q.y = (unsigned int)(dv * QSCALE + 0.5f);
      q.z = (unsigned int)rr;
      q.w = __float_as_uint(dv);
      recq[v] = q;
    }
  }
}

// one packed u64 LDS atomic per edge; decode to ABg planes
#define UAB 4
__global__ __launch_bounds__(1024) void k_ABacc(const unsigned int* __restrict__ recs,
                                                const int* __restrict__ bases,
                                                const uint4* __restrict__ recq,
                                                float* __restrict__ ABg, int N) {
  __shared__ unsigned long long Lu[128 * LSTR64];
  for (int i = threadIdx.x; i < 128 * LSTR64; i += blockDim.x) Lu[i] = 0ull;
  __syncthreads();
  int k = blockIdx.x;
  int s0 = bases[k], n = bases[k + 1] - s0;
  const unsigned int* rp = recs + s0;
  int tid = threadIdx.x, BD = blockDim.x;
  for (int base = 0; base < n; base += BD * UAB) {
    unsigned int r[UAB]; int ok[UAB];
#pragma unroll
    for (int u = 0; u < UAB; u++) {
      int idx = base + u * BD + tid;
      ok[u] = idx < n;
      r[u] = ok[u] ? rp[idx] : 0u;
    }
    uint4 q[UAB];
#pragma unroll
    for (int u = 0; u < UAB; u++) {
      q[u] = make_uint4(0u, 0u, 0u, 0u);
      if (ok[u]) q[u] = recq[r[u] >> 7];
    }
#pragma unroll
    for (int u = 0; u < UAB; u++) {
      if (ok[u]) {
        unsigned long long c = ((unsigned long long)q[u].x << 32) | (unsigned long long)q[u].y;
        atomicAdd(&Lu[(int)(r[u] & 127u) * LSTR64 + (int)q[u].z], c);
      }
    }
  }
  __syncthreads();
  float* out = ABg + (size_t)k * ABSTR;
  for (int i = tid; i < 34 * 128; i += BD) {
    int r = i >> 7, v = i & 127;
    unsigned long long w;
    float val;
    if (r < NREG) {
      w = Lu[v * LSTR64 + r];
      val = (float)((unsigned int)(w >> 32)) * INVQ;
    } else {
      w = Lu[v * LSTR64 + (r - NREG)];
      val = (float)((unsigned int)(w & 0xFFFFFFFFull)) * INVQ;
    }
    out[i] = val;
  }
}

// per node: AB planes -> x2 -> x3 -> (ps, pd) split tables
__global__ __launch_bounds__(256) void k_node2(const float* __restrict__ wsm,
                                               const float* __restrict__ ABg,
                                               const uint4* __restrict__ recq,
                                               float2* __restrict__ ps2,
                                               float2* __restrict__ pd2, int N) {
  __shared__ float sU[NREG * 32], sW[NREG * 32], sB2[32], sWn[1024], sBn[32], sM[132];
  for (int i = threadIdx.x; i < NREG * 32; i += blockDim.x) {
    sU[i] = wsm[O_U + i];
    sW[i] = wsm[O_WWR + i];
  }
  for (int i = threadIdx.x; i < 1024; i += blockDim.x) sWn[i] = wsm[O_WN + i];
  if (threadIdx.x < 32) {
    sB2[threadIdx.x] = wsm[O_B2C + threadIdx.x];
    sBn[threadIdx.x] = wsm[O_BN + threadIdx.x];
  }
  for (int i = threadIdx.x; i < 132; i += blockDim.x) sM[i] = wsm[O_M + i];
  __syncthreads();
  int v = blockIdx.x * blockDim.x + threadIdx.x;
  if (v >= N) return;
  uint4 self = recq[v];
  float dv = __uint_as_float(self.w);
  float selfa = (float)self.x * INVQ;
  int sr = (int)self.z;
  const float* pb = ABg + (size_t)(v >> 7) * ABSTR + (v & 127);
  float A[NREG], B[NREG];
#pragma unroll
  for (int r = 0; r < NREG; r++) {
    A[r] = pb[r * 128];
    B[r] = pb[(NREG + r) * 128];
  }
  float acc[32];
#pragma unroll
  for (int j = 0; j < 32; j++) acc[j] = 0.f;
#pragma unroll
  for (int r = 0; r < NREG; r++) {
    float Ar = A[r] + ((r == sr) ? selfa : 0.f);
    float Br = B[r] + ((r == sr) ? dv : 0.f);
    if (Ar != 0.f || Br != 0.f) {
#pragma unroll
      for (int j = 0; j < 32; j++)
        acc[j] += Ar * sU[r * 32 + j] + Br * sW[r * 32 + j];
    }
  }
#pragma unroll
  for (int j = 0; j < 32; j++) acc[j] = relu_(dv * acc[j] + sB2[j]);  // x2
  float x3[32];
#pragma unroll
  for (int j = 0; j < 32; j++) {
    float a = sBn[j];
#pragma unroll
    for (int q2 = 0; q2 < 32; q2++) a += acc[q2] * sWn[q2 * 32 + j];
    x3[j] = relu_(a);
  }
  float ps0 = 0.f, ps1 = 0.f, pd0 = 0.f, pd1 = 0.f;
#pragma unroll
  for (int j = 0; j < 32; j++) {
    float x = x3[j];
    ps0 += x * sM[(2 + j) * 2 + 0];
    ps1 += x * sM[(2 + j) * 2 + 1];
    pd0 += x * sM[(34 + j) * 2 + 0];
    pd1 += x * sM[(34 + j) * 2 + 1];
  }
  ps2[v] = make_float2(ps0, ps1);
  pd2[v] = make_float2(pd0, pd1);
}

#define UE 4
__global__ __launch_bounds__(256, 4) void k_edge(const float* __restrict__ wsm,
                                                 const int* __restrict__ src,
                                                 const int* __restrict__ dst,
                                                 const void* __restrict__ ewraw,
                                                 const void* __restrict__ ceraw,
                                                 const float2* __restrict__ ps2,
                                                 const float2* __restrict__ pd2,
                                                 void* __restrict__ out,
                                                 const int* __restrict__ mode, int E) {
  int e0 = (blockIdx.x * blockDim.x + threadIdx.x) * UE;
  bool bf = (*mode) != 0;
  float b0 = wsm[O_BIAS2 + 0], b1 = wsm[O_BIAS2 + 1];
  float M00 = wsm[O_M + 0], M01 = wsm[O_M + 1];
  float M10 = wsm[O_M + 2], M11 = wsm[O_M + 3];
  if (e0 + UE <= E) {
    int4 s4i = *(const int4*)(src + e0);
    int4 d4i = *(const int4*)(dst + e0);
    // all gathers issued through named scalars (SROA-friendly; no &local)
    float2 sv0 = ps2[s4i.x];
    float2 sv1 = ps2[s4i.y];
    float2 sv2 = ps2[s4i.z];
    float2 sv3 = ps2[s4i.w];
    float2 dv0 = pd2[d4i.x];
    float2 dv1 = pd2[d4i.y];
    float2 dv2 = pd2[d4i.z];
    float2 dv3 = pd2[d4i.w];
    float ew0, ew1, ew2, ew3, ce0, ce1, ce2, ce3;
    if (bf) {
      uint2 ewp = *(const uint2*)((const unsigned short*)ewraw + e0);
      uint2 cep = *(const uint2*)((const unsigned short*)ceraw + e0);
      ew0 = bf2f((unsigned short)(ewp.x & 0xFFFFu));
      ew1 = bf2f((unsigned short)(ewp.x >> 16));
      ew2 = bf2f((unsigned short)(ewp.y & 0xFFFFu));
      ew3 = bf2f((unsigned short)(ewp.y >> 16));
      ce0 = bf2f((unsigned short)(cep.x & 0xFFFFu));
      ce1 = bf2f((unsigned short)(cep.x >> 16));
      ce2 = bf2f((unsigned short)(cep.y & 0xFFFFu));
      ce3 = bf2f((unsigned short)(cep.y >> 16));
    } else {
      float4 w = *(const float4*)((const float*)ewraw + e0);
      float4 c = *(const float4*)((const float*)ceraw + e0);
      ew0 = w.x; ew1 = w.y; ew2 = w.z; ew3 = w.w;
      ce0 = c.x; ce1 = c.y; ce2 = c.z; ce3 = c.w;
    }
    float o00 = b0 + ew0 * M00 + ce0 * M10 + sv0.x + dv0.x;
    float o10 = b1 + ew0 * M01 + ce0 * M11 + sv0.y + dv0.y;
    float o01 = b0 + ew1 * M00 + ce1 * M10 + sv1.x + dv1.x;
    float o11 = b1 + ew1 * M01 + ce1 * M11 + sv1.y + dv1.y;
    float o02 = b0 + ew2 * M00 + ce2 * M10 + sv2.x + dv2.x;
    float o12 = b1 + ew2 * M01 + ce2 * M11 + sv2.y + dv2.y;
    float o03 = b0 + ew3 * M00 + ce3 * M10 + sv3.x + dv3.x;
    float o13 = b1 + ew3 * M01 + ce3 * M11 + sv3.y + dv3.y;
    if (bf) {
      uint4 pk;
      pk.x = ((unsigned int)f2bf(o10) << 16) | (unsigned int)f2bf(o00);
      pk.y = ((unsigned int)f2bf(o11) << 16) | (unsigned int)f2bf(o01);
      pk.z = ((unsigned int)f2bf(o12) << 16) | (unsigned int)f2bf(o02);
      pk.w = ((unsigned int)f2bf(o13) << 16) | (unsigned int)f2bf(o03);
      *(uint4*)((unsigned int*)out + e0) = pk;      // 16B/lane contiguous
    } else {
      float4 w0, w1;
      w0.x = o00; w0.y = o10; w0.z = o01; w0.w = o11;
      w1.x = o02; w1.y = o12; w1.z = o03; w1.w = o13;
      float* ob = (float*)out + (size_t)e0 * 2;
      *(float4*)ob = w0;
      *(float4*)(ob + 4) = w1;
    }
  } else {
    for (int e = e0; e < E; e++) {
      float ew = bf ? bf2f(((const unsigned short*)ewraw)[e]) : ((const float*)ewraw)[e];
      float ce = bf ? bf2f(((const unsigned short*)ceraw)[e]) : ((const float*)ceraw)[e];
      float2 sv = ps2[src[e]];
      float2 dv = pd2[dst[e]];
      float o0 = b0 + ew * M00 + ce * M10 + sv.x + dv.x;
      float o1 = b1 + ew * M01 + ce * M11 + sv.y + dv.y;
      if (bf) {
        unsigned int pk = ((unsigned int)f2bf(o1) << 16) | (unsigned int)f2bf(o0);
        ((unsigned int*)out)[e] = pk;
      } else {
        float2 r; r.x = o0; r.y = o1;
        ((float2*)out)[e] = r;
      }
    }
  }
}

extern "C" void kernel_launch(void* const* d_in, const int* in_sizes, int n_in,
                              void* d_out, int out_size, void* d_ws, size_t ws_size,
                              hipStream_t stream) {
  const int* eidx = (const int*)d_in[0];
  const int E = in_sizes[0] / 2;
  const int N = NNODES;
  const int* src = eidx;
  const int* dst = eidx + E;
  int chunk = (E + FBC - 1) / FBC;
  chunk = (chunk + 3) & ~3;                 // multiple of 4 for int4 loads
  if (chunk > STCAP) chunk = (E + FBC - 1) / FBC;  // safety (then scalar path)

  char* ws = (char*)d_ws;
  size_t off = 0;
  size_t off_mode = off; off += 256;
  size_t off_wsm  = off; off += (size_t)WSM_TOTAL * 4;
  off = (off + 255) & ~(size_t)255;
  size_t off_cnts = off; off += (size_t)KB * FBC * 4;
  size_t off_pfx  = off; off += (size_t)KB * FBC * 4;
  size_t off_tot  = off; off += (size_t)KB * 4;
  off = (off + 255) & ~(size_t)255;
  size_t off_base = off; off += (size_t)(KB + 1) * 4;
  off = (off + 255) & ~(size_t)255;
  size_t off_recs = off; off += (size_t)E * 4;
  size_t off_dinv = off; off += (size_t)N * 4;
  off = (off + 255) & ~(size_t)255;
  size_t off_recq = off; off += (size_t)N * 16;
  size_t off_ps2  = off; off += (size_t)N * 8;
  size_t off_pd2  = off; off += (size_t)N * 8;
  off = (off + 255) & ~(size_t)255;
  size_t off_ABg  = off; off += (size_t)KB * ABSTR * 4;
  if (ws_size < off) return;

  int*          mode   = (int*)(ws + off_mode);
  float*        wsm    = (float*)(ws + off_wsm);
  int*          counts = (int*)(ws + off_cnts);
  int*          prefx  = (int*)(ws + off_pfx);
  int*          totals = (int*)(ws + off_tot);
  int*          bases  = (int*)(ws + off_base);
  unsigned int* recs   = (unsigned int*)(ws + off_recs);
  float*        dinv   = (float*)(ws + off_dinv);
  uint4*        recq   = (uint4*)(ws + off_recq);
  float2*       ps2    = (float2*)(ws + off_ps2);
  float2*       pd2    = (float2*)(ws + off_pd2);
  float*        ABg    = (float*)(ws + off_ABg);

  k_setup<<<1, 1024, 0, stream>>>((const unsigned short*)d_in[1],
      d_in[4], d_in[5], d_in[6], d_in[7], d_in[8], d_in[9], d_in[10],
      d_in[11], d_in[12], d_in[13], d_in[14], d_in[15], mode, wsm);
  k_hist<<<FBC, 1024, 0, stream>>>(dst, counts, E, chunk);
  k_scanA<<<KB, FBC, 0, stream>>>(counts, prefx, totals);
  k_scanB<<<1, 1024, 0, stream>>>(totals, bases);
  k_fillsort<<<FBC, 1024, 0, stream>>>(src, dst, counts, prefx, bases, recs, E, chunk);
  k_degdinv<<<KB, 1024, 0, stream>>>(recs, bases, dinv, N);
  k_sA<<<KB, 1024, 0, stream>>>(wsm, recs, bases, dinv, recq, N);
  k_ABacc<<<KB, 1024, 0, stream>>>(recs, bases, recq, ABg, N);
  k_node2<<<(N + 255) / 256, 256, 0, stream>>>(wsm, ABg, recq, ps2, pd2, N);
  {
    long long tot = ((long long)E + UE - 1) / UE;
    int blocks = (int)((tot + 255) / 256);
    k_edge<<<blocks, 256, 0, stream>>>(wsm, src, dst, d_in[1], d_in[2],
                                       ps2, pd2, d_out, mode, E);
  }
}